// Round 2
// baseline (1723.844 us; speedup 1.0000x reference)
//
#include <hip/hip_runtime.h>
#include <hip/hip_bf16.h>

#define Bq 8
#define Tq 4096
#define Cq 192
#define NHq 24
#define HSq 8
#define Mq (Bq * Tq)   // 32768

// ---------------------------------------------------------------------------
// Kernel 1: fold lp/hd/vd/cd convs into one effective 3x3 kernel, laid out as
// GEMM weight W_gemm[k][cout] with k = tap*192 + cin  (tap = ky*3+kx)
// ---------------------------------------------------------------------------
__global__ void prep_weights_kernel(const float* __restrict__ w_lp,
                                    const float* __restrict__ w_hd,
                                    const float* __restrict__ w_vd,
                                    const float* __restrict__ w_cd,
                                    const float* __restrict__ theta,
                                    float* __restrict__ Wg) {
    int idx = blockIdx.x * 256 + threadIdx.x;   // cout*192 + cin
    if (idx >= Cq * Cq) return;
    int cout = idx / Cq, cin = idx - cout * Cq;
    float t9[9];
#pragma unroll
    for (int t = 0; t < 9; ++t) t9[t] = 0.f;
    float lp = w_lp[idx];
    t9[1] += lp; t9[3] += lp; t9[5] += lp; t9[7] += lp; t9[4] -= 4.f * lp;
    float h0 = w_hd[idx * 3 + 0], h1 = w_hd[idx * 3 + 1], h2 = w_hd[idx * 3 + 2];
    t9[0] += h0; t9[3] += h1; t9[6] += h2;
    t9[2] -= h0; t9[5] -= h1; t9[8] -= h2;
    float v0 = w_vd[idx * 3 + 0], v1 = w_vd[idx * 3 + 1], v2 = w_vd[idx * 3 + 2];
    t9[0] += v0; t9[1] += v1; t9[2] += v2;
    t9[6] -= v0; t9[7] -= v1; t9[8] -= v2;
    float sum = 0.f;
#pragma unroll
    for (int t = 0; t < 9; ++t) {
        float cdv = w_cd[idx * 9 + t];
        t9[t] += cdv; sum += cdv;
    }
    t9[4] -= theta[0] * sum;
#pragma unroll
    for (int t = 0; t < 9; ++t)
        Wg[((size_t)(t * Cq + cin)) * Cq + cout] = t9[t];
}

// ---------------------------------------------------------------------------
// Generic fp32 tiled GEMM: C[M][N] = A @ W  (W is [K][N] row-major)
// ALOAD: 0 = plain (lda), 1 = conv implicit-gemm from x (k = tap*192+cin),
//        2 = mixed: x + xx*maa_x  (A=x, aux0=xx, aux1=maa_x)
// EPI:   0 = none, 1 = acc - x (aux0=x), 2 = tanh, 3 = silu,
//        4 = exp(-exp(sd[n]+acc)) (aux0=spatial_decay)
// ---------------------------------------------------------------------------
#define BM 64
#define BN 64
#define BK 32
#define PADq 4

template <int ALOAD, int EPI>
__global__ __launch_bounds__(256) void gemm_kernel(
    const float* __restrict__ A, const float* __restrict__ W,
    float* __restrict__ C, int M, int N, int K, int lda,
    const float* __restrict__ aux0, const float* __restrict__ aux1) {
    __shared__ float As[BK][BM + PADq];
    __shared__ float Ws[BK][BN + PADq];
    int m0 = blockIdx.x * BM;
    int n0 = blockIdx.y * BN;
    int tid = threadIdx.x;
    int ty = tid >> 4, tx = tid & 15;
    float acc[4][4];
#pragma unroll
    for (int a = 0; a < 4; ++a)
#pragma unroll
        for (int b = 0; b < 4; ++b) acc[a][b] = 0.f;

    for (int k0 = 0; k0 < K; k0 += BK) {
        // ---- load A tile -> As[k][m] (transposed) ----
        {
            int ki = tid & 31;
            int mbase = tid >> 5;   // 0..7
#pragma unroll
            for (int rr = 0; rr < 8; ++rr) {
                int mi = mbase + rr * 8;
                int m = m0 + mi;
                int kk = k0 + ki;
                float val;
                if (ALOAD == 0) {
                    val = A[(size_t)m * lda + kk];
                } else if (ALOAD == 2) {
                    size_t g = (size_t)m * lda + kk;
                    val = A[g] + aux0[g] * aux1[kk];
                } else {  // conv implicit gemm
                    int tap = kk / Cq, cin = kk - tap * Cq;
                    int dy = tap / 3 - 1, dx = tap - (tap / 3) * 3 - 1;
                    int b = m >> 12, pos = m & 4095;
                    int hh = (pos >> 6) + dy, wc = (pos & 63) + dx;
                    bool ok = ((unsigned)hh < 64u) && ((unsigned)wc < 64u);
                    val = ok ? A[((size_t)(b << 12) + hh * 64 + wc) * Cq + cin] : 0.f;
                }
                As[ki][mi] = val;
            }
        }
        // ---- load W tile -> Ws[k][n] ----
        {
            int ni = tid & 63;
            int kbase = tid >> 6;  // 0..3
            int nn = n0 + ni;
#pragma unroll
            for (int rr = 0; rr < 8; ++rr) {
                int ki = kbase + rr * 4;
                float val = (nn < N) ? W[(size_t)(k0 + ki) * N + nn] : 0.f;
                Ws[ki][ni] = val;
            }
        }
        __syncthreads();
#pragma unroll
        for (int kk = 0; kk < BK; ++kk) {
            float4 a4 = *(const float4*)&As[kk][ty * 4];
            float4 b4 = *(const float4*)&Ws[kk][tx * 4];
            float av[4] = {a4.x, a4.y, a4.z, a4.w};
            float bv[4] = {b4.x, b4.y, b4.z, b4.w};
#pragma unroll
            for (int a = 0; a < 4; ++a)
#pragma unroll
                for (int b = 0; b < 4; ++b)
                    acc[a][b] = fmaf(av[a], bv[b], acc[a][b]);
        }
        __syncthreads();
    }
    // ---- epilogue + store ----
#pragma unroll
    for (int a = 0; a < 4; ++a) {
        int m = m0 + ty * 4 + a;
#pragma unroll
        for (int b = 0; b < 4; ++b) {
            int n = n0 + tx * 4 + b;
            if (n >= N) continue;
            float val = acc[a][b];
            if (EPI == 1) val -= aux0[(size_t)m * N + n];
            else if (EPI == 2) val = tanhf(val);
            else if (EPI == 3) val = val / (1.f + expf(-val));
            else if (EPI == 4) val = expf(-expf(aux0[n] + val));
            C[(size_t)m * N + n] = val;
        }
    }
}

// ---------------------------------------------------------------------------
// mix2: from tmp (tanh(xxx@maa_w1), [M][160]) compute the 5 data-dependent
// mixes and emit xw,xk,xv,xr,xg = x + xx*(maa_f + m_f)
// ---------------------------------------------------------------------------
#define MIX_ROWS 16
__global__ __launch_bounds__(192) void mix2_kernel(
    const float* __restrict__ x, const float* __restrict__ xx,
    const float* __restrict__ tmp, const float* __restrict__ w2,
    const float* __restrict__ maa_w, const float* __restrict__ maa_k,
    const float* __restrict__ maa_v, const float* __restrict__ maa_r,
    const float* __restrict__ maa_g,
    float* __restrict__ xw, float* __restrict__ xk, float* __restrict__ xv,
    float* __restrict__ xr, float* __restrict__ xg) {
    __shared__ float ts[MIX_ROWS][160];
    int row0 = blockIdx.x * MIX_ROWS;
    int c = threadIdx.x;  // 0..191
    for (int idx = c; idx < MIX_ROWS * 160; idx += 192) {
        int rr = idx / 160, dd = idx - rr * 160;
        ts[rr][dd] = tmp[(size_t)(row0 + rr) * 160 + dd];
    }
    __syncthreads();
    float mwc = maa_w[c], mkc = maa_k[c], mvc = maa_v[c], mrc = maa_r[c], mgc = maa_g[c];
    for (int rr = 0; rr < MIX_ROWS; ++rr) {
        size_t row = row0 + rr;
        float m0 = 0.f, m1 = 0.f, m2 = 0.f, m3 = 0.f, m4 = 0.f;
#pragma unroll 8
        for (int dd = 0; dd < 32; ++dd) {
            float t0 = ts[rr][dd];
            float t1 = ts[rr][32 + dd];
            float t2 = ts[rr][64 + dd];
            float t3 = ts[rr][96 + dd];
            float t4 = ts[rr][128 + dd];
            m0 = fmaf(t0, w2[(size_t)(0 * 32 + dd) * Cq + c], m0);
            m1 = fmaf(t1, w2[(size_t)(1 * 32 + dd) * Cq + c], m1);
            m2 = fmaf(t2, w2[(size_t)(2 * 32 + dd) * Cq + c], m2);
            m3 = fmaf(t3, w2[(size_t)(3 * 32 + dd) * Cq + c], m3);
            m4 = fmaf(t4, w2[(size_t)(4 * 32 + dd) * Cq + c], m4);
        }
        float xvv = x[row * Cq + c], xxv = xx[row * Cq + c];
        xw[row * Cq + c] = fmaf(xxv, mwc + m0, xvv);
        xk[row * Cq + c] = fmaf(xxv, mkc + m1, xvv);
        xv[row * Cq + c] = fmaf(xxv, mvc + m2, xvv);
        xr[row * Cq + c] = fmaf(xxv, mrc + m3, xvv);
        xg[row * Cq + c] = fmaf(xxv, mgc + m4, xvv);
    }
}

// ---------------------------------------------------------------------------
// WKV6 recurrence: one wave per (b, head); lane = (i<<3)|j; lane owns S[j][i]
// ---------------------------------------------------------------------------
#define TBq 64
__global__ __launch_bounds__(64) void wkv_kernel(
    const float* __restrict__ r, const float* __restrict__ k,
    const float* __restrict__ v, const float* __restrict__ d,
    const float* __restrict__ u, float* __restrict__ y) {
    int bh = blockIdx.x;
    int b = bh / NHq, h = bh - b * NHq;
    int lane = threadIdx.x;
    int i = lane >> 3, j = lane & 7;
    size_t base = (size_t)b * Tq * Cq + h * HSq;
    float S = 0.f;
    float uj = u[h * HSq + j];
    __shared__ float rs[TBq][8], ks[TBq][8], vs[TBq][8], ds[TBq][8], ys[TBq][8];

    for (int t0 = 0; t0 < Tq; t0 += TBq) {
#pragma unroll
        for (int rep = 0; rep < 2; ++rep) {
            int cidx = lane + rep * 64;        // 0..127
            int tsub = cidx >> 1, q = cidx & 1;
            size_t g = base + (size_t)(t0 + tsub) * Cq + q * 4;
            *(float4*)&rs[tsub][q * 4] = *(const float4*)&r[g];
            *(float4*)&ks[tsub][q * 4] = *(const float4*)&k[g];
            *(float4*)&vs[tsub][q * 4] = *(const float4*)&v[g];
            *(float4*)&ds[tsub][q * 4] = *(const float4*)&d[g];
        }
        __syncthreads();
#pragma unroll 16
        for (int tsub = 0; tsub < TBq; ++tsub) {
            float rj = rs[tsub][j];
            float kj = ks[tsub][j];
            float vi = vs[tsub][i];
            float dj = ds[tsub][j];
            float kv = kj * vi;
            float yp = rj * fmaf(uj, kv, S);
            S = fmaf(dj, S, kv);
            yp += __shfl_xor(yp, 1);
            yp += __shfl_xor(yp, 2);
            yp += __shfl_xor(yp, 4);
            if (j == 0) ys[tsub][i] = yp;
        }
        __syncthreads();
#pragma unroll
        for (int rep = 0; rep < 2; ++rep) {
            int cidx = lane + rep * 64;
            int tsub = cidx >> 1, q = cidx & 1;
            *(float4*)&y[base + (size_t)(t0 + tsub) * Cq + q * 4] =
                *(const float4*)&ys[tsub][q * 4];
        }
        __syncthreads();
    }
}

// ---------------------------------------------------------------------------
// LayerNorm over C then multiply by gate g -> gate buffer
// one wave per row (4 rows / 256-thread block)
// ---------------------------------------------------------------------------
__global__ __launch_bounds__(256) void ln_gate_kernel(
    const float* __restrict__ y, const float* __restrict__ g,
    const float* __restrict__ ln_g, const float* __restrict__ ln_b,
    float* __restrict__ out) {
    int row = blockIdx.x * 4 + (threadIdx.x >> 6);
    int lane = threadIdx.x & 63;
    const float* yr = y + (size_t)row * Cq;
    float a0 = yr[lane], a1 = yr[lane + 64], a2 = yr[lane + 128];
    float s = a0 + a1 + a2;
    float ss = a0 * a0 + a1 * a1 + a2 * a2;
#pragma unroll
    for (int m = 1; m < 64; m <<= 1) {
        s += __shfl_xor(s, m);
        ss += __shfl_xor(ss, m);
    }
    float mu = s * (1.f / 192.f);
    float var = ss * (1.f / 192.f) - mu * mu;
    float rstd = rsqrtf(var + 1e-5f);
    const float* gr = g + (size_t)row * Cq;
    float* orow = out + (size_t)row * Cq;
#pragma unroll
    for (int q = 0; q < 3; ++q) {
        int cc = lane + q * 64;
        float yn = (yr[cc] - mu) * rstd * ln_g[cc] + ln_b[cc];
        orow[cc] = yn * gr[cc];
    }
}

// ---------------------------------------------------------------------------
extern "C" void kernel_launch(void* const* d_in, const int* in_sizes, int n_in,
                              void* d_out, int out_size, void* d_ws, size_t ws_size,
                              hipStream_t stream) {
    const float* x        = (const float*)d_in[0];
    const float* maa_x    = (const float*)d_in[1];
    const float* maa_w    = (const float*)d_in[2];
    const float* maa_k    = (const float*)d_in[3];
    const float* maa_v    = (const float*)d_in[4];
    const float* maa_r    = (const float*)d_in[5];
    const float* maa_g    = (const float*)d_in[6];
    const float* maa_w1   = (const float*)d_in[7];
    const float* maa_w2   = (const float*)d_in[8];
    const float* decay_w1 = (const float*)d_in[9];
    const float* decay_w2 = (const float*)d_in[10];
    const float* sdecay   = (const float*)d_in[11];
    const float* u        = (const float*)d_in[12];
    const float* Wr       = (const float*)d_in[13];
    const float* Wk       = (const float*)d_in[14];
    const float* Wv       = (const float*)d_in[15];
    const float* Wgp      = (const float*)d_in[16];
    const float* Wo       = (const float*)d_in[17];
    const float* ln_g     = (const float*)d_in[18];
    const float* ln_b     = (const float*)d_in[19];
    const float* w_lp     = (const float*)d_in[20];
    const float* w_hd     = (const float*)d_in[21];
    const float* w_vd     = (const float*)d_in[22];
    const float* w_cd     = (const float*)d_in[23];
    const float* theta    = (const float*)d_in[24];
    float* out = (float*)d_out;

    const size_t BIG = (size_t)Mq * Cq;          // 6,291,456 floats
    float* ws    = (float*)d_ws;
    float* Wgemm = ws;                           // 331,776
    float* tmp   = Wgemm + 331776;               // 32768*160
    float* wtmp  = tmp + (size_t)Mq * 160;       // 32768*64
    float* buf0  = wtmp + (size_t)Mq * 64;
    float* buf1  = buf0 + BIG;
    float* buf2  = buf1 + BIG;
    float* buf3  = buf2 + BIG;
    float* buf4  = buf3 + BIG;
    float* buf5  = buf4 + BIG;

    dim3 blk(256);
    dim3 gemm_grid(Mq / BM, 3);   // N=192
    dim3 gemm_grid1(Mq / BM, 1);  // N=64

    // 1) fold conv weights
    prep_weights_kernel<<<dim3(144), blk, 0, stream>>>(w_lp, w_hd, w_vd, w_cd, theta, Wgemm);
    // 2) conv as implicit GEMM -> xx = conv(x) - x   (buf0 = xx)
    gemm_kernel<1, 1><<<gemm_grid, blk, 0, stream>>>(x, Wgemm, buf0, Mq, Cq, 1728, Cq, x, nullptr);
    // 3) tmp = tanh((x + xx*maa_x) @ maa_w1)   [M,160]
    gemm_kernel<2, 2><<<gemm_grid, blk, 0, stream>>>(x, maa_w1, tmp, Mq, 160, Cq, Cq, buf0, maa_x);
    // 4) five mixed tensors: buf1=xw buf2=xk buf3=xv buf4=xr buf5=xg
    mix2_kernel<<<dim3(Mq / MIX_ROWS), dim3(192), 0, stream>>>(
        x, buf0, tmp, maa_w2, maa_w, maa_k, maa_v, maa_r, maa_g,
        buf1, buf2, buf3, buf4, buf5);
    // 5) projections (ping-pong buffers)
    gemm_kernel<0, 0><<<gemm_grid, blk, 0, stream>>>(buf4, Wr, buf0, Mq, Cq, Cq, Cq, nullptr, nullptr); // r
    gemm_kernel<0, 0><<<gemm_grid, blk, 0, stream>>>(buf2, Wk, buf4, Mq, Cq, Cq, Cq, nullptr, nullptr); // k
    gemm_kernel<0, 0><<<gemm_grid, blk, 0, stream>>>(buf3, Wv, buf2, Mq, Cq, Cq, Cq, nullptr, nullptr); // v
    gemm_kernel<0, 3><<<gemm_grid, blk, 0, stream>>>(buf5, Wgp, buf3, Mq, Cq, Cq, Cq, nullptr, nullptr); // g=silu
    // 6) decay: wtmp = tanh(xw@decay_w1); d = exp(-exp(sd + wtmp@decay_w2)) -> buf5
    gemm_kernel<0, 2><<<gemm_grid1, blk, 0, stream>>>(buf1, decay_w1, wtmp, Mq, 64, Cq, Cq, nullptr, nullptr);
    gemm_kernel<0, 4><<<gemm_grid, blk, 0, stream>>>(wtmp, decay_w2, buf5, Mq, Cq, 64, 64, sdecay, nullptr);
    // 7) WKV recurrence: y -> buf1
    wkv_kernel<<<dim3(Bq * NHq), dim3(64), 0, stream>>>(buf0, buf4, buf2, buf5, u, buf1);
    // 8) LN + gate -> buf0
    ln_gate_kernel<<<dim3(Mq / 4), blk, 0, stream>>>(buf1, buf3, ln_g, ln_b, buf0);
    // 9) output projection
    gemm_kernel<0, 0><<<gemm_grid, blk, 0, stream>>>(buf0, Wo, out, Mq, Cq, Cq, Cq, nullptr, nullptr);
}

// Round 5
// 565.964 us; speedup vs baseline: 3.0459x; 3.0459x over previous
//
#include <hip/hip_runtime.h>
#include <hip/hip_bf16.h>

#define Bq 8
#define Tq 4096
#define Cq 192
#define NHq 24
#define HSq 8
#define Mq (Bq * Tq)   // 32768

#define CLq 64              // WKV chunk length
#define NCHq (Tq / CLq)     // 64 chunks
#define TSq 32              // LDS tile steps inside a chunk

typedef short short8 __attribute__((ext_vector_type(8)));
typedef float f32x4 __attribute__((ext_vector_type(4)));

__device__ __forceinline__ unsigned short f2bf(float f) {
    union { float f; unsigned u; } v; v.f = f;
    unsigned u = v.u;
    return (unsigned short)((u + 0x7FFFu + ((u >> 16) & 1u)) >> 16);
}

// ---------------------------------------------------------------------------
// fold lp/hd/vd/cd convs into one effective 3x3 kernel, emitted directly as
// bf16 GEMM weight Wt[cout][k] with k = tap*192 + cin (i.e. [N][K] layout)
// ---------------------------------------------------------------------------
__global__ void prep_weights_kernel(const float* __restrict__ w_lp,
                                    const float* __restrict__ w_hd,
                                    const float* __restrict__ w_vd,
                                    const float* __restrict__ w_cd,
                                    const float* __restrict__ theta,
                                    unsigned short* __restrict__ Wg) {
    int idx = blockIdx.x * 256 + threadIdx.x;   // cout*192 + cin
    if (idx >= Cq * Cq) return;
    int cout = idx / Cq, cin = idx - cout * Cq;
    float t9[9];
#pragma unroll
    for (int t = 0; t < 9; ++t) t9[t] = 0.f;
    float lp = w_lp[idx];
    t9[1] += lp; t9[3] += lp; t9[5] += lp; t9[7] += lp; t9[4] -= 4.f * lp;
    float h0 = w_hd[idx * 3 + 0], h1 = w_hd[idx * 3 + 1], h2 = w_hd[idx * 3 + 2];
    t9[0] += h0; t9[3] += h1; t9[6] += h2;
    t9[2] -= h0; t9[5] -= h1; t9[8] -= h2;
    float v0 = w_vd[idx * 3 + 0], v1 = w_vd[idx * 3 + 1], v2 = w_vd[idx * 3 + 2];
    t9[0] += v0; t9[1] += v1; t9[2] += v2;
    t9[6] -= v0; t9[7] -= v1; t9[8] -= v2;
    float sum = 0.f;
#pragma unroll
    for (int t = 0; t < 9; ++t) {
        float cdv = w_cd[idx * 9 + t];
        t9[t] += cdv; sum += cdv;
    }
    t9[4] -= theta[0] * sum;
#pragma unroll
    for (int t = 0; t < 9; ++t)
        Wg[(size_t)cout * 1728 + t * Cq + cin] = f2bf(t9[t]);
}

// ---------------------------------------------------------------------------
// transpose+convert fp32 W[K][N] -> bf16 Wt[N][K]
// ---------------------------------------------------------------------------
__global__ void wtrans_kernel(const float* __restrict__ W,
                              unsigned short* __restrict__ Wt, int K, int N) {
    int idx = blockIdx.x * 256 + threadIdx.x;
    if (idx >= N * K) return;
    int n = idx / K, k = idx - n * K;
    Wt[idx] = f2bf(W[(size_t)k * N + n]);
}

// elementwise fp32 -> bf16 (4 elems/thread)
__global__ __launch_bounds__(256) void cvt_bf16_kernel(
    const float* __restrict__ src, unsigned short* __restrict__ dst) {
    size_t g = ((size_t)blockIdx.x * 256 + threadIdx.x) * 4;
    float4 v = *(const float4*)&src[g];
    ushort4 o = make_ushort4(f2bf(v.x), f2bf(v.y), f2bf(v.z), f2bf(v.w));
    *(ushort4*)&dst[g] = o;
}

// xxx = bf16(x + xx*maa_x)
__global__ __launch_bounds__(256) void xxx_kernel(
    const float* __restrict__ x, const float* __restrict__ xx,
    const float* __restrict__ maa_x, unsigned short* __restrict__ out) {
    size_t g = ((size_t)blockIdx.x * 256 + threadIdx.x) * 4;
    int c = (int)(g % Cq);
    float4 xv = *(const float4*)&x[g];
    float4 dv = *(const float4*)&xx[g];
    float4 mv = *(const float4*)&maa_x[c];
    ushort4 o = make_ushort4(f2bf(fmaf(dv.x, mv.x, xv.x)), f2bf(fmaf(dv.y, mv.y, xv.y)),
                             f2bf(fmaf(dv.z, mv.z, xv.z)), f2bf(fmaf(dv.w, mv.w, xv.w)));
    *(ushort4*)&out[g] = o;
}

// ---------------------------------------------------------------------------
// bf16 MFMA GEMM: C[M][N] = A @ Wt^T, Wt is bf16 [N][K].
// ALOAD: 3 = plain bf16 A [M][K]; 1 = conv implicit-gemm from bf16 x [M][192]
// EPI:   0 none, 1 = acc - aux0[m*N+n], 2 = tanh, 3 = silu
// tile 128x64xK64, 4 waves, each wave 32 rows x 64 cols (2x4 16x16 frags)
// LDS XOR-swizzled (byte ^= (row&7)<<4) for conflict-free ds_read_b128 (G4)
// ---------------------------------------------------------------------------
#define GBM 128
#define GBN 64
#define GBK 64

template <int ALOAD, int EPI>
__global__ __launch_bounds__(256) void mgemm_kernel(
    const unsigned short* __restrict__ Asrc,
    const unsigned short* __restrict__ Wt,
    float* __restrict__ C, int N, int K,
    const float* __restrict__ aux0) {
    __shared__ unsigned char lds[(GBM + GBN) * GBK * 2];
    unsigned char* Alds = lds;
    unsigned char* Blds = lds + GBM * GBK * 2;

    const int tid = threadIdx.x;
    const int wid = tid >> 6, lane = tid & 63;
    const int llo = lane & 15, lhi = lane >> 4;
    const int m0 = blockIdx.x * GBM, n0 = blockIdx.y * GBN;

    f32x4 acc[2][4];
#pragma unroll
    for (int a = 0; a < 2; ++a)
#pragma unroll
        for (int b = 0; b < 4; ++b) {
            f32x4 z = {0.f, 0.f, 0.f, 0.f};
            acc[a][b] = z;
        }

    for (int k0 = 0; k0 < K; k0 += GBK) {
        __syncthreads();
        // ---- stage A (128x64 bf16): 1024 chunks of 8 elems, 4/thread ----
#pragma unroll
        for (int rep = 0; rep < 4; ++rep) {
            int c = tid + rep * 256;
            int row = c >> 3, kseg = c & 7;
            int k = k0 + kseg * 8;
            int m = m0 + row;
            short8 val = {0, 0, 0, 0, 0, 0, 0, 0};
            if (ALOAD == 3) {
                val = *(const short8*)&Asrc[(size_t)m * K + k];
            } else {  // conv implicit gemm from x_bf
                int tap = k / Cq, cin = k - tap * Cq;
                int t3 = tap / 3;
                int dy = t3 - 1, dx = tap - t3 * 3 - 1;
                int bb = m >> 12, pos = m & 4095;
                int hh = (pos >> 6) + dy, wc = (pos & 63) + dx;
                if (((unsigned)hh < 64u) && ((unsigned)wc < 64u)) {
                    size_t g = ((size_t)(bb << 12) + (hh << 6) + wc) * Cq + cin;
                    val = *(const short8*)&Asrc[g];
                }
            }
            *(short8*)(Alds + row * 128 + ((kseg * 16) ^ ((row & 7) << 4))) = val;
        }
        // ---- stage B (64x64 bf16 from Wt[n][k]): 512 chunks, 2/thread ----
#pragma unroll
        for (int rep = 0; rep < 2; ++rep) {
            int c = tid + rep * 256;
            int row = c >> 3, kseg = c & 7;
            int n = n0 + row;
            short8 val = {0, 0, 0, 0, 0, 0, 0, 0};
            if (n < N) val = *(const short8*)&Wt[(size_t)n * K + k0 + kseg * 8];
            *(short8*)(Blds + row * 128 + ((kseg * 16) ^ ((row & 7) << 4))) = val;
        }
        __syncthreads();
        // ---- MFMA: 2 k-chunks of 32, 2x4 frags ----
#pragma unroll
        for (int kc = 0; kc < 2; ++kc) {
            int kb = kc * 64 + lhi * 16;
            short8 af[2], bq[4];
#pragma unroll
            for (int mf = 0; mf < 2; ++mf) {
                int row = wid * 32 + mf * 16 + llo;
                af[mf] = *(const short8*)(Alds + row * 128 + (kb ^ ((row & 7) << 4)));
            }
#pragma unroll
            for (int nf = 0; nf < 4; ++nf) {
                int row = nf * 16 + llo;
                bq[nf] = *(const short8*)(Blds + row * 128 + (kb ^ ((row & 7) << 4)));
            }
#pragma unroll
            for (int mf = 0; mf < 2; ++mf)
#pragma unroll
                for (int nf = 0; nf < 4; ++nf)
                    acc[mf][nf] = __builtin_amdgcn_mfma_f32_16x16x32_bf16(
                        af[mf], bq[nf], acc[mf][nf], 0, 0, 0);
        }
    }
    // ---- epilogue: C/D layout col=lane&15, row=(lane>>4)*4+reg ----
#pragma unroll
    for (int mf = 0; mf < 2; ++mf) {
#pragma unroll
        for (int nf = 0; nf < 4; ++nf) {
            int n = n0 + nf * 16 + llo;
            if (n >= N) continue;
#pragma unroll
            for (int r = 0; r < 4; ++r) {
                int m = m0 + wid * 32 + mf * 16 + lhi * 4 + r;
                float val = acc[mf][nf][r];
                if (EPI == 1) val -= aux0[(size_t)m * N + n];
                else if (EPI == 2) val = tanhf(val);
                else if (EPI == 3) val = val / (1.f + expf(-val));
                C[(size_t)m * N + n] = val;
            }
        }
    }
}

// ---------------------------------------------------------------------------
// fp32 tiled GEMM (kept for the numerically-sensitive decay path)
// EPI: 2 = tanh, 4 = exp(-exp(sd[n]+acc)) (aux0=spatial_decay)
// ---------------------------------------------------------------------------
#define BM 64
#define BN 64
#define BK 32
#define PADq 4

template <int EPI>
__global__ __launch_bounds__(256) void gemm_kernel(
    const float* __restrict__ A, const float* __restrict__ W,
    float* __restrict__ C, int M, int N, int K, int lda,
    const float* __restrict__ aux0) {
    __shared__ float As[BK][BM + PADq];
    __shared__ float Ws[BK][BN + PADq];
    int m0 = blockIdx.x * BM;
    int n0 = blockIdx.y * BN;
    int tid = threadIdx.x;
    int ty = tid >> 4, tx = tid & 15;
    float acc[4][4];
#pragma unroll
    for (int a = 0; a < 4; ++a)
#pragma unroll
        for (int b = 0; b < 4; ++b) acc[a][b] = 0.f;

    for (int k0 = 0; k0 < K; k0 += BK) {
        {
            int ki = tid & 31;
            int mbase = tid >> 5;
#pragma unroll
            for (int rr = 0; rr < 8; ++rr) {
                int mi = mbase + rr * 8;
                As[ki][mi] = A[(size_t)(m0 + mi) * lda + k0 + ki];
            }
        }
        {
            int ni = tid & 63;
            int kbase = tid >> 6;
            int nn = n0 + ni;
#pragma unroll
            for (int rr = 0; rr < 8; ++rr) {
                int ki = kbase + rr * 4;
                Ws[ki][ni] = (nn < N) ? W[(size_t)(k0 + ki) * N + nn] : 0.f;
            }
        }
        __syncthreads();
#pragma unroll
        for (int kk = 0; kk < BK; ++kk) {
            float4 a4 = *(const float4*)&As[kk][ty * 4];
            float4 b4 = *(const float4*)&Ws[kk][tx * 4];
            float av[4] = {a4.x, a4.y, a4.z, a4.w};
            float bv[4] = {b4.x, b4.y, b4.z, b4.w};
#pragma unroll
            for (int a = 0; a < 4; ++a)
#pragma unroll
                for (int b = 0; b < 4; ++b)
                    acc[a][b] = fmaf(av[a], bv[b], acc[a][b]);
        }
        __syncthreads();
    }
#pragma unroll
    for (int a = 0; a < 4; ++a) {
        int m = m0 + ty * 4 + a;
#pragma unroll
        for (int b = 0; b < 4; ++b) {
            int n = n0 + tx * 4 + b;
            if (n >= N) continue;
            float val = acc[a][b];
            if (EPI == 2) val = tanhf(val);
            else if (EPI == 4) val = expf(-expf(aux0[n] + val));
            C[(size_t)m * N + n] = val;
        }
    }
}

// ---------------------------------------------------------------------------
// mix2: from tmp (tanh(xxx@maa_w1), [M][160]) emit xw (fp32, decay path) and
// xr,xk,xv,xg (bf16, MFMA projection inputs)
// ---------------------------------------------------------------------------
#define MIX_ROWS 16
__global__ __launch_bounds__(192) void mix2_kernel(
    const float* __restrict__ x, const float* __restrict__ xx,
    const float* __restrict__ tmp, const float* __restrict__ w2,
    const float* __restrict__ maa_w, const float* __restrict__ maa_k,
    const float* __restrict__ maa_v, const float* __restrict__ maa_r,
    const float* __restrict__ maa_g,
    float* __restrict__ xw, unsigned short* __restrict__ xr,
    unsigned short* __restrict__ xk, unsigned short* __restrict__ xv,
    unsigned short* __restrict__ xg) {
    __shared__ float ts[MIX_ROWS][160];
    int row0 = blockIdx.x * MIX_ROWS;
    int c = threadIdx.x;  // 0..191
    for (int idx = c; idx < MIX_ROWS * 160; idx += 192) {
        int rr = idx / 160, dd = idx - rr * 160;
        ts[rr][dd] = tmp[(size_t)(row0 + rr) * 160 + dd];
    }
    __syncthreads();
    float mwc = maa_w[c], mkc = maa_k[c], mvc = maa_v[c], mrc = maa_r[c], mgc = maa_g[c];
    for (int rr = 0; rr < MIX_ROWS; ++rr) {
        size_t row = row0 + rr;
        float m0 = 0.f, m1 = 0.f, m2 = 0.f, m3 = 0.f, m4 = 0.f;
#pragma unroll 8
        for (int dd = 0; dd < 32; ++dd) {
            float t0 = ts[rr][dd];
            float t1 = ts[rr][32 + dd];
            float t2 = ts[rr][64 + dd];
            float t3 = ts[rr][96 + dd];
            float t4 = ts[rr][128 + dd];
            m0 = fmaf(t0, w2[(size_t)(0 * 32 + dd) * Cq + c], m0);
            m1 = fmaf(t1, w2[(size_t)(1 * 32 + dd) * Cq + c], m1);
            m2 = fmaf(t2, w2[(size_t)(2 * 32 + dd) * Cq + c], m2);
            m3 = fmaf(t3, w2[(size_t)(3 * 32 + dd) * Cq + c], m3);
            m4 = fmaf(t4, w2[(size_t)(4 * 32 + dd) * Cq + c], m4);
        }
        float xvv = x[row * Cq + c], xxv = xx[row * Cq + c];
        xw[row * Cq + c] = fmaf(xxv, mwc + m0, xvv);
        xk[row * Cq + c] = f2bf(fmaf(xxv, mkc + m1, xvv));
        xv[row * Cq + c] = f2bf(fmaf(xxv, mvc + m2, xvv));
        xr[row * Cq + c] = f2bf(fmaf(xxv, mrc + m3, xvv));
        xg[row * Cq + c] = f2bf(fmaf(xxv, mgc + m4, xvv));
    }
}

// ---------------------------------------------------------------------------
// WKV6 chunked scan (unchanged from r2): lane = slot*8+i, 8 heads/wave
// ---------------------------------------------------------------------------
__global__ __launch_bounds__(64) void wkv_pass1_kernel(
    const float* __restrict__ k, const float* __restrict__ v,
    const float* __restrict__ d,
    float* __restrict__ Dbuf, float* __restrict__ Cbuf) {
    int chunk = blockIdx.x, hg = blockIdx.y, b = blockIdx.z;
    int lane = threadIdx.x;
    int slot = lane >> 3, i = lane & 7;
    int cbase = hg * 64;
    size_t gbase = ((size_t)b * Tq + (size_t)chunk * CLq) * Cq + cbase;
    __shared__ float ks[TSq][64], vs[TSq][64], ds[TSq][64];
    float S[8], D[8];
#pragma unroll
    for (int j = 0; j < 8; ++j) { S[j] = 0.f; D[j] = 1.f; }
    for (int t0 = 0; t0 < CLq; t0 += TSq) {
        int f = lane & 15, r4 = lane >> 4;
#pragma unroll
        for (int p = 0; p < 8; ++p) {
            int row = r4 + p * 4;
            size_t g = gbase + (size_t)(t0 + row) * Cq + f * 4;
            *(float4*)&ks[row][f * 4] = *(const float4*)&k[g];
            *(float4*)&vs[row][f * 4] = *(const float4*)&v[g];
            *(float4*)&ds[row][f * 4] = *(const float4*)&d[g];
        }
        __syncthreads();
#pragma unroll 8
        for (int t = 0; t < TSq; ++t) {
            float vv = vs[t][lane];
            float4 ka = *(const float4*)&ks[t][slot * 8];
            float4 kb = *(const float4*)&ks[t][slot * 8 + 4];
            float4 da = *(const float4*)&ds[t][slot * 8];
            float4 db = *(const float4*)&ds[t][slot * 8 + 4];
            float kk[8] = {ka.x, ka.y, ka.z, ka.w, kb.x, kb.y, kb.z, kb.w};
            float dd[8] = {da.x, da.y, da.z, da.w, db.x, db.y, db.z, db.w};
#pragma unroll
            for (int j = 0; j < 8; ++j) {
                float kv = kk[j] * vv;
                S[j] = fmaf(dd[j], S[j], kv);
                D[j] *= dd[j];
            }
        }
        __syncthreads();
    }
    size_t dbase = (((size_t)b * NCHq + chunk) * NHq + hg * 8) * 8;
    Dbuf[dbase + lane] = D[i];
    size_t cb = (((size_t)b * NCHq + chunk) * NHq + (hg * 8 + slot)) * 64 + i;
#pragma unroll
    for (int j = 0; j < 8; ++j) Cbuf[cb + j * 8] = S[j];
}

__global__ __launch_bounds__(64) void wkv_pass2_kernel(
    const float* __restrict__ Dbuf, const float* __restrict__ Cbuf,
    float* __restrict__ Sbuf) {
    int bh = blockIdx.x;
    int lane = threadIdx.x;
    int j = lane >> 3, i = lane & 7;
    int b = bh / NHq, h = bh - b * NHq;
    float S = 0.f;
    size_t stride = (size_t)NHq * 64;
    size_t base = ((size_t)b * NCHq * NHq + h) * 64 + j * 8 + i;
    size_t dstride = (size_t)NHq * 8;
    size_t dbase = ((size_t)b * NCHq * NHq + h) * 8 + j;
#pragma unroll 4
    for (int c = 0; c < NCHq; ++c) {
        Sbuf[base + c * stride] = S;
        float D = Dbuf[dbase + c * dstride];
        float C = Cbuf[base + c * stride];
        S = fmaf(D, S, C);
    }
}

__global__ __launch_bounds__(64) void wkv_pass3_kernel(
    const float* __restrict__ r, const float* __restrict__ k,
    const float* __restrict__ v, const float* __restrict__ d,
    const float* __restrict__ u, const float* __restrict__ Sbuf,
    float* __restrict__ y) {
    int chunk = blockIdx.x, hg = blockIdx.y, b = blockIdx.z;
    int lane = threadIdx.x;
    int slot = lane >> 3, i = lane & 7;
    int h = hg * 8 + slot;
    int cbase = hg * 64;
    size_t gbase = ((size_t)b * Tq + (size_t)chunk * CLq) * Cq + cbase;
    __shared__ float rs[TSq][64], ks[TSq][64], vs[TSq][64], ds[TSq][64];
    float S[8], uu[8];
    size_t sb = (((size_t)b * NCHq + chunk) * NHq + h) * 64 + i;
#pragma unroll
    for (int j = 0; j < 8; ++j) {
        S[j] = Sbuf[sb + j * 8];
        uu[j] = u[h * 8 + j];
    }
    for (int t0 = 0; t0 < CLq; t0 += TSq) {
        int f = lane & 15, r4 = lane >> 4;
#pragma unroll
        for (int p = 0; p < 8; ++p) {
            int row = r4 + p * 4;
            size_t g = gbase + (size_t)(t0 + row) * Cq + f * 4;
            *(float4*)&rs[row][f * 4] = *(const float4*)&r[g];
            *(float4*)&ks[row][f * 4] = *(const float4*)&k[g];
            *(float4*)&vs[row][f * 4] = *(const float4*)&v[g];
            *(float4*)&ds[row][f * 4] = *(const float4*)&d[g];
        }
        __syncthreads();
#pragma unroll 8
        for (int t = 0; t < TSq; ++t) {
            float vv = vs[t][lane];
            float4 ra = *(const float4*)&rs[t][slot * 8];
            float4 rb = *(const float4*)&rs[t][slot * 8 + 4];
            float4 ka = *(const float4*)&ks[t][slot * 8];
            float4 kb = *(const float4*)&ks[t][slot * 8 + 4];
            float4 da = *(const float4*)&ds[t][slot * 8];
            float4 db = *(const float4*)&ds[t][slot * 8 + 4];
            float rr[8] = {ra.x, ra.y, ra.z, ra.w, rb.x, rb.y, rb.z, rb.w};
            float kk[8] = {ka.x, ka.y, ka.z, ka.w, kb.x, kb.y, kb.z, kb.w};
            float dd[8] = {da.x, da.y, da.z, da.w, db.x, db.y, db.z, db.w};
            float yv = 0.f;
#pragma unroll
            for (int j = 0; j < 8; ++j) {
                float kv = kk[j] * vv;
                yv = fmaf(rr[j], fmaf(uu[j], kv, S[j]), yv);
                S[j] = fmaf(dd[j], S[j], kv);
            }
            y[gbase + (size_t)(t0 + t) * Cq + lane] = yv;
        }
        __syncthreads();
    }
}

// ---------------------------------------------------------------------------
// LayerNorm + gate -> bf16 output (feeds Wo MFMA GEMM)
// ---------------------------------------------------------------------------
__global__ __launch_bounds__(256) void ln_gate_kernel(
    const float* __restrict__ y, const float* __restrict__ g,
    const float* __restrict__ ln_g, const float* __restrict__ ln_b,
    unsigned short* __restrict__ out) {
    int row = blockIdx.x * 4 + (threadIdx.x >> 6);
    int lane = threadIdx.x & 63;
    const float* yr = y + (size_t)row * Cq;
    float a0 = yr[lane], a1 = yr[lane + 64], a2 = yr[lane + 128];
    float s = a0 + a1 + a2;
    float ss = a0 * a0 + a1 * a1 + a2 * a2;
#pragma unroll
    for (int m = 1; m < 64; m <<= 1) {
        s += __shfl_xor(s, m);
        ss += __shfl_xor(ss, m);
    }
    float mu = s * (1.f / 192.f);
    float var = ss * (1.f / 192.f) - mu * mu;
    float rstd = rsqrtf(var + 1e-5f);
    const float* gr = g + (size_t)row * Cq;
    unsigned short* orow = out + (size_t)row * Cq;
#pragma unroll
    for (int q = 0; q < 3; ++q) {
        int cc = lane + q * 64;
        float yn = (yr[cc] - mu) * rstd * ln_g[cc] + ln_b[cc];
        orow[cc] = f2bf(yn * gr[cc]);
    }
}

// ---------------------------------------------------------------------------
extern "C" void kernel_launch(void* const* d_in, const int* in_sizes, int n_in,
                              void* d_out, int out_size, void* d_ws, size_t ws_size,
                              hipStream_t stream) {
    const float* x        = (const float*)d_in[0];
    const float* maa_x    = (const float*)d_in[1];
    const float* maa_w    = (const float*)d_in[2];
    const float* maa_k    = (const float*)d_in[3];
    const float* maa_v    = (const float*)d_in[4];
    const float* maa_r    = (const float*)d_in[5];
    const float* maa_g    = (const float*)d_in[6];
    const float* maa_w1   = (const float*)d_in[7];
    const float* maa_w2   = (const float*)d_in[8];
    const float* decay_w1 = (const float*)d_in[9];
    const float* decay_w2 = (const float*)d_in[10];
    const float* sdecay   = (const float*)d_in[11];
    const float* u        = (const float*)d_in[12];
    const float* Wr       = (const float*)d_in[13];
    const float* Wk       = (const float*)d_in[14];
    const float* Wv       = (const float*)d_in[15];
    const float* Wgp      = (const float*)d_in[16];
    const float* Wo       = (const float*)d_in[17];
    const float* ln_g     = (const float*)d_in[18];
    const float* ln_b     = (const float*)d_in[19];
    const float* w_lp     = (const float*)d_in[20];
    const float* w_hd     = (const float*)d_in[21];
    const float* w_vd     = (const float*)d_in[22];
    const float* w_cd     = (const float*)d_in[23];
    const float* theta    = (const float*)d_in[24];
    float* out = (float*)d_out;

    const size_t BIG = (size_t)Mq * Cq;          // 6,291,456 floats
    float* ws = (float*)d_ws;
    // bf16 weight regions packed into the first 331,776-float slot
    unsigned short* Wgt_conv = (unsigned short*)ws;            // 192*1728
    unsigned short* Wt_maa = Wgt_conv + (size_t)Cq * 1728;     // 160*192
    unsigned short* Wt_r = Wt_maa + 160 * Cq;
    unsigned short* Wt_k = Wt_r + Cq * Cq;
    unsigned short* Wt_v = Wt_k + Cq * Cq;
    unsigned short* Wt_g = Wt_v + Cq * Cq;
    unsigned short* Wt_o = Wt_g + Cq * Cq;                     // ends < slot
    float* tmp  = ws + 331776;                  // M*160 fp32
    float* wtmp = tmp + (size_t)Mq * 160;       // M*64 fp32
    float* buf0 = wtmp + (size_t)Mq * 64;
    float* buf1 = buf0 + BIG;
    float* buf2 = buf1 + BIG;
    float* buf3 = buf2 + BIG;
    float* buf4 = buf3 + BIG;
    float* buf5 = buf4 + BIG;

    // WKV scratch + gate_b inside tmp region (dead after mix2)
    float* Dbuf = tmp;
    float* Cbuf = Dbuf + (size_t)Bq * NCHq * NHq * 8;
    float* Sbuf = Cbuf + (size_t)Bq * NCHq * NHq * 64;
    unsigned short* gate_b = (unsigned short*)(Sbuf + (size_t)Bq * NCHq * NHq * 64);

    // bf16 staging buffers overlaid on dead fp32 windows
    unsigned short* x_bf  = (unsigned short*)buf2;             // until conv done
    unsigned short* xxx_b = (unsigned short*)(buf2 + BIG / 2); // until maa done
    unsigned short* xv_b  = x_bf;                              // mix2 .. v-proj
    unsigned short* xg_b  = xxx_b;                             // mix2 .. g-proj
    unsigned short* xr_b  = (unsigned short*)buf5;             // mix2 .. r-proj
    unsigned short* xk_b  = (unsigned short*)(buf5 + BIG / 2); // mix2 .. k-proj

    dim3 blk(256);
    dim3 mg(Mq / GBM, 3);        // all MFMA gemms: N=192 or 160 -> 3 col-blocks
    dim3 ew(Mq * Cq / 4 / 256);  // elementwise cvt grids

    // 1) weight prep (bf16, [N][K])
    prep_weights_kernel<<<dim3(144), blk, 0, stream>>>(w_lp, w_hd, w_vd, w_cd, theta, Wgt_conv);
    wtrans_kernel<<<dim3(120), blk, 0, stream>>>(maa_w1, Wt_maa, Cq, 160);
    wtrans_kernel<<<dim3(144), blk, 0, stream>>>(Wr, Wt_r, Cq, Cq);
    wtrans_kernel<<<dim3(144), blk, 0, stream>>>(Wk, Wt_k, Cq, Cq);
    wtrans_kernel<<<dim3(144), blk, 0, stream>>>(Wv, Wt_v, Cq, Cq);
    wtrans_kernel<<<dim3(144), blk, 0, stream>>>(Wgp, Wt_g, Cq, Cq);
    wtrans_kernel<<<dim3(144), blk, 0, stream>>>(Wo, Wt_o, Cq, Cq);
    // 2) x -> bf16; conv as MFMA implicit GEMM -> xx = conv(x) - x (buf0)
    cvt_bf16_kernel<<<ew, blk, 0, stream>>>(x, x_bf);
    mgemm_kernel<1, 1><<<mg, blk, 0, stream>>>(x_bf, Wgt_conv, buf0, Cq, 1728, x);
    // 3) xxx = bf16(x + xx*maa_x); tmp = tanh(xxx @ maa_w1) [M,160]
    xxx_kernel<<<ew, blk, 0, stream>>>(x, buf0, maa_x, xxx_b);
    mgemm_kernel<3, 2><<<mg, blk, 0, stream>>>(xxx_b, Wt_maa, tmp, 160, Cq, nullptr);
    // 4) five mixes: xw fp32 (buf1), xr/xk/xv/xg bf16
    mix2_kernel<<<dim3(Mq / MIX_ROWS), dim3(192), 0, stream>>>(
        x, buf0, tmp, maa_w2, maa_w, maa_k, maa_v, maa_r, maa_g,
        buf1, xr_b, xk_b, xv_b, xg_b);
    // 5) MFMA projections (order matters for buffer overlays)
    mgemm_kernel<3, 0><<<mg, blk, 0, stream>>>(xv_b, Wt_v, buf3, Cq, Cq, nullptr); // v
    mgemm_kernel<3, 3><<<mg, blk, 0, stream>>>(xg_b, Wt_g, buf4, Cq, Cq, nullptr); // g=silu
    mgemm_kernel<3, 0><<<mg, blk, 0, stream>>>(xr_b, Wt_r, buf0, Cq, Cq, nullptr); // r
    mgemm_kernel<3, 0><<<mg, blk, 0, stream>>>(xk_b, Wt_k, buf2, Cq, Cq, nullptr); // k
    // 6) decay (fp32): wtmp = tanh(xw@w1); d = exp(-exp(sd + wtmp@w2)) -> buf5
    gemm_kernel<2><<<dim3(Mq / BM, 1), blk, 0, stream>>>(buf1, decay_w1, wtmp, Mq, 64, Cq, Cq, nullptr);
    gemm_kernel<4><<<dim3(Mq / BM, 3), blk, 0, stream>>>(wtmp, decay_w2, buf5, Mq, Cq, 64, 64, sdecay);
    // 7) WKV chunked scan: r=buf0 k=buf2 v=buf3 d=buf5 -> y=buf1
    wkv_pass1_kernel<<<dim3(NCHq, 3, Bq), dim3(64), 0, stream>>>(buf2, buf3, buf5, Dbuf, Cbuf);
    wkv_pass2_kernel<<<dim3(Bq * NHq), dim3(64), 0, stream>>>(Dbuf, Cbuf, Sbuf);
    wkv_pass3_kernel<<<dim3(NCHq, 3, Bq), dim3(64), 0, stream>>>(buf0, buf2, buf3, buf5, u, Sbuf, buf1);
    // 8) LN + gate -> bf16
    ln_gate_kernel<<<dim3(Mq / 4), blk, 0, stream>>>(buf1, buf4, ln_g, ln_b, gate_b);
    // 9) output projection (MFMA)
    mgemm_kernel<3, 0><<<mg, blk, 0, stream>>>(gate_b, Wt_o, out, Cq, Cq, nullptr);
}

// Round 6
// 451.179 us; speedup vs baseline: 3.8208x; 1.2544x over previous
//
#include <hip/hip_runtime.h>
#include <hip/hip_bf16.h>

#define Bq 8
#define Tq 4096
#define Cq 192
#define NHq 24
#define HSq 8
#define Mq (Bq * Tq)   // 32768

#define CLq 64              // WKV chunk length
#define NCHq (Tq / CLq)     // 64 chunks
#define TSq 32              // LDS tile steps inside a chunk

typedef short short8 __attribute__((ext_vector_type(8)));
typedef float f32x4 __attribute__((ext_vector_type(4)));

__device__ __forceinline__ unsigned short f2bf(float f) {
    union { float f; unsigned u; } v; v.f = f;
    unsigned u = v.u;
    return (unsigned short)((u + 0x7FFFu + ((u >> 16) & 1u)) >> 16);
}

// ---------------------------------------------------------------------------
// fold lp/hd/vd/cd convs into one effective 3x3 kernel, emitted directly as
// bf16 GEMM weight Wt[cout][k] with k = tap*192 + cin (i.e. [N][K] layout)
// ---------------------------------------------------------------------------
__global__ void prep_weights_kernel(const float* __restrict__ w_lp,
                                    const float* __restrict__ w_hd,
                                    const float* __restrict__ w_vd,
                                    const float* __restrict__ w_cd,
                                    const float* __restrict__ theta,
                                    unsigned short* __restrict__ Wg) {
    int idx = blockIdx.x * 256 + threadIdx.x;   // cout*192 + cin
    if (idx >= Cq * Cq) return;
    int cout = idx / Cq, cin = idx - cout * Cq;
    float t9[9];
#pragma unroll
    for (int t = 0; t < 9; ++t) t9[t] = 0.f;
    float lp = w_lp[idx];
    t9[1] += lp; t9[3] += lp; t9[5] += lp; t9[7] += lp; t9[4] -= 4.f * lp;
    float h0 = w_hd[idx * 3 + 0], h1 = w_hd[idx * 3 + 1], h2 = w_hd[idx * 3 + 2];
    t9[0] += h0; t9[3] += h1; t9[6] += h2;
    t9[2] -= h0; t9[5] -= h1; t9[8] -= h2;
    float v0 = w_vd[idx * 3 + 0], v1 = w_vd[idx * 3 + 1], v2 = w_vd[idx * 3 + 2];
    t9[0] += v0; t9[1] += v1; t9[2] += v2;
    t9[6] -= v0; t9[7] -= v1; t9[8] -= v2;
    float sum = 0.f;
#pragma unroll
    for (int t = 0; t < 9; ++t) {
        float cdv = w_cd[idx * 9 + t];
        t9[t] += cdv; sum += cdv;
    }
    t9[4] -= theta[0] * sum;
#pragma unroll
    for (int t = 0; t < 9; ++t)
        Wg[(size_t)cout * 1728 + t * Cq + cin] = f2bf(t9[t]);
}

// ---------------------------------------------------------------------------
// transpose+convert fp32 W[K][N] -> bf16 Wt[N][K]
// ---------------------------------------------------------------------------
__global__ void wtrans_kernel(const float* __restrict__ W,
                              unsigned short* __restrict__ Wt, int K, int N) {
    int idx = blockIdx.x * 256 + threadIdx.x;
    if (idx >= N * K) return;
    int n = idx / K, k = idx - n * K;
    Wt[idx] = f2bf(W[(size_t)k * N + n]);
}

// w2 [5][32][192] fp32 -> w2t [5][192][32] bf16
__global__ void w2t_kernel(const float* __restrict__ w2,
                           unsigned short* __restrict__ w2t) {
    int idx = blockIdx.x * 256 + threadIdx.x;  // f*192*32 + n*32 + k
    if (idx >= 5 * 192 * 32) return;
    int f = idx / (192 * 32), rem = idx - f * 192 * 32;
    int n = rem >> 5, k = rem & 31;
    w2t[idx] = f2bf(w2[(size_t)(f * 32 + k) * Cq + n]);
}

// elementwise fp32 -> bf16 (4 elems/thread)
__global__ __launch_bounds__(256) void cvt_bf16_kernel(
    const float* __restrict__ src, unsigned short* __restrict__ dst) {
    size_t g = ((size_t)blockIdx.x * 256 + threadIdx.x) * 4;
    float4 v = *(const float4*)&src[g];
    ushort4 o = make_ushort4(f2bf(v.x), f2bf(v.y), f2bf(v.z), f2bf(v.w));
    *(ushort4*)&dst[g] = o;
}

// xxx = bf16(x + xx*maa_x)
__global__ __launch_bounds__(256) void xxx_kernel(
    const float* __restrict__ x, const float* __restrict__ xx,
    const float* __restrict__ maa_x, unsigned short* __restrict__ out) {
    size_t g = ((size_t)blockIdx.x * 256 + threadIdx.x) * 4;
    int c = (int)(g % Cq);
    float4 xv = *(const float4*)&x[g];
    float4 dv = *(const float4*)&xx[g];
    float4 mv = *(const float4*)&maa_x[c];
    ushort4 o = make_ushort4(f2bf(fmaf(dv.x, mv.x, xv.x)), f2bf(fmaf(dv.y, mv.y, xv.y)),
                             f2bf(fmaf(dv.z, mv.z, xv.z)), f2bf(fmaf(dv.w, mv.w, xv.w)));
    *(ushort4*)&out[g] = o;
}

// ---------------------------------------------------------------------------
// bf16 MFMA GEMM: C[M][N] = A @ Wt^T, Wt is bf16 [N][K].
// ALOAD: 3 = plain bf16 A [M][K]; 1 = conv implicit-gemm from bf16 x [M][192]
// EPI:   0 none, 1 = acc - aux0[m*N+n], 2 = tanh, 3 = silu
// OBF16: 1 = store bf16 instead of fp32
// tile 128x64xK64, 4 waves, each wave 32 rows x 64 cols (2x4 16x16 frags)
// LDS XOR-swizzled (byte ^= (row&7)<<4) for conflict-free ds_read_b128 (G4)
// ---------------------------------------------------------------------------
#define GBM 128
#define GBN 64
#define GBK 64

template <int ALOAD, int EPI, int OBF16>
__global__ __launch_bounds__(256) void mgemm_kernel(
    const unsigned short* __restrict__ Asrc,
    const unsigned short* __restrict__ Wt,
    void* __restrict__ Cv, int N, int K,
    const float* __restrict__ aux0) {
    __shared__ unsigned char lds[(GBM + GBN) * GBK * 2];
    unsigned char* Alds = lds;
    unsigned char* Blds = lds + GBM * GBK * 2;
    float* C = (float*)Cv;
    unsigned short* Cb = (unsigned short*)Cv;

    const int tid = threadIdx.x;
    const int wid = tid >> 6, lane = tid & 63;
    const int llo = lane & 15, lhi = lane >> 4;
    const int m0 = blockIdx.x * GBM, n0 = blockIdx.y * GBN;

    f32x4 acc[2][4];
#pragma unroll
    for (int a = 0; a < 2; ++a)
#pragma unroll
        for (int b = 0; b < 4; ++b) {
            f32x4 z = {0.f, 0.f, 0.f, 0.f};
            acc[a][b] = z;
        }

    for (int k0 = 0; k0 < K; k0 += GBK) {
        __syncthreads();
        // ---- stage A (128x64 bf16): 1024 chunks of 8 elems, 4/thread ----
#pragma unroll
        for (int rep = 0; rep < 4; ++rep) {
            int c = tid + rep * 256;
            int row = c >> 3, kseg = c & 7;
            int k = k0 + kseg * 8;
            int m = m0 + row;
            short8 val = {0, 0, 0, 0, 0, 0, 0, 0};
            if (ALOAD == 3) {
                val = *(const short8*)&Asrc[(size_t)m * K + k];
            } else {  // conv implicit gemm from x_bf
                int tap = k / Cq, cin = k - tap * Cq;
                int t3 = tap / 3;
                int dy = t3 - 1, dx = tap - t3 * 3 - 1;
                int bb = m >> 12, pos = m & 4095;
                int hh = (pos >> 6) + dy, wc = (pos & 63) + dx;
                if (((unsigned)hh < 64u) && ((unsigned)wc < 64u)) {
                    size_t g = ((size_t)(bb << 12) + (hh << 6) + wc) * Cq + cin;
                    val = *(const short8*)&Asrc[g];
                }
            }
            *(short8*)(Alds + row * 128 + ((kseg * 16) ^ ((row & 7) << 4))) = val;
        }
        // ---- stage B (64x64 bf16 from Wt[n][k]): 512 chunks, 2/thread ----
#pragma unroll
        for (int rep = 0; rep < 2; ++rep) {
            int c = tid + rep * 256;
            int row = c >> 3, kseg = c & 7;
            int n = n0 + row;
            short8 val = {0, 0, 0, 0, 0, 0, 0, 0};
            if (n < N) val = *(const short8*)&Wt[(size_t)n * K + k0 + kseg * 8];
            *(short8*)(Blds + row * 128 + ((kseg * 16) ^ ((row & 7) << 4))) = val;
        }
        __syncthreads();
        // ---- MFMA: 2 k-chunks of 32, 2x4 frags ----
#pragma unroll
        for (int kc = 0; kc < 2; ++kc) {
            int kb = kc * 64 + lhi * 16;
            short8 af[2], bq[4];
#pragma unroll
            for (int mf = 0; mf < 2; ++mf) {
                int row = wid * 32 + mf * 16 + llo;
                af[mf] = *(const short8*)(Alds + row * 128 + (kb ^ ((row & 7) << 4)));
            }
#pragma unroll
            for (int nf = 0; nf < 4; ++nf) {
                int row = nf * 16 + llo;
                bq[nf] = *(const short8*)(Blds + row * 128 + (kb ^ ((row & 7) << 4)));
            }
#pragma unroll
            for (int mf = 0; mf < 2; ++mf)
#pragma unroll
                for (int nf = 0; nf < 4; ++nf)
                    acc[mf][nf] = __builtin_amdgcn_mfma_f32_16x16x32_bf16(
                        af[mf], bq[nf], acc[mf][nf], 0, 0, 0);
        }
    }
    // ---- epilogue: C/D layout col=lane&15, row=(lane>>4)*4+reg ----
#pragma unroll
    for (int mf = 0; mf < 2; ++mf) {
#pragma unroll
        for (int nf = 0; nf < 4; ++nf) {
            int n = n0 + nf * 16 + llo;
            if (n >= N) continue;
#pragma unroll
            for (int r = 0; r < 4; ++r) {
                int m = m0 + wid * 32 + mf * 16 + lhi * 4 + r;
                float val = acc[mf][nf][r];
                if (EPI == 1) val -= aux0[(size_t)m * N + n];
                else if (EPI == 2) val = tanhf(val);
                else if (EPI == 3) val = val / (1.f + expf(-val));
                if (OBF16) Cb[(size_t)m * N + n] = f2bf(val);
                else C[(size_t)m * N + n] = val;
            }
        }
    }
}

// ---------------------------------------------------------------------------
// fp32 tiled GEMM (kept for the numerically-sensitive decay path)
// EPI: 2 = tanh, 4 = exp(-exp(sd[n]+acc)) (aux0=spatial_decay)
// ---------------------------------------------------------------------------
#define BM 64
#define BN 64
#define BK 32
#define PADq 4

template <int EPI>
__global__ __launch_bounds__(256) void gemm_kernel(
    const float* __restrict__ A, const float* __restrict__ W,
    float* __restrict__ C, int M, int N, int K, int lda,
    const float* __restrict__ aux0) {
    __shared__ float As[BK][BM + PADq];
    __shared__ float Ws[BK][BN + PADq];
    int m0 = blockIdx.x * BM;
    int n0 = blockIdx.y * BN;
    int tid = threadIdx.x;
    int ty = tid >> 4, tx = tid & 15;
    float acc[4][4];
#pragma unroll
    for (int a = 0; a < 4; ++a)
#pragma unroll
        for (int b = 0; b < 4; ++b) acc[a][b] = 0.f;

    for (int k0 = 0; k0 < K; k0 += BK) {
        {
            int ki = tid & 31;
            int mbase = tid >> 5;
#pragma unroll
            for (int rr = 0; rr < 8; ++rr) {
                int mi = mbase + rr * 8;
                As[ki][mi] = A[(size_t)(m0 + mi) * lda + k0 + ki];
            }
        }
        {
            int ni = tid & 63;
            int kbase = tid >> 6;
            int nn = n0 + ni;
#pragma unroll
            for (int rr = 0; rr < 8; ++rr) {
                int ki = kbase + rr * 4;
                Ws[ki][ni] = (nn < N) ? W[(size_t)(k0 + ki) * N + nn] : 0.f;
            }
        }
        __syncthreads();
#pragma unroll
        for (int kk = 0; kk < BK; ++kk) {
            float4 a4 = *(const float4*)&As[kk][ty * 4];
            float4 b4 = *(const float4*)&Ws[kk][tx * 4];
            float av[4] = {a4.x, a4.y, a4.z, a4.w};
            float bv[4] = {b4.x, b4.y, b4.z, b4.w};
#pragma unroll
            for (int a = 0; a < 4; ++a)
#pragma unroll
                for (int b = 0; b < 4; ++b)
                    acc[a][b] = fmaf(av[a], bv[b], acc[a][b]);
        }
        __syncthreads();
    }
#pragma unroll
    for (int a = 0; a < 4; ++a) {
        int m = m0 + ty * 4 + a;
#pragma unroll
        for (int b = 0; b < 4; ++b) {
            int n = n0 + tx * 4 + b;
            if (n >= N) continue;
            float val = acc[a][b];
            if (EPI == 2) val = tanhf(val);
            else if (EPI == 4) val = expf(-expf(aux0[n] + val));
            C[(size_t)m * N + n] = val;
        }
    }
}

// ---------------------------------------------------------------------------
// mix5: fused MFMA einsum + mix epilogue. For each f in 0..4:
//   m_f = tmp[:, f*32:(f+1)*32] @ w2[f]  (K=32, one MFMA K-step)
//   x_f = x + xx*(maa_f + m_f)
// tmp is bf16 [M][160]; w2t is bf16 [5][192][32] ([N][K] per f).
// 4 waves/block, each wave 32 rows; no LDS (w2t is L2-resident).
// outputs: xw fp32 (decay path), xk/xv/xr/xg bf16 (MFMA projection inputs)
// ---------------------------------------------------------------------------
__global__ __launch_bounds__(256) void mix5_kernel(
    const float* __restrict__ x, const float* __restrict__ xx,
    const unsigned short* __restrict__ tmp_bf,
    const unsigned short* __restrict__ w2t,
    const float* __restrict__ maa_w, const float* __restrict__ maa_k,
    const float* __restrict__ maa_v, const float* __restrict__ maa_r,
    const float* __restrict__ maa_g,
    float* __restrict__ xw, unsigned short* __restrict__ xr,
    unsigned short* __restrict__ xk, unsigned short* __restrict__ xv,
    unsigned short* __restrict__ xg) {
    const int tid = threadIdx.x;
    const int wid = tid >> 6, lane = tid & 63;
    const int llo = lane & 15, lhi = lane >> 4;
    const int mb = blockIdx.x * 128 + wid * 32;

    // A-frags: lane holds tmp[mb+mf*16+llo][f*32 + lhi*8 .. +8]
    short8 af[5][2];
#pragma unroll
    for (int f = 0; f < 5; ++f)
#pragma unroll
        for (int mf = 0; mf < 2; ++mf)
            af[f][mf] = *(const short8*)&tmp_bf[(size_t)(mb + mf * 16 + llo) * 160 + f * 32 + lhi * 8];

#pragma unroll
    for (int nf = 0; nf < 12; ++nf) {
        int n = nf * 16 + llo;
        f32x4 acc[5][2];
#pragma unroll
        for (int f = 0; f < 5; ++f)
#pragma unroll
            for (int mf = 0; mf < 2; ++mf) {
                f32x4 z = {0.f, 0.f, 0.f, 0.f};
                acc[f][mf] = z;
            }
#pragma unroll
        for (int f = 0; f < 5; ++f) {
            short8 bq = *(const short8*)&w2t[((size_t)f * Cq + n) * 32 + lhi * 8];
            acc[f][0] = __builtin_amdgcn_mfma_f32_16x16x32_bf16(af[f][0], bq, acc[f][0], 0, 0, 0);
            acc[f][1] = __builtin_amdgcn_mfma_f32_16x16x32_bf16(af[f][1], bq, acc[f][1], 0, 0, 0);
        }
        float mw = maa_w[n], mk = maa_k[n], mv = maa_v[n], mr = maa_r[n], mg = maa_g[n];
#pragma unroll
        for (int mf = 0; mf < 2; ++mf)
#pragma unroll
            for (int r = 0; r < 4; ++r) {
                int m = mb + mf * 16 + lhi * 4 + r;
                size_t g = (size_t)m * Cq + n;
                float xv_ = x[g], xxv = xx[g];
                xw[g] = fmaf(xxv, mw + acc[0][mf][r], xv_);
                xk[g] = f2bf(fmaf(xxv, mk + acc[1][mf][r], xv_));
                xv[g] = f2bf(fmaf(xxv, mv + acc[2][mf][r], xv_));
                xr[g] = f2bf(fmaf(xxv, mr + acc[3][mf][r], xv_));
                xg[g] = f2bf(fmaf(xxv, mg + acc[4][mf][r], xv_));
            }
    }
}

// ---------------------------------------------------------------------------
// WKV6 chunked scan: lane = slot*8+i, 8 heads/wave
// ---------------------------------------------------------------------------
__global__ __launch_bounds__(64) void wkv_pass1_kernel(
    const float* __restrict__ k, const float* __restrict__ v,
    const float* __restrict__ d,
    float* __restrict__ Dbuf, float* __restrict__ Cbuf) {
    int chunk = blockIdx.x, hg = blockIdx.y, b = blockIdx.z;
    int lane = threadIdx.x;
    int slot = lane >> 3, i = lane & 7;
    int cbase = hg * 64;
    size_t gbase = ((size_t)b * Tq + (size_t)chunk * CLq) * Cq + cbase;
    __shared__ float ks[TSq][64], vs[TSq][64], ds[TSq][64];
    float S[8], D[8];
#pragma unroll
    for (int j = 0; j < 8; ++j) { S[j] = 0.f; D[j] = 1.f; }
    for (int t0 = 0; t0 < CLq; t0 += TSq) {
        int f = lane & 15, r4 = lane >> 4;
#pragma unroll
        for (int p = 0; p < 8; ++p) {
            int row = r4 + p * 4;
            size_t g = gbase + (size_t)(t0 + row) * Cq + f * 4;
            *(float4*)&ks[row][f * 4] = *(const float4*)&k[g];
            *(float4*)&vs[row][f * 4] = *(const float4*)&v[g];
            *(float4*)&ds[row][f * 4] = *(const float4*)&d[g];
        }
        __syncthreads();
#pragma unroll 8
        for (int t = 0; t < TSq; ++t) {
            float vv = vs[t][lane];
            float4 ka = *(const float4*)&ks[t][slot * 8];
            float4 kb = *(const float4*)&ks[t][slot * 8 + 4];
            float4 da = *(const float4*)&ds[t][slot * 8];
            float4 db = *(const float4*)&ds[t][slot * 8 + 4];
            float kk[8] = {ka.x, ka.y, ka.z, ka.w, kb.x, kb.y, kb.z, kb.w};
            float dd[8] = {da.x, da.y, da.z, da.w, db.x, db.y, db.z, db.w};
#pragma unroll
            for (int j = 0; j < 8; ++j) {
                float kv = kk[j] * vv;
                S[j] = fmaf(dd[j], S[j], kv);
                D[j] *= dd[j];
            }
        }
        __syncthreads();
    }
    size_t dbase = (((size_t)b * NCHq + chunk) * NHq + hg * 8) * 8;
    Dbuf[dbase + lane] = D[i];
    size_t cb = (((size_t)b * NCHq + chunk) * NHq + (hg * 8 + slot)) * 64 + i;
#pragma unroll
    for (int j = 0; j < 8; ++j) Cbuf[cb + j * 8] = S[j];
}

__global__ __launch_bounds__(64) void wkv_pass2_kernel(
    const float* __restrict__ Dbuf, const float* __restrict__ Cbuf,
    float* __restrict__ Sbuf) {
    int bh = blockIdx.x;
    int lane = threadIdx.x;
    int j = lane >> 3, i = lane & 7;
    int b = bh / NHq, h = bh - b * NHq;
    float S = 0.f;
    size_t stride = (size_t)NHq * 64;
    size_t base = ((size_t)b * NCHq * NHq + h) * 64 + j * 8 + i;
    size_t dstride = (size_t)NHq * 8;
    size_t dbase = ((size_t)b * NCHq * NHq + h) * 8 + j;
#pragma unroll 4
    for (int c = 0; c < NCHq; ++c) {
        Sbuf[base + c * stride] = S;
        float D = Dbuf[dbase + c * dstride];
        float C = Cbuf[base + c * stride];
        S = fmaf(D, S, C);
    }
}

__global__ __launch_bounds__(64) void wkv_pass3_kernel(
    const float* __restrict__ r, const float* __restrict__ k,
    const float* __restrict__ v, const float* __restrict__ d,
    const float* __restrict__ u, const float* __restrict__ Sbuf,
    float* __restrict__ y) {
    int chunk = blockIdx.x, hg = blockIdx.y, b = blockIdx.z;
    int lane = threadIdx.x;
    int slot = lane >> 3, i = lane & 7;
    int h = hg * 8 + slot;
    int cbase = hg * 64;
    size_t gbase = ((size_t)b * Tq + (size_t)chunk * CLq) * Cq + cbase;
    __shared__ float rs[TSq][64], ks[TSq][64], vs[TSq][64], ds[TSq][64];
    float S[8], uu[8];
    size_t sb = (((size_t)b * NCHq + chunk) * NHq + h) * 64 + i;
#pragma unroll
    for (int j = 0; j < 8; ++j) {
        S[j] = Sbuf[sb + j * 8];
        uu[j] = u[h * 8 + j];
    }
    for (int t0 = 0; t0 < CLq; t0 += TSq) {
        int f = lane & 15, r4 = lane >> 4;
#pragma unroll
        for (int p = 0; p < 8; ++p) {
            int row = r4 + p * 4;
            size_t g = gbase + (size_t)(t0 + row) * Cq + f * 4;
            *(float4*)&rs[row][f * 4] = *(const float4*)&r[g];
            *(float4*)&ks[row][f * 4] = *(const float4*)&k[g];
            *(float4*)&vs[row][f * 4] = *(const float4*)&v[g];
            *(float4*)&ds[row][f * 4] = *(const float4*)&d[g];
        }
        __syncthreads();
#pragma unroll 8
        for (int t = 0; t < TSq; ++t) {
            float vv = vs[t][lane];
            float4 ra = *(const float4*)&rs[t][slot * 8];
            float4 rb = *(const float4*)&rs[t][slot * 8 + 4];
            float4 ka = *(const float4*)&ks[t][slot * 8];
            float4 kb = *(const float4*)&ks[t][slot * 8 + 4];
            float4 da = *(const float4*)&ds[t][slot * 8];
            float4 db = *(const float4*)&ds[t][slot * 8 + 4];
            float rr[8] = {ra.x, ra.y, ra.z, ra.w, rb.x, rb.y, rb.z, rb.w};
            float kk[8] = {ka.x, ka.y, ka.z, ka.w, kb.x, kb.y, kb.z, kb.w};
            float dd[8] = {da.x, da.y, da.z, da.w, db.x, db.y, db.z, db.w};
            float yv = 0.f;
#pragma unroll
            for (int j = 0; j < 8; ++j) {
                float kv = kk[j] * vv;
                yv = fmaf(rr[j], fmaf(uu[j], kv, S[j]), yv);
                S[j] = fmaf(dd[j], S[j], kv);
            }
            y[gbase + (size_t)(t0 + t) * Cq + lane] = yv;
        }
        __syncthreads();
    }
}

// ---------------------------------------------------------------------------
// LayerNorm + gate -> bf16 output (feeds Wo MFMA GEMM)
// ---------------------------------------------------------------------------
__global__ __launch_bounds__(256) void ln_gate_kernel(
    const float* __restrict__ y, const float* __restrict__ g,
    const float* __restrict__ ln_g, const float* __restrict__ ln_b,
    unsigned short* __restrict__ out) {
    int row = blockIdx.x * 4 + (threadIdx.x >> 6);
    int lane = threadIdx.x & 63;
    const float* yr = y + (size_t)row * Cq;
    float a0 = yr[lane], a1 = yr[lane + 64], a2 = yr[lane + 128];
    float s = a0 + a1 + a2;
    float ss = a0 * a0 + a1 * a1 + a2 * a2;
#pragma unroll
    for (int m = 1; m < 64; m <<= 1) {
        s += __shfl_xor(s, m);
        ss += __shfl_xor(ss, m);
    }
    float mu = s * (1.f / 192.f);
    float var = ss * (1.f / 192.f) - mu * mu;
    float rstd = rsqrtf(var + 1e-5f);
    const float* gr = g + (size_t)row * Cq;
    unsigned short* orow = out + (size_t)row * Cq;
#pragma unroll
    for (int q = 0; q < 3; ++q) {
        int cc = lane + q * 64;
        float yn = (yr[cc] - mu) * rstd * ln_g[cc] + ln_b[cc];
        orow[cc] = f2bf(yn * gr[cc]);
    }
}

// ---------------------------------------------------------------------------
extern "C" void kernel_launch(void* const* d_in, const int* in_sizes, int n_in,
                              void* d_out, int out_size, void* d_ws, size_t ws_size,
                              hipStream_t stream) {
    const float* x        = (const float*)d_in[0];
    const float* maa_x    = (const float*)d_in[1];
    const float* maa_w    = (const float*)d_in[2];
    const float* maa_k    = (const float*)d_in[3];
    const float* maa_v    = (const float*)d_in[4];
    const float* maa_r    = (const float*)d_in[5];
    const float* maa_g    = (const float*)d_in[6];
    const float* maa_w1   = (const float*)d_in[7];
    const float* maa_w2   = (const float*)d_in[8];
    const float* decay_w1 = (const float*)d_in[9];
    const float* decay_w2 = (const float*)d_in[10];
    const float* sdecay   = (const float*)d_in[11];
    const float* u        = (const float*)d_in[12];
    const float* Wr       = (const float*)d_in[13];
    const float* Wk       = (const float*)d_in[14];
    const float* Wv       = (const float*)d_in[15];
    const float* Wgp      = (const float*)d_in[16];
    const float* Wo       = (const float*)d_in[17];
    const float* ln_g     = (const float*)d_in[18];
    const float* ln_b     = (const float*)d_in[19];
    const float* w_lp     = (const float*)d_in[20];
    const float* w_hd     = (const float*)d_in[21];
    const float* w_vd     = (const float*)d_in[22];
    const float* w_cd     = (const float*)d_in[23];
    const float* theta    = (const float*)d_in[24];
    float* out = (float*)d_out;

    const size_t BIG = (size_t)Mq * Cq;          // 6,291,456 floats
    float* ws = (float*)d_ws;
    // bf16 weight regions packed into the first 331,776-float slot
    unsigned short* Wgt_conv = (unsigned short*)ws;            // 192*1728
    unsigned short* Wt_maa = Wgt_conv + (size_t)Cq * 1728;     // 160*192
    unsigned short* Wt_r = Wt_maa + 160 * Cq;
    unsigned short* Wt_k = Wt_r + Cq * Cq;
    unsigned short* Wt_v = Wt_k + Cq * Cq;
    unsigned short* Wt_g = Wt_v + Cq * Cq;
    unsigned short* Wt_o = Wt_g + Cq * Cq;
    unsigned short* w2t  = Wt_o + Cq * Cq;                     // 5*192*32
    float* tmp  = ws + 331776;                  // M*160 (bf16 uses half)
    float* wtmp = tmp + (size_t)Mq * 160;       // M*64 fp32
    float* buf0 = wtmp + (size_t)Mq * 64;
    float* buf1 = buf0 + BIG;
    float* buf2 = buf1 + BIG;
    float* buf3 = buf2 + BIG;
    float* buf4 = buf3 + BIG;
    float* buf5 = buf4 + BIG;

    // tmp region: bf16 tmp lives at the start; WKV scratch + gate_b follow
    // after mix5 has consumed it (Dbuf starts past the bf16 tmp: M*160 ushort
    // = M*80 float).
    unsigned short* tmp_bf = (unsigned short*)tmp;
    float* Dbuf = tmp + (size_t)Mq * 80;
    float* Cbuf = Dbuf + (size_t)Bq * NCHq * NHq * 8;
    float* Sbuf = Cbuf + (size_t)Bq * NCHq * NHq * 64;
    unsigned short* gate_b = (unsigned short*)(Sbuf + (size_t)Bq * NCHq * NHq * 64);

    // bf16 staging buffers overlaid on dead fp32 windows
    unsigned short* x_bf  = (unsigned short*)buf2;             // until conv done
    unsigned short* xxx_b = (unsigned short*)(buf2 + BIG / 2); // until maa done
    unsigned short* xv_b  = x_bf;                              // mix5 .. v-proj
    unsigned short* xg_b  = xxx_b;                             // mix5 .. g-proj
    unsigned short* xr_b  = (unsigned short*)buf5;             // mix5 .. r-proj
    unsigned short* xk_b  = (unsigned short*)(buf5 + BIG / 2); // mix5 .. k-proj

    dim3 blk(256);
    dim3 mg(Mq / GBM, 3);        // MFMA gemms: N=192 or 160 -> 3 col-blocks
    dim3 ew(Mq * Cq / 4 / 256);  // elementwise cvt grids

    // 1) weight prep (bf16, [N][K])
    prep_weights_kernel<<<dim3(144), blk, 0, stream>>>(w_lp, w_hd, w_vd, w_cd, theta, Wgt_conv);
    wtrans_kernel<<<dim3(120), blk, 0, stream>>>(maa_w1, Wt_maa, Cq, 160);
    wtrans_kernel<<<dim3(144), blk, 0, stream>>>(Wr, Wt_r, Cq, Cq);
    wtrans_kernel<<<dim3(144), blk, 0, stream>>>(Wk, Wt_k, Cq, Cq);
    wtrans_kernel<<<dim3(144), blk, 0, stream>>>(Wv, Wt_v, Cq, Cq);
    wtrans_kernel<<<dim3(144), blk, 0, stream>>>(Wgp, Wt_g, Cq, Cq);
    wtrans_kernel<<<dim3(144), blk, 0, stream>>>(Wo, Wt_o, Cq, Cq);
    w2t_kernel<<<dim3(120), blk, 0, stream>>>(maa_w2, w2t);
    // 2) x -> bf16; conv as MFMA implicit GEMM -> xx = conv(x) - x (buf0)
    cvt_bf16_kernel<<<ew, blk, 0, stream>>>(x, x_bf);
    mgemm_kernel<1, 1, 0><<<mg, blk, 0, stream>>>(x_bf, Wgt_conv, buf0, Cq, 1728, x);
    // 3) xxx = bf16(x + xx*maa_x); tmp_bf = bf16(tanh(xxx @ maa_w1)) [M,160]
    xxx_kernel<<<ew, blk, 0, stream>>>(x, buf0, maa_x, xxx_b);
    mgemm_kernel<3, 2, 1><<<mg, blk, 0, stream>>>(xxx_b, Wt_maa, tmp_bf, 160, Cq, nullptr);
    // 4) fused mixes: xw fp32 (buf1), xr/xk/xv/xg bf16
    mix5_kernel<<<dim3(Mq / 128), blk, 0, stream>>>(
        x, buf0, tmp_bf, w2t, maa_w, maa_k, maa_v, maa_r, maa_g,
        buf1, xr_b, xk_b, xv_b, xg_b);
    // 5) MFMA projections (order matters for buffer overlays)
    mgemm_kernel<3, 0, 0><<<mg, blk, 0, stream>>>(xv_b, Wt_v, buf3, Cq, Cq, nullptr); // v
    mgemm_kernel<3, 3, 0><<<mg, blk, 0, stream>>>(xg_b, Wt_g, buf4, Cq, Cq, nullptr); // g=silu
    mgemm_kernel<3, 0, 0><<<mg, blk, 0, stream>>>(xr_b, Wt_r, buf0, Cq, Cq, nullptr); // r
    mgemm_kernel<3, 0, 0><<<mg, blk, 0, stream>>>(xk_b, Wt_k, buf2, Cq, Cq, nullptr); // k
    // 6) decay (fp32): wtmp = tanh(xw@w1); d = exp(-exp(sd + wtmp@w2)) -> buf5
    gemm_kernel<2><<<dim3(Mq / BM, 1), blk, 0, stream>>>(buf1, decay_w1, wtmp, Mq, 64, Cq, Cq, nullptr);
    gemm_kernel<4><<<dim3(Mq / BM, 3), blk, 0, stream>>>(wtmp, decay_w2, buf5, Mq, Cq, 64, 64, sdecay);
    // 7) WKV chunked scan: r=buf0 k=buf2 v=buf3 d=buf5 -> y=buf1
    wkv_pass1_kernel<<<dim3(NCHq, 3, Bq), dim3(64), 0, stream>>>(buf2, buf3, buf5, Dbuf, Cbuf);
    wkv_pass2_kernel<<<dim3(Bq * NHq), dim3(64), 0, stream>>>(Dbuf, Cbuf, Sbuf);
    wkv_pass3_kernel<<<dim3(NCHq, 3, Bq), dim3(64), 0, stream>>>(buf0, buf2, buf3, buf5, u, Sbuf, buf1);
    // 8) LN + gate -> bf16
    ln_gate_kernel<<<dim3(Mq / 4), blk, 0, stream>>>(buf1, buf4, ln_g, ln_b, gate_b);
    // 9) output projection (MFMA)
    mgemm_kernel<3, 0, 0><<<mg, blk, 0, stream>>>(gate_b, Wt_o, out, Cq, Cq, nullptr);
}

// Round 7
// 428.841 us; speedup vs baseline: 4.0198x; 1.0521x over previous
//
#include <hip/hip_runtime.h>
#include <hip/hip_bf16.h>

#define Bq 8
#define Tq 4096
#define Cq 192
#define NHq 24
#define HSq 8
#define Mq (Bq * Tq)   // 32768

#define CLq 64              // WKV chunk length
#define NCHq (Tq / CLq)     // 64 chunks
#define TSq 32              // LDS tile steps inside a chunk

typedef short short8 __attribute__((ext_vector_type(8)));
typedef float f32x4 __attribute__((ext_vector_type(4)));

__device__ __forceinline__ unsigned short f2bf(float f) {
    union { float f; unsigned u; } v; v.f = f;
    unsigned u = v.u;
    return (unsigned short)((u + 0x7FFFu + ((u >> 16) & 1u)) >> 16);
}

// ---------------------------------------------------------------------------
// fold lp/hd/vd/cd convs into one effective 3x3 kernel, emitted directly as
// bf16 GEMM weight Wt[cout][k] with k = tap*192 + cin (i.e. [N][K] layout)
// ---------------------------------------------------------------------------
__global__ void prep_weights_kernel(const float* __restrict__ w_lp,
                                    const float* __restrict__ w_hd,
                                    const float* __restrict__ w_vd,
                                    const float* __restrict__ w_cd,
                                    const float* __restrict__ theta,
                                    unsigned short* __restrict__ Wg) {
    int idx = blockIdx.x * 256 + threadIdx.x;   // cout*192 + cin
    if (idx >= Cq * Cq) return;
    int cout = idx / Cq, cin = idx - cout * Cq;
    float t9[9];
#pragma unroll
    for (int t = 0; t < 9; ++t) t9[t] = 0.f;
    float lp = w_lp[idx];
    t9[1] += lp; t9[3] += lp; t9[5] += lp; t9[7] += lp; t9[4] -= 4.f * lp;
    float h0 = w_hd[idx * 3 + 0], h1 = w_hd[idx * 3 + 1], h2 = w_hd[idx * 3 + 2];
    t9[0] += h0; t9[3] += h1; t9[6] += h2;
    t9[2] -= h0; t9[5] -= h1; t9[8] -= h2;
    float v0 = w_vd[idx * 3 + 0], v1 = w_vd[idx * 3 + 1], v2 = w_vd[idx * 3 + 2];
    t9[0] += v0; t9[1] += v1; t9[2] += v2;
    t9[6] -= v0; t9[7] -= v1; t9[8] -= v2;
    float sum = 0.f;
#pragma unroll
    for (int t = 0; t < 9; ++t) {
        float cdv = w_cd[idx * 9 + t];
        t9[t] += cdv; sum += cdv;
    }
    t9[4] -= theta[0] * sum;
#pragma unroll
    for (int t = 0; t < 9; ++t)
        Wg[(size_t)cout * 1728 + t * Cq + cin] = f2bf(t9[t]);
}

// ---------------------------------------------------------------------------
// transpose+convert fp32 W[K][N] -> bf16 Wt[N][K]
// ---------------------------------------------------------------------------
__global__ void wtrans_kernel(const float* __restrict__ W,
                              unsigned short* __restrict__ Wt, int K, int N) {
    int idx = blockIdx.x * 256 + threadIdx.x;
    if (idx >= N * K) return;
    int n = idx / K, k = idx - n * K;
    Wt[idx] = f2bf(W[(size_t)k * N + n]);
}

// w2 [5][32][192] fp32 -> w2t [5][192][32] bf16
__global__ void w2t_kernel(const float* __restrict__ w2,
                           unsigned short* __restrict__ w2t) {
    int idx = blockIdx.x * 256 + threadIdx.x;  // f*192*32 + n*32 + k
    if (idx >= 5 * 192 * 32) return;
    int f = idx / (192 * 32), rem = idx - f * 192 * 32;
    int n = rem >> 5, k = rem & 31;
    w2t[idx] = f2bf(w2[(size_t)(f * 32 + k) * Cq + n]);
}

// elementwise fp32 -> bf16 (4 elems/thread)
__global__ __launch_bounds__(256) void cvt_bf16_kernel(
    const float* __restrict__ src, unsigned short* __restrict__ dst) {
    size_t g = ((size_t)blockIdx.x * 256 + threadIdx.x) * 4;
    float4 v = *(const float4*)&src[g];
    ushort4 o = make_ushort4(f2bf(v.x), f2bf(v.y), f2bf(v.z), f2bf(v.w));
    *(ushort4*)&dst[g] = o;
}

// xxx = bf16(x + xx*maa_x)
__global__ __launch_bounds__(256) void xxx_kernel(
    const float* __restrict__ x, const float* __restrict__ xx,
    const float* __restrict__ maa_x, unsigned short* __restrict__ out) {
    size_t g = ((size_t)blockIdx.x * 256 + threadIdx.x) * 4;
    int c = (int)(g % Cq);
    float4 xv = *(const float4*)&x[g];
    float4 dv = *(const float4*)&xx[g];
    float4 mv = *(const float4*)&maa_x[c];
    ushort4 o = make_ushort4(f2bf(fmaf(dv.x, mv.x, xv.x)), f2bf(fmaf(dv.y, mv.y, xv.y)),
                             f2bf(fmaf(dv.z, mv.z, xv.z)), f2bf(fmaf(dv.w, mv.w, xv.w)));
    *(ushort4*)&out[g] = o;
}

// ---------------------------------------------------------------------------
// bf16 MFMA GEMM: C[M][N] = A @ Wt^T, Wt is bf16 [N][K].
// ALOAD: 3 = plain bf16 A [M][K]; 1 = conv implicit-gemm from bf16 x [M][192]
// EPI:   0 none, 1 = acc - aux0[m*N+n], 2 = tanh, 3 = silu
// OBF16: 1 = store bf16 instead of fp32
// tile 128x64xK64, 4 waves, each wave 32 rows x 64 cols (2x4 16x16 frags)
// LDS XOR-swizzled (byte ^= (row&7)<<4) for conflict-free ds_read_b128 (G4)
// ---------------------------------------------------------------------------
#define GBM 128
#define GBN 64
#define GBK 64

template <int ALOAD, int EPI, int OBF16>
__global__ __launch_bounds__(256) void mgemm_kernel(
    const unsigned short* __restrict__ Asrc,
    const unsigned short* __restrict__ Wt,
    void* __restrict__ Cv, int N, int K,
    const float* __restrict__ aux0) {
    __shared__ unsigned char lds[(GBM + GBN) * GBK * 2];
    unsigned char* Alds = lds;
    unsigned char* Blds = lds + GBM * GBK * 2;
    float* C = (float*)Cv;
    unsigned short* Cb = (unsigned short*)Cv;

    const int tid = threadIdx.x;
    const int wid = tid >> 6, lane = tid & 63;
    const int llo = lane & 15, lhi = lane >> 4;
    const int m0 = blockIdx.x * GBM, n0 = blockIdx.y * GBN;

    f32x4 acc[2][4];
#pragma unroll
    for (int a = 0; a < 2; ++a)
#pragma unroll
        for (int b = 0; b < 4; ++b) {
            f32x4 z = {0.f, 0.f, 0.f, 0.f};
            acc[a][b] = z;
        }

    for (int k0 = 0; k0 < K; k0 += GBK) {
        __syncthreads();
        // ---- stage A (128x64 bf16): 1024 chunks of 8 elems, 4/thread ----
#pragma unroll
        for (int rep = 0; rep < 4; ++rep) {
            int c = tid + rep * 256;
            int row = c >> 3, kseg = c & 7;
            int k = k0 + kseg * 8;
            int m = m0 + row;
            short8 val = {0, 0, 0, 0, 0, 0, 0, 0};
            if (ALOAD == 3) {
                val = *(const short8*)&Asrc[(size_t)m * K + k];
            } else {  // conv implicit gemm from x_bf
                int tap = k / Cq, cin = k - tap * Cq;
                int t3 = tap / 3;
                int dy = t3 - 1, dx = tap - t3 * 3 - 1;
                int bb = m >> 12, pos = m & 4095;
                int hh = (pos >> 6) + dy, wc = (pos & 63) + dx;
                if (((unsigned)hh < 64u) && ((unsigned)wc < 64u)) {
                    size_t g = ((size_t)(bb << 12) + (hh << 6) + wc) * Cq + cin;
                    val = *(const short8*)&Asrc[g];
                }
            }
            *(short8*)(Alds + row * 128 + ((kseg * 16) ^ ((row & 7) << 4))) = val;
        }
        // ---- stage B (64x64 bf16 from Wt[n][k]): 512 chunks, 2/thread ----
#pragma unroll
        for (int rep = 0; rep < 2; ++rep) {
            int c = tid + rep * 256;
            int row = c >> 3, kseg = c & 7;
            int n = n0 + row;
            short8 val = {0, 0, 0, 0, 0, 0, 0, 0};
            if (n < N) val = *(const short8*)&Wt[(size_t)n * K + k0 + kseg * 8];
            *(short8*)(Blds + row * 128 + ((kseg * 16) ^ ((row & 7) << 4))) = val;
        }
        __syncthreads();
        // ---- MFMA: 2 k-chunks of 32, 2x4 frags ----
#pragma unroll
        for (int kc = 0; kc < 2; ++kc) {
            int kb = kc * 64 + lhi * 16;
            short8 af[2], bq[4];
#pragma unroll
            for (int mf = 0; mf < 2; ++mf) {
                int row = wid * 32 + mf * 16 + llo;
                af[mf] = *(const short8*)(Alds + row * 128 + (kb ^ ((row & 7) << 4)));
            }
#pragma unroll
            for (int nf = 0; nf < 4; ++nf) {
                int row = nf * 16 + llo;
                bq[nf] = *(const short8*)(Blds + row * 128 + (kb ^ ((row & 7) << 4)));
            }
#pragma unroll
            for (int mf = 0; mf < 2; ++mf)
#pragma unroll
                for (int nf = 0; nf < 4; ++nf)
                    acc[mf][nf] = __builtin_amdgcn_mfma_f32_16x16x32_bf16(
                        af[mf], bq[nf], acc[mf][nf], 0, 0, 0);
        }
    }
    // ---- epilogue: C/D layout col=lane&15, row=(lane>>4)*4+reg ----
#pragma unroll
    for (int mf = 0; mf < 2; ++mf) {
#pragma unroll
        for (int nf = 0; nf < 4; ++nf) {
            int n = n0 + nf * 16 + llo;
            if (n >= N) continue;
#pragma unroll
            for (int r = 0; r < 4; ++r) {
                int m = m0 + wid * 32 + mf * 16 + lhi * 4 + r;
                float val = acc[mf][nf][r];
                if (EPI == 1) val -= aux0[(size_t)m * N + n];
                else if (EPI == 2) val = tanhf(val);
                else if (EPI == 3) val = val / (1.f + expf(-val));
                if (OBF16) Cb[(size_t)m * N + n] = f2bf(val);
                else C[(size_t)m * N + n] = val;
            }
        }
    }
}

// ---------------------------------------------------------------------------
// fp32 tiled GEMM (kept for the numerically-sensitive decay path)
// EPI: 2 = tanh, 4 = exp(-exp(sd[n]+acc)) (aux0=spatial_decay)
// ---------------------------------------------------------------------------
#define BM 64
#define BN 64
#define BK 32
#define PADq 4

template <int EPI>
__global__ __launch_bounds__(256) void gemm_kernel(
    const float* __restrict__ A, const float* __restrict__ W,
    float* __restrict__ C, int M, int N, int K, int lda,
    const float* __restrict__ aux0) {
    __shared__ float As[BK][BM + PADq];
    __shared__ float Ws[BK][BN + PADq];
    int m0 = blockIdx.x * BM;
    int n0 = blockIdx.y * BN;
    int tid = threadIdx.x;
    int ty = tid >> 4, tx = tid & 15;
    float acc[4][4];
#pragma unroll
    for (int a = 0; a < 4; ++a)
#pragma unroll
        for (int b = 0; b < 4; ++b) acc[a][b] = 0.f;

    for (int k0 = 0; k0 < K; k0 += BK) {
        {
            int ki = tid & 31;
            int mbase = tid >> 5;
#pragma unroll
            for (int rr = 0; rr < 8; ++rr) {
                int mi = mbase + rr * 8;
                As[ki][mi] = A[(size_t)(m0 + mi) * lda + k0 + ki];
            }
        }
        {
            int ni = tid & 63;
            int kbase = tid >> 6;
            int nn = n0 + ni;
#pragma unroll
            for (int rr = 0; rr < 8; ++rr) {
                int ki = kbase + rr * 4;
                Ws[ki][ni] = (nn < N) ? W[(size_t)(k0 + ki) * N + nn] : 0.f;
            }
        }
        __syncthreads();
#pragma unroll
        for (int kk = 0; kk < BK; ++kk) {
            float4 a4 = *(const float4*)&As[kk][ty * 4];
            float4 b4 = *(const float4*)&Ws[kk][tx * 4];
            float av[4] = {a4.x, a4.y, a4.z, a4.w};
            float bv[4] = {b4.x, b4.y, b4.z, b4.w};
#pragma unroll
            for (int a = 0; a < 4; ++a)
#pragma unroll
                for (int b = 0; b < 4; ++b)
                    acc[a][b] = fmaf(av[a], bv[b], acc[a][b]);
        }
        __syncthreads();
    }
#pragma unroll
    for (int a = 0; a < 4; ++a) {
        int m = m0 + ty * 4 + a;
#pragma unroll
        for (int b = 0; b < 4; ++b) {
            int n = n0 + tx * 4 + b;
            if (n >= N) continue;
            float val = acc[a][b];
            if (EPI == 2) val = tanhf(val);
            else if (EPI == 4) val = expf(-expf(aux0[n] + val));
            C[(size_t)m * N + n] = val;
        }
    }
}

// ---------------------------------------------------------------------------
// mix5 (operand-swapped): m_f computed as mfma(A=w2t frag, B=tmp frag) so
// D[i][j] = m_f[n=i][m=j]: lane owns 4 CONSECUTIVE COLUMNS (n) of one row (m)
// -> vectorized float4/ushort4 epilogue I/O.
// grid (Mq/128, 3): block = 128 rows x 64 cols; 4 waves, wave = 32 rows.
// outputs: xw fp32 (decay path), xk/xv/xr/xg bf16 (MFMA projection inputs)
// ---------------------------------------------------------------------------
__global__ __launch_bounds__(256) void mix5_kernel(
    const float* __restrict__ x, const float* __restrict__ xx,
    const unsigned short* __restrict__ tmp_bf,
    const unsigned short* __restrict__ w2t,
    const float* __restrict__ maa_w, const float* __restrict__ maa_k,
    const float* __restrict__ maa_v, const float* __restrict__ maa_r,
    const float* __restrict__ maa_g,
    float* __restrict__ xw, unsigned short* __restrict__ xr,
    unsigned short* __restrict__ xk, unsigned short* __restrict__ xv,
    unsigned short* __restrict__ xg) {
    const int tid = threadIdx.x;
    const int wid = tid >> 6, lane = tid & 63;
    const int llo = lane & 15, lhi = lane >> 4;
    const int mb = blockIdx.x * 128 + wid * 32;   // 32 rows per wave
    const int nb = blockIdx.y * 64;               // 64 cols per block

    // A-frags (w2t, rows = n): lane holds w2t[f][nb+nf*16+llo][lhi*8..+8]
    short8 aw[5][4];
#pragma unroll
    for (int f = 0; f < 5; ++f)
#pragma unroll
        for (int nf = 0; nf < 4; ++nf)
            aw[f][nf] = *(const short8*)&w2t[((size_t)f * Cq + nb + nf * 16 + llo) * 32 + lhi * 8];

#pragma unroll
    for (int sub = 0; sub < 2; ++sub) {
        // B-frags (tmp, cols = m): lane holds tmp[mb+sub*16+llo][f*32+lhi*8..]
        short8 bt[5];
        {
            const unsigned short* trow = &tmp_bf[(size_t)(mb + sub * 16 + llo) * 160 + lhi * 8];
#pragma unroll
            for (int f = 0; f < 5; ++f) bt[f] = *(const short8*)&trow[f * 32];
        }
#pragma unroll
        for (int nf = 0; nf < 4; ++nf) {
            f32x4 acc[5];
#pragma unroll
            for (int f = 0; f < 5; ++f) {
                f32x4 z = {0.f, 0.f, 0.f, 0.f};
                acc[f] = __builtin_amdgcn_mfma_f32_16x16x32_bf16(aw[f][nf], bt[f], z, 0, 0, 0);
            }
            // D layout: col(lane&15)=m offset, row(lhi*4+r)=n offset
            int m = mb + sub * 16 + llo;
            int n0 = nb + nf * 16 + lhi * 4;
            size_t g = (size_t)m * Cq + n0;
            float4 xv4 = *(const float4*)&x[g];
            float4 xx4 = *(const float4*)&xx[g];
            float4 mw4 = *(const float4*)&maa_w[n0];
            float4 mk4 = *(const float4*)&maa_k[n0];
            float4 mv4 = *(const float4*)&maa_v[n0];
            float4 mr4 = *(const float4*)&maa_r[n0];
            float4 mg4 = *(const float4*)&maa_g[n0];
            float xvv[4] = {xv4.x, xv4.y, xv4.z, xv4.w};
            float xxv[4] = {xx4.x, xx4.y, xx4.z, xx4.w};
            float mwv[4] = {mw4.x, mw4.y, mw4.z, mw4.w};
            float mkv[4] = {mk4.x, mk4.y, mk4.z, mk4.w};
            float mvv[4] = {mv4.x, mv4.y, mv4.z, mv4.w};
            float mrv[4] = {mr4.x, mr4.y, mr4.z, mr4.w};
            float mgv[4] = {mg4.x, mg4.y, mg4.z, mg4.w};
            float4 ow;
            ushort4 ok, ov, orr, og;
            float* owp = (float*)&ow;
            unsigned short* okp = (unsigned short*)&ok;
            unsigned short* ovp = (unsigned short*)&ov;
            unsigned short* orp = (unsigned short*)&orr;
            unsigned short* ogp = (unsigned short*)&og;
#pragma unroll
            for (int r = 0; r < 4; ++r) {
                owp[r] = fmaf(xxv[r], mwv[r] + acc[0][r], xvv[r]);
                okp[r] = f2bf(fmaf(xxv[r], mkv[r] + acc[1][r], xvv[r]));
                ovp[r] = f2bf(fmaf(xxv[r], mvv[r] + acc[2][r], xvv[r]));
                orp[r] = f2bf(fmaf(xxv[r], mrv[r] + acc[3][r], xvv[r]));
                ogp[r] = f2bf(fmaf(xxv[r], mgv[r] + acc[4][r], xvv[r]));
            }
            *(float4*)&xw[g] = ow;
            *(ushort4*)&xk[g] = ok;
            *(ushort4*)&xv[g] = ov;
            *(ushort4*)&xr[g] = orr;
            *(ushort4*)&xg[g] = og;
        }
    }
}

// ---------------------------------------------------------------------------
// WKV6 chunked scan: lane = slot*8+i, 8 heads/wave
// ---------------------------------------------------------------------------
__global__ __launch_bounds__(64) void wkv_pass1_kernel(
    const float* __restrict__ k, const float* __restrict__ v,
    const float* __restrict__ d,
    float* __restrict__ Dbuf, float* __restrict__ Cbuf) {
    int chunk = blockIdx.x, hg = blockIdx.y, b = blockIdx.z;
    int lane = threadIdx.x;
    int slot = lane >> 3, i = lane & 7;
    int cbase = hg * 64;
    size_t gbase = ((size_t)b * Tq + (size_t)chunk * CLq) * Cq + cbase;
    __shared__ float ks[TSq][64], vs[TSq][64], ds[TSq][64];
    float S[8], D[8];
#pragma unroll
    for (int j = 0; j < 8; ++j) { S[j] = 0.f; D[j] = 1.f; }
    for (int t0 = 0; t0 < CLq; t0 += TSq) {
        int f = lane & 15, r4 = lane >> 4;
#pragma unroll
        for (int p = 0; p < 8; ++p) {
            int row = r4 + p * 4;
            size_t g = gbase + (size_t)(t0 + row) * Cq + f * 4;
            *(float4*)&ks[row][f * 4] = *(const float4*)&k[g];
            *(float4*)&vs[row][f * 4] = *(const float4*)&v[g];
            *(float4*)&ds[row][f * 4] = *(const float4*)&d[g];
        }
        __syncthreads();
#pragma unroll 8
        for (int t = 0; t < TSq; ++t) {
            float vv = vs[t][lane];
            float4 ka = *(const float4*)&ks[t][slot * 8];
            float4 kb = *(const float4*)&ks[t][slot * 8 + 4];
            float4 da = *(const float4*)&ds[t][slot * 8];
            float4 db = *(const float4*)&ds[t][slot * 8 + 4];
            float kk[8] = {ka.x, ka.y, ka.z, ka.w, kb.x, kb.y, kb.z, kb.w};
            float dd[8] = {da.x, da.y, da.z, da.w, db.x, db.y, db.z, db.w};
#pragma unroll
            for (int j = 0; j < 8; ++j) {
                float kv = kk[j] * vv;
                S[j] = fmaf(dd[j], S[j], kv);
                D[j] *= dd[j];
            }
        }
        __syncthreads();
    }
    size_t dbase = (((size_t)b * NCHq + chunk) * NHq + hg * 8) * 8;
    Dbuf[dbase + lane] = D[i];
    size_t cb = (((size_t)b * NCHq + chunk) * NHq + (hg * 8 + slot)) * 64 + i;
#pragma unroll
    for (int j = 0; j < 8; ++j) Cbuf[cb + j * 8] = S[j];
}

__global__ __launch_bounds__(64) void wkv_pass2_kernel(
    const float* __restrict__ Dbuf, const float* __restrict__ Cbuf,
    float* __restrict__ Sbuf) {
    int bh = blockIdx.x;
    int lane = threadIdx.x;
    int j = lane >> 3, i = lane & 7;
    int b = bh / NHq, h = bh - b * NHq;
    float S = 0.f;
    size_t stride = (size_t)NHq * 64;
    size_t base = ((size_t)b * NCHq * NHq + h) * 64 + j * 8 + i;
    size_t dstride = (size_t)NHq * 8;
    size_t dbase = ((size_t)b * NCHq * NHq + h) * 8 + j;
#pragma unroll 4
    for (int c = 0; c < NCHq; ++c) {
        Sbuf[base + c * stride] = S;
        float D = Dbuf[dbase + c * dstride];
        float C = Cbuf[base + c * stride];
        S = fmaf(D, S, C);
    }
}

__global__ __launch_bounds__(64) void wkv_pass3_kernel(
    const float* __restrict__ r, const float* __restrict__ k,
    const float* __restrict__ v, const float* __restrict__ d,
    const float* __restrict__ u, const float* __restrict__ Sbuf,
    float* __restrict__ y) {
    int chunk = blockIdx.x, hg = blockIdx.y, b = blockIdx.z;
    int lane = threadIdx.x;
    int slot = lane >> 3, i = lane & 7;
    int h = hg * 8 + slot;
    int cbase = hg * 64;
    size_t gbase = ((size_t)b * Tq + (size_t)chunk * CLq) * Cq + cbase;
    __shared__ float rs[TSq][64], ks[TSq][64], vs[TSq][64], ds[TSq][64];
    float S[8], uu[8];
    size_t sb = (((size_t)b * NCHq + chunk) * NHq + h) * 64 + i;
#pragma unroll
    for (int j = 0; j < 8; ++j) {
        S[j] = Sbuf[sb + j * 8];
        uu[j] = u[h * 8 + j];
    }
    for (int t0 = 0; t0 < CLq; t0 += TSq) {
        int f = lane & 15, r4 = lane >> 4;
#pragma unroll
        for (int p = 0; p < 8; ++p) {
            int row = r4 + p * 4;
            size_t g = gbase + (size_t)(t0 + row) * Cq + f * 4;
            *(float4*)&rs[row][f * 4] = *(const float4*)&r[g];
            *(float4*)&ks[row][f * 4] = *(const float4*)&k[g];
            *(float4*)&vs[row][f * 4] = *(const float4*)&v[g];
            *(float4*)&ds[row][f * 4] = *(const float4*)&d[g];
        }
        __syncthreads();
#pragma unroll 8
        for (int t = 0; t < TSq; ++t) {
            float vv = vs[t][lane];
            float4 ra = *(const float4*)&rs[t][slot * 8];
            float4 rb = *(const float4*)&rs[t][slot * 8 + 4];
            float4 ka = *(const float4*)&ks[t][slot * 8];
            float4 kb = *(const float4*)&ks[t][slot * 8 + 4];
            float4 da = *(const float4*)&ds[t][slot * 8];
            float4 db = *(const float4*)&ds[t][slot * 8 + 4];
            float rr[8] = {ra.x, ra.y, ra.z, ra.w, rb.x, rb.y, rb.z, rb.w};
            float kk[8] = {ka.x, ka.y, ka.z, ka.w, kb.x, kb.y, kb.z, kb.w};
            float dd[8] = {da.x, da.y, da.z, da.w, db.x, db.y, db.z, db.w};
            float yv = 0.f;
#pragma unroll
            for (int j = 0; j < 8; ++j) {
                float kv = kk[j] * vv;
                yv = fmaf(rr[j], fmaf(uu[j], kv, S[j]), yv);
                S[j] = fmaf(dd[j], S[j], kv);
            }
            y[gbase + (size_t)(t0 + t) * Cq + lane] = yv;
        }
        __syncthreads();
    }
}

// ---------------------------------------------------------------------------
// LayerNorm + gate -> bf16 output (feeds Wo MFMA GEMM)
// ---------------------------------------------------------------------------
__global__ __launch_bounds__(256) void ln_gate_kernel(
    const float* __restrict__ y, const float* __restrict__ g,
    const float* __restrict__ ln_g, const float* __restrict__ ln_b,
    unsigned short* __restrict__ out) {
    int row = blockIdx.x * 4 + (threadIdx.x >> 6);
    int lane = threadIdx.x & 63;
    const float* yr = y + (size_t)row * Cq;
    float a0 = yr[lane], a1 = yr[lane + 64], a2 = yr[lane + 128];
    float s = a0 + a1 + a2;
    float ss = a0 * a0 + a1 * a1 + a2 * a2;
#pragma unroll
    for (int m = 1; m < 64; m <<= 1) {
        s += __shfl_xor(s, m);
        ss += __shfl_xor(ss, m);
    }
    float mu = s * (1.f / 192.f);
    float var = ss * (1.f / 192.f) - mu * mu;
    float rstd = rsqrtf(var + 1e-5f);
    const float* gr = g + (size_t)row * Cq;
    unsigned short* orow = out + (size_t)row * Cq;
#pragma unroll
    for (int q = 0; q < 3; ++q) {
        int cc = lane + q * 64;
        float yn = (yr[cc] - mu) * rstd * ln_g[cc] + ln_b[cc];
        orow[cc] = f2bf(yn * gr[cc]);
    }
}

// ---------------------------------------------------------------------------
extern "C" void kernel_launch(void* const* d_in, const int* in_sizes, int n_in,
                              void* d_out, int out_size, void* d_ws, size_t ws_size,
                              hipStream_t stream) {
    const float* x        = (const float*)d_in[0];
    const float* maa_x    = (const float*)d_in[1];
    const float* maa_w    = (const float*)d_in[2];
    const float* maa_k    = (const float*)d_in[3];
    const float* maa_v    = (const float*)d_in[4];
    const float* maa_r    = (const float*)d_in[5];
    const float* maa_g    = (const float*)d_in[6];
    const float* maa_w1   = (const float*)d_in[7];
    const float* maa_w2   = (const float*)d_in[8];
    const float* decay_w1 = (const float*)d_in[9];
    const float* decay_w2 = (const float*)d_in[10];
    const float* sdecay   = (const float*)d_in[11];
    const float* u        = (const float*)d_in[12];
    const float* Wr       = (const float*)d_in[13];
    const float* Wk       = (const float*)d_in[14];
    const float* Wv       = (const float*)d_in[15];
    const float* Wgp      = (const float*)d_in[16];
    const float* Wo       = (const float*)d_in[17];
    const float* ln_g     = (const float*)d_in[18];
    const float* ln_b     = (const float*)d_in[19];
    const float* w_lp     = (const float*)d_in[20];
    const float* w_hd     = (const float*)d_in[21];
    const float* w_vd     = (const float*)d_in[22];
    const float* w_cd     = (const float*)d_in[23];
    const float* theta    = (const float*)d_in[24];
    float* out = (float*)d_out;

    const size_t BIG = (size_t)Mq * Cq;          // 6,291,456 floats
    float* ws = (float*)d_ws;
    // bf16 weight regions packed into the first 331,776-float slot
    unsigned short* Wgt_conv = (unsigned short*)ws;            // 192*1728
    unsigned short* Wt_maa = Wgt_conv + (size_t)Cq * 1728;     // 160*192
    unsigned short* Wt_r = Wt_maa + 160 * Cq;
    unsigned short* Wt_k = Wt_r + Cq * Cq;
    unsigned short* Wt_v = Wt_k + Cq * Cq;
    unsigned short* Wt_g = Wt_v + Cq * Cq;
    unsigned short* Wt_o = Wt_g + Cq * Cq;
    unsigned short* w2t  = Wt_o + Cq * Cq;                     // 5*192*32
    float* tmp  = ws + 331776;                  // M*160 (bf16 uses half)
    float* wtmp = tmp + (size_t)Mq * 160;       // M*64 fp32
    float* buf0 = wtmp + (size_t)Mq * 64;
    float* buf1 = buf0 + BIG;
    float* buf2 = buf1 + BIG;
    float* buf3 = buf2 + BIG;
    float* buf4 = buf3 + BIG;
    float* buf5 = buf4 + BIG;

    // tmp region: bf16 tmp lives at the start; WKV scratch + gate_b follow
    unsigned short* tmp_bf = (unsigned short*)tmp;
    float* Dbuf = tmp + (size_t)Mq * 80;
    float* Cbuf = Dbuf + (size_t)Bq * NCHq * NHq * 8;
    float* Sbuf = Cbuf + (size_t)Bq * NCHq * NHq * 64;
    unsigned short* gate_b = (unsigned short*)(Sbuf + (size_t)Bq * NCHq * NHq * 64);

    // bf16 staging buffers overlaid on dead fp32 windows
    unsigned short* x_bf  = (unsigned short*)buf2;             // until conv done
    unsigned short* xxx_b = (unsigned short*)(buf2 + BIG / 2); // until maa done
    unsigned short* xv_b  = x_bf;                              // mix5 .. v-proj
    unsigned short* xg_b  = xxx_b;                             // mix5 .. g-proj
    unsigned short* xr_b  = (unsigned short*)buf5;             // mix5 .. r-proj
    unsigned short* xk_b  = (unsigned short*)(buf5 + BIG / 2); // mix5 .. k-proj

    dim3 blk(256);
    dim3 mg(Mq / GBM, 3);        // MFMA gemms: N=192 or 160 -> 3 col-blocks
    dim3 ew(Mq * Cq / 4 / 256);  // elementwise cvt grids

    // 1) weight prep (bf16, [N][K])
    prep_weights_kernel<<<dim3(144), blk, 0, stream>>>(w_lp, w_hd, w_vd, w_cd, theta, Wgt_conv);
    wtrans_kernel<<<dim3(120), blk, 0, stream>>>(maa_w1, Wt_maa, Cq, 160);
    wtrans_kernel<<<dim3(144), blk, 0, stream>>>(Wr, Wt_r, Cq, Cq);
    wtrans_kernel<<<dim3(144), blk, 0, stream>>>(Wk, Wt_k, Cq, Cq);
    wtrans_kernel<<<dim3(144), blk, 0, stream>>>(Wv, Wt_v, Cq, Cq);
    wtrans_kernel<<<dim3(144), blk, 0, stream>>>(Wgp, Wt_g, Cq, Cq);
    wtrans_kernel<<<dim3(144), blk, 0, stream>>>(Wo, Wt_o, Cq, Cq);
    w2t_kernel<<<dim3(120), blk, 0, stream>>>(maa_w2, w2t);
    // 2) x -> bf16; conv as MFMA implicit GEMM -> xx = conv(x) - x (buf0)
    cvt_bf16_kernel<<<ew, blk, 0, stream>>>(x, x_bf);
    mgemm_kernel<1, 1, 0><<<mg, blk, 0, stream>>>(x_bf, Wgt_conv, buf0, Cq, 1728, x);
    // 3) xxx = bf16(x + xx*maa_x); tmp_bf = bf16(tanh(xxx @ maa_w1)) [M,160]
    xxx_kernel<<<ew, blk, 0, stream>>>(x, buf0, maa_x, xxx_b);
    mgemm_kernel<3, 2, 1><<<mg, blk, 0, stream>>>(xxx_b, Wt_maa, tmp_bf, 160, Cq, nullptr);
    // 4) fused mixes (operand-swapped, vectorized): xw fp32, xr/xk/xv/xg bf16
    mix5_kernel<<<dim3(Mq / 128, 3), blk, 0, stream>>>(
        x, buf0, tmp_bf, w2t, maa_w, maa_k, maa_v, maa_r, maa_g,
        buf1, xr_b, xk_b, xv_b, xg_b);
    // 5) MFMA projections (order matters for buffer overlays)
    mgemm_kernel<3, 0, 0><<<mg, blk, 0, stream>>>(xv_b, Wt_v, buf3, Cq, Cq, nullptr); // v
    mgemm_kernel<3, 3, 0><<<mg, blk, 0, stream>>>(xg_b, Wt_g, buf4, Cq, Cq, nullptr); // g=silu
    mgemm_kernel<3, 0, 0><<<mg, blk, 0, stream>>>(xr_b, Wt_r, buf0, Cq, Cq, nullptr); // r
    mgemm_kernel<3, 0, 0><<<mg, blk, 0, stream>>>(xk_b, Wt_k, buf2, Cq, Cq, nullptr); // k
    // 6) decay (fp32): wtmp = tanh(xw@w1); d = exp(-exp(sd + wtmp@w2)) -> buf5
    gemm_kernel<2><<<dim3(Mq / BM, 1), blk, 0, stream>>>(buf1, decay_w1, wtmp, Mq, 64, Cq, Cq, nullptr);
    gemm_kernel<4><<<dim3(Mq / BM, 3), blk, 0, stream>>>(wtmp, decay_w2, buf5, Mq, Cq, 64, 64, sdecay);
    // 7) WKV chunked scan: r=buf0 k=buf2 v=buf3 d=buf5 -> y=buf1
    wkv_pass1_kernel<<<dim3(NCHq, 3, Bq), dim3(64), 0, stream>>>(buf2, buf3, buf5, Dbuf, Cbuf);
    wkv_pass2_kernel<<<dim3(Bq * NHq), dim3(64), 0, stream>>>(Dbuf, Cbuf, Sbuf);
    wkv_pass3_kernel<<<dim3(NCHq, 3, Bq), dim3(64), 0, stream>>>(buf0, buf2, buf3, buf5, u, Sbuf, buf1);
    // 8) LN + gate -> bf16
    ln_gate_kernel<<<dim3(Mq / 4), blk, 0, stream>>>(buf1, buf4, ln_g, ln_b, gate_b);
    // 9) output projection (MFMA)
    mgemm_kernel<3, 0, 0><<<mg, blk, 0, stream>>>(gate_b, Wt_o, out, Cq, Cq, nullptr);
}

// Round 8
// 388.406 us; speedup vs baseline: 4.4383x; 1.1041x over previous
//
#include <hip/hip_runtime.h>
#include <hip/hip_bf16.h>

#define Bq 8
#define Tq 4096
#define Cq 192
#define NHq 24
#define HSq 8
#define Mq (Bq * Tq)   // 32768

#define CLq 64              // WKV chunk length
#define NCHq (Tq / CLq)     // 64 chunks
#define TSq 32              // LDS tile steps inside a chunk

typedef short short8 __attribute__((ext_vector_type(8)));
typedef float f32x4 __attribute__((ext_vector_type(4)));

__device__ __forceinline__ unsigned short f2bf(float f) {
    union { float f; unsigned u; } v; v.f = f;
    unsigned u = v.u;
    return (unsigned short)((u + 0x7FFFu + ((u >> 16) & 1u)) >> 16);
}

// ---------------------------------------------------------------------------
// fold lp/hd/vd/cd convs into one effective 3x3 kernel, emitted directly as
// bf16 GEMM weight Wt[cout][k] with k = tap*192 + cin (i.e. [N][K] layout)
// ---------------------------------------------------------------------------
__global__ void prep_weights_kernel(const float* __restrict__ w_lp,
                                    const float* __restrict__ w_hd,
                                    const float* __restrict__ w_vd,
                                    const float* __restrict__ w_cd,
                                    const float* __restrict__ theta,
                                    unsigned short* __restrict__ Wg) {
    int idx = blockIdx.x * 256 + threadIdx.x;   // cout*192 + cin
    if (idx >= Cq * Cq) return;
    int cout = idx / Cq, cin = idx - cout * Cq;
    float t9[9];
#pragma unroll
    for (int t = 0; t < 9; ++t) t9[t] = 0.f;
    float lp = w_lp[idx];
    t9[1] += lp; t9[3] += lp; t9[5] += lp; t9[7] += lp; t9[4] -= 4.f * lp;
    float h0 = w_hd[idx * 3 + 0], h1 = w_hd[idx * 3 + 1], h2 = w_hd[idx * 3 + 2];
    t9[0] += h0; t9[3] += h1; t9[6] += h2;
    t9[2] -= h0; t9[5] -= h1; t9[8] -= h2;
    float v0 = w_vd[idx * 3 + 0], v1 = w_vd[idx * 3 + 1], v2 = w_vd[idx * 3 + 2];
    t9[0] += v0; t9[1] += v1; t9[2] += v2;
    t9[6] -= v0; t9[7] -= v1; t9[8] -= v2;
    float sum = 0.f;
#pragma unroll
    for (int t = 0; t < 9; ++t) {
        float cdv = w_cd[idx * 9 + t];
        t9[t] += cdv; sum += cdv;
    }
    t9[4] -= theta[0] * sum;
#pragma unroll
    for (int t = 0; t < 9; ++t)
        Wg[(size_t)cout * 1728 + t * Cq + cin] = f2bf(t9[t]);
}

// ---------------------------------------------------------------------------
// transpose+convert fp32 W[K][N] -> bf16 Wt[N][K]
// ---------------------------------------------------------------------------
__global__ void wtrans_kernel(const float* __restrict__ W,
                              unsigned short* __restrict__ Wt, int K, int N) {
    int idx = blockIdx.x * 256 + threadIdx.x;
    if (idx >= N * K) return;
    int n = idx / K, k = idx - n * K;
    Wt[idx] = f2bf(W[(size_t)k * N + n]);
}

// w2 [5][32][192] fp32 -> w2t [5][192][32] bf16
__global__ void w2t_kernel(const float* __restrict__ w2,
                           unsigned short* __restrict__ w2t) {
    int idx = blockIdx.x * 256 + threadIdx.x;  // f*192*32 + n*32 + k
    if (idx >= 5 * 192 * 32) return;
    int f = idx / (192 * 32), rem = idx - f * 192 * 32;
    int n = rem >> 5, k = rem & 31;
    w2t[idx] = f2bf(w2[(size_t)(f * 32 + k) * Cq + n]);
}

// ---------------------------------------------------------------------------
// x [B,4096,192] fp32 -> x_halo [B][66][66][192] bf16, zero borders
// cell = bb*4356 + hy*66 + hx  (matches conv staging addressing)
// ---------------------------------------------------------------------------
__global__ __launch_bounds__(256) void halo_kernel(
    const float* __restrict__ x, unsigned short* __restrict__ xh) {
    int idx = blockIdx.x * 256 + threadIdx.x;   // 8*66*66*48 threads
    int c4 = (idx % 48) * 4;
    int cell = idx / 48;
    int hx = cell % 66;
    int rest = cell / 66;
    int hy = rest % 66;
    int bb = rest / 66;
    ushort4 o = make_ushort4(0, 0, 0, 0);
    if (hy >= 1 && hy <= 64 && hx >= 1 && hx <= 64) {
        size_t g = ((size_t)(bb << 12) + (hy - 1) * 64 + (hx - 1)) * Cq + c4;
        float4 v = *(const float4*)&x[g];
        o = make_ushort4(f2bf(v.x), f2bf(v.y), f2bf(v.z), f2bf(v.w));
    }
    *(ushort4*)&xh[(size_t)cell * Cq + c4] = o;
}

// xxx = bf16(x + xx*maa_x)
__global__ __launch_bounds__(256) void xxx_kernel(
    const float* __restrict__ x, const float* __restrict__ xx,
    const float* __restrict__ maa_x, unsigned short* __restrict__ out) {
    size_t g = ((size_t)blockIdx.x * 256 + threadIdx.x) * 4;
    int c = (int)(g % Cq);
    float4 xv = *(const float4*)&x[g];
    float4 dv = *(const float4*)&xx[g];
    float4 mv = *(const float4*)&maa_x[c];
    ushort4 o = make_ushort4(f2bf(fmaf(dv.x, mv.x, xv.x)), f2bf(fmaf(dv.y, mv.y, xv.y)),
                             f2bf(fmaf(dv.z, mv.z, xv.z)), f2bf(fmaf(dv.w, mv.w, xv.w)));
    *(ushort4*)&out[g] = o;
}

// ---------------------------------------------------------------------------
// bf16 MFMA GEMM: C[M][N] = A @ Wt^T, Wt is bf16 [N][K].
// ALOAD: 3 = plain bf16 A [M][K]
//        1 = conv implicit-gemm from x_halo [8][66][66][192] bf16
//            (GBK=64 divides 192 -> each K-step lies in ONE tap; tap math is
//             loop-uniform, staging is a branch-free linear load)
// EPI:   0 none, 1 = acc - aux0[m*N+n], 2 = tanh, 3 = silu,
//        4 = exp(-exp(aux0[n] + acc))   (aux0 = spatial_decay)
// OBF16: 1 = store bf16 instead of fp32
// tile 128x64xK64, 4 waves, each wave 32 rows x 64 cols (2x4 16x16 frags)
// LDS XOR-swizzled (byte ^= (row&7)<<4) for conflict-free ds_read_b128 (G4)
// ---------------------------------------------------------------------------
#define GBM 128
#define GBN 64
#define GBK 64

template <int ALOAD, int EPI, int OBF16>
__global__ __launch_bounds__(256) void mgemm_kernel(
    const unsigned short* __restrict__ Asrc,
    const unsigned short* __restrict__ Wt,
    void* __restrict__ Cv, int N, int K,
    const float* __restrict__ aux0) {
    __shared__ unsigned char lds[(GBM + GBN) * GBK * 2];
    unsigned char* Alds = lds;
    unsigned char* Blds = lds + GBM * GBK * 2;
    float* C = (float*)Cv;
    unsigned short* Cb = (unsigned short*)Cv;

    const int tid = threadIdx.x;
    const int wid = tid >> 6, lane = tid & 63;
    const int llo = lane & 15, lhi = lane >> 4;
    const int m0 = blockIdx.x * GBM, n0 = blockIdx.y * GBN;

    f32x4 acc[2][4];
#pragma unroll
    for (int a = 0; a < 2; ++a)
#pragma unroll
        for (int b = 0; b < 4; ++b) {
            f32x4 z = {0.f, 0.f, 0.f, 0.f};
            acc[a][b] = z;
        }

    for (int k0 = 0; k0 < K; k0 += GBK) {
        __syncthreads();
        // ---- stage A (128x64 bf16): 1024 chunks of 8 elems, 4/thread ----
#pragma unroll
        for (int rep = 0; rep < 4; ++rep) {
            int c = tid + rep * 256;
            int row = c >> 3, kseg = c & 7;
            int m = m0 + row;
            short8 val;
            if (ALOAD == 3) {
                val = *(const short8*)&Asrc[(size_t)m * K + k0 + kseg * 8];
            } else {  // conv from halo: tap uniform per K-step, branch-free
                int tap = k0 / Cq;
                int cinb = k0 - tap * Cq;
                int t3 = tap / 3;
                int bb = m >> 12, pos = m & 4095;
                int hy = (pos >> 6) + t3;
                int hx = (pos & 63) + tap - t3 * 3;
                size_t g = ((size_t)bb * 4356 + hy * 66 + hx) * Cq + cinb + kseg * 8;
                val = *(const short8*)&Asrc[g];
            }
            *(short8*)(Alds + row * 128 + ((kseg * 16) ^ ((row & 7) << 4))) = val;
        }
        // ---- stage B (64x64 bf16 from Wt[n][k]): 512 chunks, 2/thread ----
#pragma unroll
        for (int rep = 0; rep < 2; ++rep) {
            int c = tid + rep * 256;
            int row = c >> 3, kseg = c & 7;
            int n = n0 + row;
            short8 val = {0, 0, 0, 0, 0, 0, 0, 0};
            if (n < N) val = *(const short8*)&Wt[(size_t)n * K + k0 + kseg * 8];
            *(short8*)(Blds + row * 128 + ((kseg * 16) ^ ((row & 7) << 4))) = val;
        }
        __syncthreads();
        // ---- MFMA: 2 k-chunks of 32, 2x4 frags ----
#pragma unroll
        for (int kc = 0; kc < 2; ++kc) {
            int kb = kc * 64 + lhi * 16;
            short8 af[2], bq[4];
#pragma unroll
            for (int mf = 0; mf < 2; ++mf) {
                int row = wid * 32 + mf * 16 + llo;
                af[mf] = *(const short8*)(Alds + row * 128 + (kb ^ ((row & 7) << 4)));
            }
#pragma unroll
            for (int nf = 0; nf < 4; ++nf) {
                int row = nf * 16 + llo;
                bq[nf] = *(const short8*)(Blds + row * 128 + (kb ^ ((row & 7) << 4)));
            }
#pragma unroll
            for (int mf = 0; mf < 2; ++mf)
#pragma unroll
                for (int nf = 0; nf < 4; ++nf)
                    acc[mf][nf] = __builtin_amdgcn_mfma_f32_16x16x32_bf16(
                        af[mf], bq[nf], acc[mf][nf], 0, 0, 0);
        }
    }
    // ---- epilogue: C/D layout col=lane&15, row=(lane>>4)*4+reg ----
#pragma unroll
    for (int mf = 0; mf < 2; ++mf) {
#pragma unroll
        for (int nf = 0; nf < 4; ++nf) {
            int n = n0 + nf * 16 + llo;
            if (n >= N) continue;
#pragma unroll
            for (int r = 0; r < 4; ++r) {
                int m = m0 + wid * 32 + mf * 16 + lhi * 4 + r;
                float val = acc[mf][nf][r];
                if (EPI == 1) val -= aux0[(size_t)m * N + n];
                else if (EPI == 2) val = tanhf(val);
                else if (EPI == 3) val = val / (1.f + expf(-val));
                else if (EPI == 4) val = expf(-expf(aux0[n] + val));
                if (OBF16) Cb[(size_t)m * N + n] = f2bf(val);
                else C[(size_t)m * N + n] = val;
            }
        }
    }
}

// ---------------------------------------------------------------------------
// mix5 (operand-swapped): m_f computed as mfma(A=w2t frag, B=tmp frag) so
// lane owns 4 CONSECUTIVE COLUMNS (n) of one row (m) -> vectorized I/O.
// grid (Mq/128, 3). outputs: xw bf16 (decay path), xk/xv/xr/xg bf16.
// ---------------------------------------------------------------------------
__global__ __launch_bounds__(256) void mix5_kernel(
    const float* __restrict__ x, const float* __restrict__ xx,
    const unsigned short* __restrict__ tmp_bf,
    const unsigned short* __restrict__ w2t,
    const float* __restrict__ maa_w, const float* __restrict__ maa_k,
    const float* __restrict__ maa_v, const float* __restrict__ maa_r,
    const float* __restrict__ maa_g,
    unsigned short* __restrict__ xw, unsigned short* __restrict__ xr,
    unsigned short* __restrict__ xk, unsigned short* __restrict__ xv,
    unsigned short* __restrict__ xg) {
    const int tid = threadIdx.x;
    const int wid = tid >> 6, lane = tid & 63;
    const int llo = lane & 15, lhi = lane >> 4;
    const int mb = blockIdx.x * 128 + wid * 32;   // 32 rows per wave
    const int nb = blockIdx.y * 64;               // 64 cols per block

    short8 aw[5][4];
#pragma unroll
    for (int f = 0; f < 5; ++f)
#pragma unroll
        for (int nf = 0; nf < 4; ++nf)
            aw[f][nf] = *(const short8*)&w2t[((size_t)f * Cq + nb + nf * 16 + llo) * 32 + lhi * 8];

#pragma unroll
    for (int sub = 0; sub < 2; ++sub) {
        short8 bt[5];
        {
            const unsigned short* trow = &tmp_bf[(size_t)(mb + sub * 16 + llo) * 160 + lhi * 8];
#pragma unroll
            for (int f = 0; f < 5; ++f) bt[f] = *(const short8*)&trow[f * 32];
        }
#pragma unroll
        for (int nf = 0; nf < 4; ++nf) {
            f32x4 acc[5];
#pragma unroll
            for (int f = 0; f < 5; ++f) {
                f32x4 z = {0.f, 0.f, 0.f, 0.f};
                acc[f] = __builtin_amdgcn_mfma_f32_16x16x32_bf16(aw[f][nf], bt[f], z, 0, 0, 0);
            }
            int m = mb + sub * 16 + llo;
            int n0 = nb + nf * 16 + lhi * 4;
            size_t g = (size_t)m * Cq + n0;
            float4 xv4 = *(const float4*)&x[g];
            float4 xx4 = *(const float4*)&xx[g];
            float4 mw4 = *(const float4*)&maa_w[n0];
            float4 mk4 = *(const float4*)&maa_k[n0];
            float4 mv4 = *(const float4*)&maa_v[n0];
            float4 mr4 = *(const float4*)&maa_r[n0];
            float4 mg4 = *(const float4*)&maa_g[n0];
            float xvv[4] = {xv4.x, xv4.y, xv4.z, xv4.w};
            float xxv[4] = {xx4.x, xx4.y, xx4.z, xx4.w};
            float mwv[4] = {mw4.x, mw4.y, mw4.z, mw4.w};
            float mkv[4] = {mk4.x, mk4.y, mk4.z, mk4.w};
            float mvv[4] = {mv4.x, mv4.y, mv4.z, mv4.w};
            float mrv[4] = {mr4.x, mr4.y, mr4.z, mr4.w};
            float mgv[4] = {mg4.x, mg4.y, mg4.z, mg4.w};
            ushort4 ow, ok, ov, orr, og;
            unsigned short* owp = (unsigned short*)&ow;
            unsigned short* okp = (unsigned short*)&ok;
            unsigned short* ovp = (unsigned short*)&ov;
            unsigned short* orp = (unsigned short*)&orr;
            unsigned short* ogp = (unsigned short*)&og;
#pragma unroll
            for (int r = 0; r < 4; ++r) {
                owp[r] = f2bf(fmaf(xxv[r], mwv[r] + acc[0][r], xvv[r]));
                okp[r] = f2bf(fmaf(xxv[r], mkv[r] + acc[1][r], xvv[r]));
                ovp[r] = f2bf(fmaf(xxv[r], mvv[r] + acc[2][r], xvv[r]));
                orp[r] = f2bf(fmaf(xxv[r], mrv[r] + acc[3][r], xvv[r]));
                ogp[r] = f2bf(fmaf(xxv[r], mgv[r] + acc[4][r], xvv[r]));
            }
            *(ushort4*)&xw[g] = ow;
            *(ushort4*)&xk[g] = ok;
            *(ushort4*)&xv[g] = ov;
            *(ushort4*)&xr[g] = orr;
            *(ushort4*)&xg[g] = og;
        }
    }
}

// ---------------------------------------------------------------------------
// WKV6 chunked scan: lane = slot*8+i, 8 heads/wave
// ---------------------------------------------------------------------------
__global__ __launch_bounds__(64) void wkv_pass1_kernel(
    const float* __restrict__ k, const float* __restrict__ v,
    const float* __restrict__ d,
    float* __restrict__ Dbuf, float* __restrict__ Cbuf) {
    int chunk = blockIdx.x, hg = blockIdx.y, b = blockIdx.z;
    int lane = threadIdx.x;
    int slot = lane >> 3, i = lane & 7;
    int cbase = hg * 64;
    size_t gbase = ((size_t)b * Tq + (size_t)chunk * CLq) * Cq + cbase;
    __shared__ float ks[TSq][64], vs[TSq][64], ds[TSq][64];
    float S[8], D[8];
#pragma unroll
    for (int j = 0; j < 8; ++j) { S[j] = 0.f; D[j] = 1.f; }
    for (int t0 = 0; t0 < CLq; t0 += TSq) {
        int f = lane & 15, r4 = lane >> 4;
#pragma unroll
        for (int p = 0; p < 8; ++p) {
            int row = r4 + p * 4;
            size_t g = gbase + (size_t)(t0 + row) * Cq + f * 4;
            *(float4*)&ks[row][f * 4] = *(const float4*)&k[g];
            *(float4*)&vs[row][f * 4] = *(const float4*)&v[g];
            *(float4*)&ds[row][f * 4] = *(const float4*)&d[g];
        }
        __syncthreads();
#pragma unroll 8
        for (int t = 0; t < TSq; ++t) {
            float vv = vs[t][lane];
            float4 ka = *(const float4*)&ks[t][slot * 8];
            float4 kb = *(const float4*)&ks[t][slot * 8 + 4];
            float4 da = *(const float4*)&ds[t][slot * 8];
            float4 db = *(const float4*)&ds[t][slot * 8 + 4];
            float kk[8] = {ka.x, ka.y, ka.z, ka.w, kb.x, kb.y, kb.z, kb.w};
            float dd[8] = {da.x, da.y, da.z, da.w, db.x, db.y, db.z, db.w};
#pragma unroll
            for (int j = 0; j < 8; ++j) {
                float kv = kk[j] * vv;
                S[j] = fmaf(dd[j], S[j], kv);
                D[j] *= dd[j];
            }
        }
        __syncthreads();
    }
    size_t dbase = (((size_t)b * NCHq + chunk) * NHq + hg * 8) * 8;
    Dbuf[dbase + lane] = D[i];
    size_t cb = (((size_t)b * NCHq + chunk) * NHq + (hg * 8 + slot)) * 64 + i;
#pragma unroll
    for (int j = 0; j < 8; ++j) Cbuf[cb + j * 8] = S[j];
}

__global__ __launch_bounds__(64) void wkv_pass2_kernel(
    const float* __restrict__ Dbuf, const float* __restrict__ Cbuf,
    float* __restrict__ Sbuf) {
    int bh = blockIdx.x;
    int lane = threadIdx.x;
    int j = lane >> 3, i = lane & 7;
    int b = bh / NHq, h = bh - b * NHq;
    float S = 0.f;
    size_t stride = (size_t)NHq * 64;
    size_t base = ((size_t)b * NCHq * NHq + h) * 64 + j * 8 + i;
    size_t dstride = (size_t)NHq * 8;
    size_t dbase = ((size_t)b * NCHq * NHq + h) * 8 + j;
#pragma unroll 4
    for (int c = 0; c < NCHq; ++c) {
        Sbuf[base + c * stride] = S;
        float D = Dbuf[dbase + c * dstride];
        float C = Cbuf[base + c * stride];
        S = fmaf(D, S, C);
    }
}

__global__ __launch_bounds__(64) void wkv_pass3_kernel(
    const float* __restrict__ r, const float* __restrict__ k,
    const float* __restrict__ v, const float* __restrict__ d,
    const float* __restrict__ u, const float* __restrict__ Sbuf,
    float* __restrict__ y) {
    int chunk = blockIdx.x, hg = blockIdx.y, b = blockIdx.z;
    int lane = threadIdx.x;
    int slot = lane >> 3, i = lane & 7;
    int h = hg * 8 + slot;
    int cbase = hg * 64;
    size_t gbase = ((size_t)b * Tq + (size_t)chunk * CLq) * Cq + cbase;
    __shared__ float rs[TSq][64], ks[TSq][64], vs[TSq][64], ds[TSq][64];
    float S[8], uu[8];
    size_t sb = (((size_t)b * NCHq + chunk) * NHq + h) * 64 + i;
#pragma unroll
    for (int j = 0; j < 8; ++j) {
        S[j] = Sbuf[sb + j * 8];
        uu[j] = u[h * 8 + j];
    }
    for (int t0 = 0; t0 < CLq; t0 += TSq) {
        int f = lane & 15, r4 = lane >> 4;
#pragma unroll
        for (int p = 0; p < 8; ++p) {
            int row = r4 + p * 4;
            size_t g = gbase + (size_t)(t0 + row) * Cq + f * 4;
            *(float4*)&rs[row][f * 4] = *(const float4*)&r[g];
            *(float4*)&ks[row][f * 4] = *(const float4*)&k[g];
            *(float4*)&vs[row][f * 4] = *(const float4*)&v[g];
            *(float4*)&ds[row][f * 4] = *(const float4*)&d[g];
        }
        __syncthreads();
#pragma unroll 8
        for (int t = 0; t < TSq; ++t) {
            float vv = vs[t][lane];
            float4 ra = *(const float4*)&rs[t][slot * 8];
            float4 rb = *(const float4*)&rs[t][slot * 8 + 4];
            float4 ka = *(const float4*)&ks[t][slot * 8];
            float4 kb = *(const float4*)&ks[t][slot * 8 + 4];
            float4 da = *(const float4*)&ds[t][slot * 8];
            float4 db = *(const float4*)&ds[t][slot * 8 + 4];
            float rr[8] = {ra.x, ra.y, ra.z, ra.w, rb.x, rb.y, rb.z, rb.w};
            float kk[8] = {ka.x, ka.y, ka.z, ka.w, kb.x, kb.y, kb.z, kb.w};
            float dd[8] = {da.x, da.y, da.z, da.w, db.x, db.y, db.z, db.w};
            float yv = 0.f;
#pragma unroll
            for (int j = 0; j < 8; ++j) {
                float kv = kk[j] * vv;
                yv = fmaf(rr[j], fmaf(uu[j], kv, S[j]), yv);
                S[j] = fmaf(dd[j], S[j], kv);
            }
            y[gbase + (size_t)(t0 + t) * Cq + lane] = yv;
        }
        __syncthreads();
    }
}

// ---------------------------------------------------------------------------
// LayerNorm + gate -> bf16 output (feeds Wo MFMA GEMM)
// ---------------------------------------------------------------------------
__global__ __launch_bounds__(256) void ln_gate_kernel(
    const float* __restrict__ y, const float* __restrict__ g,
    const float* __restrict__ ln_g, const float* __restrict__ ln_b,
    unsigned short* __restrict__ out) {
    int row = blockIdx.x * 4 + (threadIdx.x >> 6);
    int lane = threadIdx.x & 63;
    const float* yr = y + (size_t)row * Cq;
    float a0 = yr[lane], a1 = yr[lane + 64], a2 = yr[lane + 128];
    float s = a0 + a1 + a2;
    float ss = a0 * a0 + a1 * a1 + a2 * a2;
#pragma unroll
    for (int m = 1; m < 64; m <<= 1) {
        s += __shfl_xor(s, m);
        ss += __shfl_xor(ss, m);
    }
    float mu = s * (1.f / 192.f);
    float var = ss * (1.f / 192.f) - mu * mu;
    float rstd = rsqrtf(var + 1e-5f);
    const float* gr = g + (size_t)row * Cq;
    unsigned short* orow = out + (size_t)row * Cq;
#pragma unroll
    for (int q = 0; q < 3; ++q) {
        int cc = lane + q * 64;
        float yn = (yr[cc] - mu) * rstd * ln_g[cc] + ln_b[cc];
        orow[cc] = f2bf(yn * gr[cc]);
    }
}

// ---------------------------------------------------------------------------
extern "C" void kernel_launch(void* const* d_in, const int* in_sizes, int n_in,
                              void* d_out, int out_size, void* d_ws, size_t ws_size,
                              hipStream_t stream) {
    const float* x        = (const float*)d_in[0];
    const float* maa_x    = (const float*)d_in[1];
    const float* maa_w    = (const float*)d_in[2];
    const float* maa_k    = (const float*)d_in[3];
    const float* maa_v    = (const float*)d_in[4];
    const float* maa_r    = (const float*)d_in[5];
    const float* maa_g    = (const float*)d_in[6];
    const float* maa_w1   = (const float*)d_in[7];
    const float* maa_w2   = (const float*)d_in[8];
    const float* decay_w1 = (const float*)d_in[9];
    const float* decay_w2 = (const float*)d_in[10];
    const float* sdecay   = (const float*)d_in[11];
    const float* u        = (const float*)d_in[12];
    const float* Wr       = (const float*)d_in[13];
    const float* Wk       = (const float*)d_in[14];
    const float* Wv       = (const float*)d_in[15];
    const float* Wgp      = (const float*)d_in[16];
    const float* Wo       = (const float*)d_in[17];
    const float* ln_g     = (const float*)d_in[18];
    const float* ln_b     = (const float*)d_in[19];
    const float* w_lp     = (const float*)d_in[20];
    const float* w_hd     = (const float*)d_in[21];
    const float* w_vd     = (const float*)d_in[22];
    const float* w_cd     = (const float*)d_in[23];
    const float* theta    = (const float*)d_in[24];
    float* out = (float*)d_out;

    const size_t BIG = (size_t)Mq * Cq;          // 6,291,456 floats
    float* ws = (float*)d_ws;
    // bf16 weight regions packed into the first 331,776-float slot
    unsigned short* Wgt_conv = (unsigned short*)ws;            // 192*1728
    unsigned short* Wt_maa = Wgt_conv + (size_t)Cq * 1728;     // 160*192
    unsigned short* Wt_r = Wt_maa + 160 * Cq;
    unsigned short* Wt_k = Wt_r + Cq * Cq;
    unsigned short* Wt_v = Wt_k + Cq * Cq;
    unsigned short* Wt_g = Wt_v + Cq * Cq;
    unsigned short* Wt_o = Wt_g + Cq * Cq;
    unsigned short* w2t  = Wt_o + Cq * Cq;                     // 5*192*32
    unsigned short* Wt_d1 = w2t + 5 * 192 * 32;                // 64*192
    unsigned short* Wt_d2 = Wt_d1 + 64 * Cq;                   // 192*64
    float* tmp  = ws + 331776;                  // M*160 (bf16 uses half)
    float* wtmp = tmp + (size_t)Mq * 160;       // M*64
    float* buf0 = wtmp + (size_t)Mq * 64;
    float* buf1 = buf0 + BIG;
    float* buf2 = buf1 + BIG;
    float* buf3 = buf2 + BIG;
    float* buf4 = buf3 + BIG;
    float* buf5 = buf4 + BIG;

    // tmp region: bf16 tmp at start; WKV scratch + gate_b follow
    unsigned short* tmp_bf = (unsigned short*)tmp;
    float* Dbuf = tmp + (size_t)Mq * 80;
    float* Cbuf = Dbuf + (size_t)Bq * NCHq * NHq * 8;
    float* Sbuf = Cbuf + (size_t)Bq * NCHq * NHq * 64;
    unsigned short* gate_b = (unsigned short*)(Sbuf + (size_t)Bq * NCHq * NHq * 64);

    // overlays:
    // buf1: x_halo (until conv done) -> xw_b (mix5..decay1) -> y (pass3..)
    unsigned short* x_halo = (unsigned short*)buf1;            // 8*66*66*192
    unsigned short* xw_b   = (unsigned short*)buf1;
    unsigned short* xxx_b  = (unsigned short*)(buf2 + BIG / 2); // until maa done
    unsigned short* xv_b   = (unsigned short*)buf2;            // mix5 .. v-proj
    unsigned short* xg_b   = xxx_b;                            // mix5 .. g-proj
    unsigned short* xr_b   = (unsigned short*)buf5;            // mix5 .. r-proj
    unsigned short* xk_b   = (unsigned short*)(buf5 + BIG / 2); // mix5 .. k-proj
    unsigned short* wtmp_b = (unsigned short*)wtmp;            // decay mid [M][64]

    dim3 blk(256);
    dim3 mg(Mq / GBM, 3);        // MFMA gemms: N=192 or 160 -> 3 col-blocks
    dim3 ew(Mq * Cq / 4 / 256);  // elementwise grids

    // 1) weight prep (bf16, [N][K])
    prep_weights_kernel<<<dim3(144), blk, 0, stream>>>(w_lp, w_hd, w_vd, w_cd, theta, Wgt_conv);
    wtrans_kernel<<<dim3(120), blk, 0, stream>>>(maa_w1, Wt_maa, Cq, 160);
    wtrans_kernel<<<dim3(144), blk, 0, stream>>>(Wr, Wt_r, Cq, Cq);
    wtrans_kernel<<<dim3(144), blk, 0, stream>>>(Wk, Wt_k, Cq, Cq);
    wtrans_kernel<<<dim3(144), blk, 0, stream>>>(Wv, Wt_v, Cq, Cq);
    wtrans_kernel<<<dim3(144), blk, 0, stream>>>(Wgp, Wt_g, Cq, Cq);
    wtrans_kernel<<<dim3(144), blk, 0, stream>>>(Wo, Wt_o, Cq, Cq);
    w2t_kernel<<<dim3(120), blk, 0, stream>>>(maa_w2, w2t);
    wtrans_kernel<<<dim3(48), blk, 0, stream>>>(decay_w1, Wt_d1, Cq, 64);
    wtrans_kernel<<<dim3(48), blk, 0, stream>>>(decay_w2, Wt_d2, 64, Cq);
    // 2) halo-pad x; conv as MFMA implicit GEMM -> xx = conv(x) - x (buf0)
    halo_kernel<<<dim3(8 * 66 * 66 * 48 / 256), blk, 0, stream>>>(x, x_halo);
    mgemm_kernel<1, 1, 0><<<mg, blk, 0, stream>>>(x_halo, Wgt_conv, buf0, Cq, 1728, x);
    // 3) xxx = bf16(x + xx*maa_x); tmp_bf = bf16(tanh(xxx @ maa_w1)) [M,160]
    xxx_kernel<<<ew, blk, 0, stream>>>(x, buf0, maa_x, xxx_b);
    mgemm_kernel<3, 2, 1><<<mg, blk, 0, stream>>>(xxx_b, Wt_maa, tmp_bf, 160, Cq, nullptr);
    // 4) fused mixes: all five bf16 (xw_b overwrites dead x_halo in buf1)
    mix5_kernel<<<dim3(Mq / 128, 3), blk, 0, stream>>>(
        x, buf0, tmp_bf, w2t, maa_w, maa_k, maa_v, maa_r, maa_g,
        xw_b, xr_b, xk_b, xv_b, xg_b);
    // 5) MFMA projections (order matters for buffer overlays)
    mgemm_kernel<3, 0, 0><<<mg, blk, 0, stream>>>(xv_b, Wt_v, buf3, Cq, Cq, nullptr); // v
    mgemm_kernel<3, 3, 0><<<mg, blk, 0, stream>>>(xg_b, Wt_g, buf4, Cq, Cq, nullptr); // g=silu
    mgemm_kernel<3, 0, 0><<<mg, blk, 0, stream>>>(xr_b, Wt_r, buf0, Cq, Cq, nullptr); // r
    mgemm_kernel<3, 0, 0><<<mg, blk, 0, stream>>>(xk_b, Wt_k, buf2, Cq, Cq, nullptr); // k
    // 6) decay (bf16 MFMA): wtmp_b = bf16(tanh(xw@w1)); d = exp(-exp(sd+.@w2))
    mgemm_kernel<3, 2, 1><<<dim3(Mq / GBM, 1), blk, 0, stream>>>(xw_b, Wt_d1, wtmp_b, 64, Cq, nullptr);
    mgemm_kernel<3, 4, 0><<<mg, blk, 0, stream>>>(wtmp_b, Wt_d2, buf5, Cq, 64, sdecay);
    // 7) WKV chunked scan: r=buf0 k=buf2 v=buf3 d=buf5 -> y=buf1
    wkv_pass1_kernel<<<dim3(NCHq, 3, Bq), dim3(64), 0, stream>>>(buf2, buf3, buf5, Dbuf, Cbuf);
    wkv_pass2_kernel<<<dim3(Bq * NHq), dim3(64), 0, stream>>>(Dbuf, Cbuf, Sbuf);
    wkv_pass3_kernel<<<dim3(NCHq, 3, Bq), dim3(64), 0, stream>>>(buf0, buf2, buf3, buf5, u, Sbuf, buf1);
    // 8) LN + gate -> bf16
    ln_gate_kernel<<<dim3(Mq / 4), blk, 0, stream>>>(buf1, buf4, ln_g, ln_b, gate_b);
    // 9) output projection (MFMA)
    mgemm_kernel<3, 0, 0><<<mg, blk, 0, stream>>>(gate_b, Wt_o, out, Cq, Cq, nullptr);
}

// Round 9
// 359.729 us; speedup vs baseline: 4.7921x; 1.0797x over previous
//
#include <hip/hip_runtime.h>
#include <hip/hip_bf16.h>

#define Bq 8
#define Tq 4096
#define Cq 192
#define NHq 24
#define HSq 8
#define Mq (Bq * Tq)   // 32768

#define CLq 64              // WKV chunk length
#define NCHq (Tq / CLq)     // 64 chunks
#define TSq 32              // LDS tile steps inside a chunk

typedef short short8 __attribute__((ext_vector_type(8)));
typedef float f32x4 __attribute__((ext_vector_type(4)));

__device__ __forceinline__ unsigned short f2bf(float f) {
    union { float f; unsigned u; } v; v.f = f;
    unsigned u = v.u;
    return (unsigned short)((u + 0x7FFFu + ((u >> 16) & 1u)) >> 16);
}
__device__ __forceinline__ float bf2f(unsigned short u) {
    union { unsigned u; float f; } v; v.u = (unsigned)u << 16;
    return v.f;
}
__device__ __forceinline__ float4 bf4_to_f4(ushort4 u) {
    return make_float4(bf2f(u.x), bf2f(u.y), bf2f(u.z), bf2f(u.w));
}

// ---------------------------------------------------------------------------
// fold lp/hd/vd/cd convs into one effective 3x3 kernel, bf16 [N=cout][K]
// ---------------------------------------------------------------------------
__global__ void prep_weights_kernel(const float* __restrict__ w_lp,
                                    const float* __restrict__ w_hd,
                                    const float* __restrict__ w_vd,
                                    const float* __restrict__ w_cd,
                                    const float* __restrict__ theta,
                                    unsigned short* __restrict__ Wg) {
    int idx = blockIdx.x * 256 + threadIdx.x;   // cout*192 + cin
    if (idx >= Cq * Cq) return;
    int cout = idx / Cq, cin = idx - cout * Cq;
    float t9[9];
#pragma unroll
    for (int t = 0; t < 9; ++t) t9[t] = 0.f;
    float lp = w_lp[idx];
    t9[1] += lp; t9[3] += lp; t9[5] += lp; t9[7] += lp; t9[4] -= 4.f * lp;
    float h0 = w_hd[idx * 3 + 0], h1 = w_hd[idx * 3 + 1], h2 = w_hd[idx * 3 + 2];
    t9[0] += h0; t9[3] += h1; t9[6] += h2;
    t9[2] -= h0; t9[5] -= h1; t9[8] -= h2;
    float v0 = w_vd[idx * 3 + 0], v1 = w_vd[idx * 3 + 1], v2 = w_vd[idx * 3 + 2];
    t9[0] += v0; t9[1] += v1; t9[2] += v2;
    t9[6] -= v0; t9[7] -= v1; t9[8] -= v2;
    float sum = 0.f;
#pragma unroll
    for (int t = 0; t < 9; ++t) {
        float cdv = w_cd[idx * 9 + t];
        t9[t] += cdv; sum += cdv;
    }
    t9[4] -= theta[0] * sum;
#pragma unroll
    for (int t = 0; t < 9; ++t)
        Wg[(size_t)cout * 1728 + t * Cq + cin] = f2bf(t9[t]);
}

// transpose+convert fp32 W[K][N] -> bf16 Wt[N][K]
__global__ void wtrans_kernel(const float* __restrict__ W,
                              unsigned short* __restrict__ Wt, int K, int N) {
    int idx = blockIdx.x * 256 + threadIdx.x;
    if (idx >= N * K) return;
    int n = idx / K, k = idx - n * K;
    Wt[idx] = f2bf(W[(size_t)k * N + n]);
}

// w2 [5][32][192] fp32 -> w2t [5][192][32] bf16
__global__ void w2t_kernel(const float* __restrict__ w2,
                           unsigned short* __restrict__ w2t) {
    int idx = blockIdx.x * 256 + threadIdx.x;
    if (idx >= 5 * 192 * 32) return;
    int f = idx / (192 * 32), rem = idx - f * 192 * 32;
    int n = rem >> 5, k = rem & 31;
    w2t[idx] = f2bf(w2[(size_t)(f * 32 + k) * Cq + n]);
}

// x [B,4096,192] fp32 -> x_halo [B][66][66][192] bf16, zero borders
__global__ __launch_bounds__(256) void halo_kernel(
    const float* __restrict__ x, unsigned short* __restrict__ xh) {
    int idx = blockIdx.x * 256 + threadIdx.x;
    int c4 = (idx % 48) * 4;
    int cell = idx / 48;
    int hx = cell % 66;
    int rest = cell / 66;
    int hy = rest % 66;
    int bb = rest / 66;
    ushort4 o = make_ushort4(0, 0, 0, 0);
    if (hy >= 1 && hy <= 64 && hx >= 1 && hx <= 64) {
        size_t g = ((size_t)(bb << 12) + (hy - 1) * 64 + (hx - 1)) * Cq + c4;
        float4 v = *(const float4*)&x[g];
        o = make_ushort4(f2bf(v.x), f2bf(v.y), f2bf(v.z), f2bf(v.w));
    }
    *(ushort4*)&xh[(size_t)cell * Cq + c4] = o;
}

// ---------------------------------------------------------------------------
// bf16 MFMA GEMM: C[M][N] = A @ Wt^T, Wt bf16 [N][K].
// ALOAD: 3 = plain bf16 A [M][K]; 1 = conv implicit-gemm from x_halo
// EPI: 0 none, 2 tanh, 3 silu, 4 exp(-exp(aux0[n]+acc)),
//      5 conv dual-out: xx=acc-x_halo -> Cb, xxx=x+xx*maa_x -> C2 (both bf16)
// OBF16: 1 = store bf16
// ---------------------------------------------------------------------------
#define GBM 128
#define GBN 64
#define GBK 64

template <int ALOAD, int EPI, int OBF16>
__global__ __launch_bounds__(256) void mgemm_kernel(
    const unsigned short* __restrict__ Asrc,
    const unsigned short* __restrict__ Wt,
    void* __restrict__ Cv, int N, int K,
    const float* __restrict__ aux0,
    const unsigned short* __restrict__ xh,
    unsigned short* __restrict__ C2) {
    __shared__ unsigned char lds[(GBM + GBN) * GBK * 2];
    unsigned char* Alds = lds;
    unsigned char* Blds = lds + GBM * GBK * 2;
    float* C = (float*)Cv;
    unsigned short* Cb = (unsigned short*)Cv;

    const int tid = threadIdx.x;
    const int wid = tid >> 6, lane = tid & 63;
    const int llo = lane & 15, lhi = lane >> 4;
    const int m0 = blockIdx.x * GBM, n0 = blockIdx.y * GBN;

    f32x4 acc[2][4];
#pragma unroll
    for (int a = 0; a < 2; ++a)
#pragma unroll
        for (int b = 0; b < 4; ++b) {
            f32x4 z = {0.f, 0.f, 0.f, 0.f};
            acc[a][b] = z;
        }

    for (int k0 = 0; k0 < K; k0 += GBK) {
        __syncthreads();
#pragma unroll
        for (int rep = 0; rep < 4; ++rep) {
            int c = tid + rep * 256;
            int row = c >> 3, kseg = c & 7;
            int m = m0 + row;
            short8 val;
            if (ALOAD == 3) {
                val = *(const short8*)&Asrc[(size_t)m * K + k0 + kseg * 8];
            } else {  // conv from halo: tap uniform per K-step, branch-free
                int tap = k0 / Cq;
                int cinb = k0 - tap * Cq;
                int t3 = tap / 3;
                int bb = m >> 12, pos = m & 4095;
                int hy = (pos >> 6) + t3;
                int hx = (pos & 63) + tap - t3 * 3;
                size_t g = ((size_t)bb * 4356 + hy * 66 + hx) * Cq + cinb + kseg * 8;
                val = *(const short8*)&Asrc[g];
            }
            *(short8*)(Alds + row * 128 + ((kseg * 16) ^ ((row & 7) << 4))) = val;
        }
#pragma unroll
        for (int rep = 0; rep < 2; ++rep) {
            int c = tid + rep * 256;
            int row = c >> 3, kseg = c & 7;
            int n = n0 + row;
            short8 val = {0, 0, 0, 0, 0, 0, 0, 0};
            if (n < N) val = *(const short8*)&Wt[(size_t)n * K + k0 + kseg * 8];
            *(short8*)(Blds + row * 128 + ((kseg * 16) ^ ((row & 7) << 4))) = val;
        }
        __syncthreads();
#pragma unroll
        for (int kc = 0; kc < 2; ++kc) {
            int kb = kc * 64 + lhi * 16;
            short8 af[2], bq[4];
#pragma unroll
            for (int mf = 0; mf < 2; ++mf) {
                int row = wid * 32 + mf * 16 + llo;
                af[mf] = *(const short8*)(Alds + row * 128 + (kb ^ ((row & 7) << 4)));
            }
#pragma unroll
            for (int nf = 0; nf < 4; ++nf) {
                int row = nf * 16 + llo;
                bq[nf] = *(const short8*)(Blds + row * 128 + (kb ^ ((row & 7) << 4)));
            }
#pragma unroll
            for (int mf = 0; mf < 2; ++mf)
#pragma unroll
                for (int nf = 0; nf < 4; ++nf)
                    acc[mf][nf] = __builtin_amdgcn_mfma_f32_16x16x32_bf16(
                        af[mf], bq[nf], acc[mf][nf], 0, 0, 0);
        }
    }
    // ---- epilogue: C/D layout col(lane&15)=n, row(lhi*4+r)=m ----
    if (EPI == 5) {
#pragma unroll
        for (int mf = 0; mf < 2; ++mf)
#pragma unroll
            for (int nf = 0; nf < 4; ++nf) {
                int n = n0 + nf * 16 + llo;
#pragma unroll
                for (int r = 0; r < 4; ++r) {
                    int m = m0 + wid * 32 + mf * 16 + lhi * 4 + r;
                    int pos = m & 4095, bb = m >> 12;
                    size_t cell = (size_t)bb * 4356 + ((pos >> 6) + 1) * 66 + (pos & 63) + 1;
                    float xv = bf2f(xh[cell * Cq + n]);
                    float xxv = acc[mf][nf][r] - xv;
                    Cb[(size_t)m * Cq + n] = f2bf(xxv);
                    C2[(size_t)m * Cq + n] = f2bf(fmaf(xxv, aux0[n], xv));
                }
            }
        return;
    }
#pragma unroll
    for (int mf = 0; mf < 2; ++mf) {
#pragma unroll
        for (int nf = 0; nf < 4; ++nf) {
            int n = n0 + nf * 16 + llo;
            if (n >= N) continue;
#pragma unroll
            for (int r = 0; r < 4; ++r) {
                int m = m0 + wid * 32 + mf * 16 + lhi * 4 + r;
                float val = acc[mf][nf][r];
                if (EPI == 2) val = tanhf(val);
                else if (EPI == 3) val = val / (1.f + expf(-val));
                else if (EPI == 4) val = expf(-expf(aux0[n] + val));
                if (OBF16) Cb[(size_t)m * N + n] = f2bf(val);
                else C[(size_t)m * N + n] = val;
            }
        }
    }
}

// ---------------------------------------------------------------------------
// mix5 (operand-swapped): lane owns 4 consecutive cols of one row.
// reads x from x_halo (bf16) and xx_b (bf16); outputs 5x bf16.
// grid (Mq/64, 3), 128 threads (2 waves x 32 rows).
// ---------------------------------------------------------------------------
__global__ __launch_bounds__(128) void mix5_kernel(
    const unsigned short* __restrict__ xh,
    const unsigned short* __restrict__ xxb,
    const unsigned short* __restrict__ tmp_bf,
    const unsigned short* __restrict__ w2t,
    const float* __restrict__ maa_w, const float* __restrict__ maa_k,
    const float* __restrict__ maa_v, const float* __restrict__ maa_r,
    const float* __restrict__ maa_g,
    unsigned short* __restrict__ xw, unsigned short* __restrict__ xr,
    unsigned short* __restrict__ xk, unsigned short* __restrict__ xv,
    unsigned short* __restrict__ xg) {
    const int tid = threadIdx.x;
    const int wid = tid >> 6, lane = tid & 63;
    const int llo = lane & 15, lhi = lane >> 4;
    const int mb = blockIdx.x * 64 + wid * 32;    // 32 rows per wave
    const int nb = blockIdx.y * 64;               // 64 cols per block

    short8 aw[5][4];
#pragma unroll
    for (int f = 0; f < 5; ++f)
#pragma unroll
        for (int nf = 0; nf < 4; ++nf)
            aw[f][nf] = *(const short8*)&w2t[((size_t)f * Cq + nb + nf * 16 + llo) * 32 + lhi * 8];

#pragma unroll
    for (int sub = 0; sub < 2; ++sub) {
        short8 bt[5];
        {
            const unsigned short* trow = &tmp_bf[(size_t)(mb + sub * 16 + llo) * 160 + lhi * 8];
#pragma unroll
            for (int f = 0; f < 5; ++f) bt[f] = *(const short8*)&trow[f * 32];
        }
        int m = mb + sub * 16 + llo;
        int pos = m & 4095, bb = m >> 12;
        size_t xbase = ((size_t)bb * 4356 + ((pos >> 6) + 1) * 66 + (pos & 63) + 1) * Cq;
#pragma unroll
        for (int nf = 0; nf < 4; ++nf) {
            f32x4 acc[5];
#pragma unroll
            for (int f = 0; f < 5; ++f) {
                f32x4 z = {0.f, 0.f, 0.f, 0.f};
                acc[f] = __builtin_amdgcn_mfma_f32_16x16x32_bf16(aw[f][nf], bt[f], z, 0, 0, 0);
            }
            int n0 = nb + nf * 16 + lhi * 4;
            size_t g = (size_t)m * Cq + n0;
            float4 xv4 = bf4_to_f4(*(const ushort4*)&xh[xbase + n0]);
            float4 xx4 = bf4_to_f4(*(const ushort4*)&xxb[g]);
            float4 mw4 = *(const float4*)&maa_w[n0];
            float4 mk4 = *(const float4*)&maa_k[n0];
            float4 mv4 = *(const float4*)&maa_v[n0];
            float4 mr4 = *(const float4*)&maa_r[n0];
            float4 mg4 = *(const float4*)&maa_g[n0];
            float xvv[4] = {xv4.x, xv4.y, xv4.z, xv4.w};
            float xxv[4] = {xx4.x, xx4.y, xx4.z, xx4.w};
            float mwv[4] = {mw4.x, mw4.y, mw4.z, mw4.w};
            float mkv[4] = {mk4.x, mk4.y, mk4.z, mk4.w};
            float mvv[4] = {mv4.x, mv4.y, mv4.z, mv4.w};
            float mrv[4] = {mr4.x, mr4.y, mr4.z, mr4.w};
            float mgv[4] = {mg4.x, mg4.y, mg4.z, mg4.w};
            ushort4 ow, ok, ov, orr, og;
            unsigned short* owp = (unsigned short*)&ow;
            unsigned short* okp = (unsigned short*)&ok;
            unsigned short* ovp = (unsigned short*)&ov;
            unsigned short* orp = (unsigned short*)&orr;
            unsigned short* ogp = (unsigned short*)&og;
#pragma unroll
            for (int r = 0; r < 4; ++r) {
                owp[r] = f2bf(fmaf(xxv[r], mwv[r] + acc[0][r], xvv[r]));
                okp[r] = f2bf(fmaf(xxv[r], mkv[r] + acc[1][r], xvv[r]));
                ovp[r] = f2bf(fmaf(xxv[r], mvv[r] + acc[2][r], xvv[r]));
                orp[r] = f2bf(fmaf(xxv[r], mrv[r] + acc[3][r], xvv[r]));
                ogp[r] = f2bf(fmaf(xxv[r], mgv[r] + acc[4][r], xvv[r]));
            }
            *(ushort4*)&xw[g] = ow;
            *(ushort4*)&xk[g] = ok;
            *(ushort4*)&xv[g] = ov;
            *(ushort4*)&xr[g] = orr;
            *(ushort4*)&xg[g] = og;
        }
    }
}

// ---------------------------------------------------------------------------
// WKV6 chunked scan: lane = slot*8+i, 8 heads/wave. k,v (and r in pass3) bf16;
// d fp32 (bf16 error would compound through the 64-step decay product).
// ---------------------------------------------------------------------------
__global__ __launch_bounds__(64) void wkv_pass1_kernel(
    const unsigned short* __restrict__ k, const unsigned short* __restrict__ v,
    const float* __restrict__ d,
    float* __restrict__ Dbuf, float* __restrict__ Cbuf) {
    int chunk = blockIdx.x, hg = blockIdx.y, b = blockIdx.z;
    int lane = threadIdx.x;
    int slot = lane >> 3, i = lane & 7;
    int cbase = hg * 64;
    size_t gbase = ((size_t)b * Tq + (size_t)chunk * CLq) * Cq + cbase;
    __shared__ float ks[TSq][64], vs[TSq][64], ds[TSq][64];
    float S[8], D[8];
#pragma unroll
    for (int j = 0; j < 8; ++j) { S[j] = 0.f; D[j] = 1.f; }
    for (int t0 = 0; t0 < CLq; t0 += TSq) {
        int f = lane & 15, r4 = lane >> 4;
#pragma unroll
        for (int p = 0; p < 8; ++p) {
            int row = r4 + p * 4;
            size_t g = gbase + (size_t)(t0 + row) * Cq + f * 4;
            *(float4*)&ks[row][f * 4] = bf4_to_f4(*(const ushort4*)&k[g]);
            *(float4*)&vs[row][f * 4] = bf4_to_f4(*(const ushort4*)&v[g]);
            *(float4*)&ds[row][f * 4] = *(const float4*)&d[g];
        }
        __syncthreads();
#pragma unroll 8
        for (int t = 0; t < TSq; ++t) {
            float vv = vs[t][lane];
            float4 ka = *(const float4*)&ks[t][slot * 8];
            float4 kb = *(const float4*)&ks[t][slot * 8 + 4];
            float4 da = *(const float4*)&ds[t][slot * 8];
            float4 db = *(const float4*)&ds[t][slot * 8 + 4];
            float kk[8] = {ka.x, ka.y, ka.z, ka.w, kb.x, kb.y, kb.z, kb.w};
            float dd[8] = {da.x, da.y, da.z, da.w, db.x, db.y, db.z, db.w};
#pragma unroll
            for (int j = 0; j < 8; ++j) {
                float kv = kk[j] * vv;
                S[j] = fmaf(dd[j], S[j], kv);
                D[j] *= dd[j];
            }
        }
        __syncthreads();
    }
    size_t dbase = (((size_t)b * NCHq + chunk) * NHq + hg * 8) * 8;
    Dbuf[dbase + lane] = D[i];
    size_t cb = (((size_t)b * NCHq + chunk) * NHq + (hg * 8 + slot)) * 64 + i;
#pragma unroll
    for (int j = 0; j < 8; ++j) Cbuf[cb + j * 8] = S[j];
}

__global__ __launch_bounds__(64) void wkv_pass2_kernel(
    const float* __restrict__ Dbuf, const float* __restrict__ Cbuf,
    float* __restrict__ Sbuf) {
    int bh = blockIdx.x;
    int lane = threadIdx.x;
    int j = lane >> 3, i = lane & 7;
    int b = bh / NHq, h = bh - b * NHq;
    float S = 0.f;
    size_t stride = (size_t)NHq * 64;
    size_t base = ((size_t)b * NCHq * NHq + h) * 64 + j * 8 + i;
    size_t dstride = (size_t)NHq * 8;
    size_t dbase = ((size_t)b * NCHq * NHq + h) * 8 + j;
#pragma unroll 4
    for (int c = 0; c < NCHq; ++c) {
        Sbuf[base + c * stride] = S;
        float D = Dbuf[dbase + c * dstride];
        float C = Cbuf[base + c * stride];
        S = fmaf(D, S, C);
    }
}

__global__ __launch_bounds__(64) void wkv_pass3_kernel(
    const unsigned short* __restrict__ r, const unsigned short* __restrict__ k,
    const unsigned short* __restrict__ v, const float* __restrict__ d,
    const float* __restrict__ u, const float* __restrict__ Sbuf,
    unsigned short* __restrict__ y) {
    int chunk = blockIdx.x, hg = blockIdx.y, b = blockIdx.z;
    int lane = threadIdx.x;
    int slot = lane >> 3, i = lane & 7;
    int h = hg * 8 + slot;
    int cbase = hg * 64;
    size_t gbase = ((size_t)b * Tq + (size_t)chunk * CLq) * Cq + cbase;
    __shared__ float rs[TSq][64], ks[TSq][64], vs[TSq][64], ds[TSq][64];
    float S[8], uu[8];
    size_t sb = (((size_t)b * NCHq + chunk) * NHq + h) * 64 + i;
#pragma unroll
    for (int j = 0; j < 8; ++j) {
        S[j] = Sbuf[sb + j * 8];
        uu[j] = u[h * 8 + j];
    }
    for (int t0 = 0; t0 < CLq; t0 += TSq) {
        int f = lane & 15, r4 = lane >> 4;
#pragma unroll
        for (int p = 0; p < 8; ++p) {
            int row = r4 + p * 4;
            size_t g = gbase + (size_t)(t0 + row) * Cq + f * 4;
            *(float4*)&rs[row][f * 4] = bf4_to_f4(*(const ushort4*)&r[g]);
            *(float4*)&ks[row][f * 4] = bf4_to_f4(*(const ushort4*)&k[g]);
            *(float4*)&vs[row][f * 4] = bf4_to_f4(*(const ushort4*)&v[g]);
            *(float4*)&ds[row][f * 4] = *(const float4*)&d[g];
        }
        __syncthreads();
#pragma unroll 8
        for (int t = 0; t < TSq; ++t) {
            float vv = vs[t][lane];
            float4 ra = *(const float4*)&rs[t][slot * 8];
            float4 rb = *(const float4*)&rs[t][slot * 8 + 4];
            float4 ka = *(const float4*)&ks[t][slot * 8];
            float4 kb = *(const float4*)&ks[t][slot * 8 + 4];
            float4 da = *(const float4*)&ds[t][slot * 8];
            float4 db = *(const float4*)&ds[t][slot * 8 + 4];
            float rr[8] = {ra.x, ra.y, ra.z, ra.w, rb.x, rb.y, rb.z, rb.w};
            float kk[8] = {ka.x, ka.y, ka.z, ka.w, kb.x, kb.y, kb.z, kb.w};
            float dd[8] = {da.x, da.y, da.z, da.w, db.x, db.y, db.z, db.w};
            float yv = 0.f;
#pragma unroll
            for (int j = 0; j < 8; ++j) {
                float kv = kk[j] * vv;
                yv = fmaf(rr[j], fmaf(uu[j], kv, S[j]), yv);
                S[j] = fmaf(dd[j], S[j], kv);
            }
            y[gbase + (size_t)(t0 + t) * Cq + lane] = f2bf(yv);
        }
        __syncthreads();
    }
}

// ---------------------------------------------------------------------------
// LayerNorm + gate (y, g bf16 in) -> bf16 out
// ---------------------------------------------------------------------------
__global__ __launch_bounds__(256) void ln_gate_kernel(
    const unsigned short* __restrict__ y, const unsigned short* __restrict__ g,
    const float* __restrict__ ln_g, const float* __restrict__ ln_b,
    unsigned short* __restrict__ out) {
    int row = blockIdx.x * 4 + (threadIdx.x >> 6);
    int lane = threadIdx.x & 63;
    const unsigned short* yr = y + (size_t)row * Cq;
    float a0 = bf2f(yr[lane]), a1 = bf2f(yr[lane + 64]), a2 = bf2f(yr[lane + 128]);
    float s = a0 + a1 + a2;
    float ss = a0 * a0 + a1 * a1 + a2 * a2;
#pragma unroll
    for (int m = 1; m < 64; m <<= 1) {
        s += __shfl_xor(s, m);
        ss += __shfl_xor(ss, m);
    }
    float mu = s * (1.f / 192.f);
    float var = ss * (1.f / 192.f) - mu * mu;
    float rstd = rsqrtf(var + 1e-5f);
    const unsigned short* gr = g + (size_t)row * Cq;
    unsigned short* orow = out + (size_t)row * Cq;
    float aa[3] = {a0, a1, a2};
#pragma unroll
    for (int q = 0; q < 3; ++q) {
        int cc = lane + q * 64;
        float yn = (aa[q] - mu) * rstd * ln_g[cc] + ln_b[cc];
        orow[cc] = f2bf(yn * bf2f(gr[cc]));
    }
}

// ---------------------------------------------------------------------------
extern "C" void kernel_launch(void* const* d_in, const int* in_sizes, int n_in,
                              void* d_out, int out_size, void* d_ws, size_t ws_size,
                              hipStream_t stream) {
    const float* x        = (const float*)d_in[0];
    const float* maa_x    = (const float*)d_in[1];
    const float* maa_w    = (const float*)d_in[2];
    const float* maa_k    = (const float*)d_in[3];
    const float* maa_v    = (const float*)d_in[4];
    const float* maa_r    = (const float*)d_in[5];
    const float* maa_g    = (const float*)d_in[6];
    const float* maa_w1   = (const float*)d_in[7];
    const float* maa_w2   = (const float*)d_in[8];
    const float* decay_w1 = (const float*)d_in[9];
    const float* decay_w2 = (const float*)d_in[10];
    const float* sdecay   = (const float*)d_in[11];
    const float* u        = (const float*)d_in[12];
    const float* Wr       = (const float*)d_in[13];
    const float* Wk       = (const float*)d_in[14];
    const float* Wv       = (const float*)d_in[15];
    const float* Wgp      = (const float*)d_in[16];
    const float* Wo       = (const float*)d_in[17];
    const float* ln_g     = (const float*)d_in[18];
    const float* ln_b     = (const float*)d_in[19];
    const float* w_lp     = (const float*)d_in[20];
    const float* w_hd     = (const float*)d_in[21];
    const float* w_vd     = (const float*)d_in[22];
    const float* w_cd     = (const float*)d_in[23];
    const float* theta    = (const float*)d_in[24];
    float* out = (float*)d_out;

    const size_t BIG = (size_t)Mq * Cq;          // 6,291,456 floats
    float* ws = (float*)d_ws;
    unsigned short* Wgt_conv = (unsigned short*)ws;            // 192*1728
    unsigned short* Wt_maa = Wgt_conv + (size_t)Cq * 1728;     // 160*192
    unsigned short* Wt_r = Wt_maa + 160 * Cq;
    unsigned short* Wt_k = Wt_r + Cq * Cq;
    unsigned short* Wt_v = Wt_k + Cq * Cq;
    unsigned short* Wt_g = Wt_v + Cq * Cq;
    unsigned short* Wt_o = Wt_g + Cq * Cq;
    unsigned short* w2t  = Wt_o + Cq * Cq;                     // 5*192*32
    unsigned short* Wt_d1 = w2t + 5 * 192 * 32;                // 64*192
    unsigned short* Wt_d2 = Wt_d1 + 64 * Cq;                   // 192*64
    float* tmp  = ws + 331776;                  // M*160 region
    float* wtmp = tmp + (size_t)Mq * 160;       // M*64
    float* buf0 = wtmp + (size_t)Mq * 64;
    float* buf1 = buf0 + BIG;
    float* buf2 = buf1 + BIG;
    float* buf3 = buf2 + BIG;
    float* buf4 = buf3 + BIG;
    float* buf5 = buf4 + BIG;

    // tmp region: bf16 tmp (M*80 floats) then WKV scan scratch
    unsigned short* tmp_bf = (unsigned short*)tmp;
    float* Dbuf = tmp + (size_t)Mq * 80;
    float* Cbuf = Dbuf + (size_t)Bq * NCHq * NHq * 8;
    float* Sbuf = Cbuf + (size_t)Bq * NCHq * NHq * 64;

    // overlays (bf16 halves of fp32 buffers); lifetimes annotated:
    unsigned short* x_halo = (unsigned short*)buf1;            // halo..mix5
    unsigned short* y_b    = (unsigned short*)buf1;            // pass3..ln (halo dead)
    unsigned short* xx_b   = (unsigned short*)buf0;            // conv..mix5
    unsigned short* xw_b   = (unsigned short*)(buf0 + BIG / 2); // mix5..decay1
    unsigned short* r_b    = (unsigned short*)buf0;            // r-proj..pass3 (xx dead)
    unsigned short* xxx_b  = (unsigned short*)(buf2 + BIG / 2); // conv..maa
    unsigned short* xg_b   = xxx_b;                            // mix5..g-proj
    unsigned short* xv_b   = (unsigned short*)buf2;            // mix5..v-proj
    unsigned short* k_b    = (unsigned short*)buf2;            // k-proj..pass3 (xv dead)
    unsigned short* gate_b = (unsigned short*)buf2;            // ln..Wo (k_b dead)
    unsigned short* v_b    = (unsigned short*)buf3;            // v-proj..pass3
    unsigned short* g_b    = (unsigned short*)buf4;            // g-proj..ln
    unsigned short* xr_b   = (unsigned short*)buf5;            // mix5..r-proj
    unsigned short* xk_b   = (unsigned short*)(buf5 + BIG / 2); // mix5..k-proj
    float* d_f             = buf5;                             // decay2..pass3 (fp32)
    unsigned short* wtmp_b = (unsigned short*)wtmp;            // decay mid [M][64]

    dim3 blk(256);
    dim3 mg(Mq / GBM, 3);        // MFMA gemms over N=192/160
    const unsigned short* nosrc = nullptr;
    unsigned short* nodst = nullptr;

    // 1) weight prep (bf16, [N][K])
    prep_weights_kernel<<<dim3(144), blk, 0, stream>>>(w_lp, w_hd, w_vd, w_cd, theta, Wgt_conv);
    wtrans_kernel<<<dim3(120), blk, 0, stream>>>(maa_w1, Wt_maa, Cq, 160);
    wtrans_kernel<<<dim3(144), blk, 0, stream>>>(Wr, Wt_r, Cq, Cq);
    wtrans_kernel<<<dim3(144), blk, 0, stream>>>(Wk, Wt_k, Cq, Cq);
    wtrans_kernel<<<dim3(144), blk, 0, stream>>>(Wv, Wt_v, Cq, Cq);
    wtrans_kernel<<<dim3(144), blk, 0, stream>>>(Wgp, Wt_g, Cq, Cq);
    wtrans_kernel<<<dim3(144), blk, 0, stream>>>(Wo, Wt_o, Cq, Cq);
    w2t_kernel<<<dim3(120), blk, 0, stream>>>(maa_w2, w2t);
    wtrans_kernel<<<dim3(48), blk, 0, stream>>>(decay_w1, Wt_d1, Cq, 64);
    wtrans_kernel<<<dim3(48), blk, 0, stream>>>(decay_w2, Wt_d2, 64, Cq);
    // 2) halo-pad x; conv implicit GEMM, fused dual-out: xx_b + xxx_b (bf16)
    halo_kernel<<<dim3(8 * 66 * 66 * 48 / 256), blk, 0, stream>>>(x, x_halo);
    mgemm_kernel<1, 5, 1><<<mg, blk, 0, stream>>>(x_halo, Wgt_conv, xx_b, Cq, 1728, maa_x, x_halo, xxx_b);
    // 3) tmp_bf = bf16(tanh(xxx @ maa_w1)) [M,160]
    mgemm_kernel<3, 2, 1><<<mg, blk, 0, stream>>>(xxx_b, Wt_maa, tmp_bf, 160, Cq, nullptr, nosrc, nodst);
    // 4) fused mixes: all five bf16
    mix5_kernel<<<dim3(Mq / 64, 3), dim3(128), 0, stream>>>(
        x_halo, xx_b, tmp_bf, w2t, maa_w, maa_k, maa_v, maa_r, maa_g,
        xw_b, xr_b, xk_b, xv_b, xg_b);
    // 5) projections -> bf16
    mgemm_kernel<3, 0, 1><<<mg, blk, 0, stream>>>(xv_b, Wt_v, v_b, Cq, Cq, nullptr, nosrc, nodst); // v
    mgemm_kernel<3, 3, 1><<<mg, blk, 0, stream>>>(xg_b, Wt_g, g_b, Cq, Cq, nullptr, nosrc, nodst); // g=silu
    mgemm_kernel<3, 0, 1><<<mg, blk, 0, stream>>>(xr_b, Wt_r, r_b, Cq, Cq, nullptr, nosrc, nodst); // r
    mgemm_kernel<3, 0, 1><<<mg, blk, 0, stream>>>(xk_b, Wt_k, k_b, Cq, Cq, nullptr, nosrc, nodst); // k
    // 6) decay: wtmp_b = bf16(tanh(xw@w1)); d = exp(-exp(sd+.@w2)) fp32
    mgemm_kernel<3, 2, 1><<<dim3(Mq / GBM, 1), blk, 0, stream>>>(xw_b, Wt_d1, wtmp_b, 64, Cq, nullptr, nosrc, nodst);
    mgemm_kernel<3, 4, 0><<<mg, blk, 0, stream>>>(wtmp_b, Wt_d2, d_f, Cq, 64, sdecay, nosrc, nodst);
    // 7) WKV chunked scan (k,v,r bf16; d fp32) -> y_b bf16
    wkv_pass1_kernel<<<dim3(NCHq, 3, Bq), dim3(64), 0, stream>>>(k_b, v_b, d_f, Dbuf, Cbuf);
    wkv_pass2_kernel<<<dim3(Bq * NHq), dim3(64), 0, stream>>>(Dbuf, Cbuf, Sbuf);
    wkv_pass3_kernel<<<dim3(NCHq, 3, Bq), dim3(64), 0, stream>>>(r_b, k_b, v_b, d_f, u, Sbuf, y_b);
    // 8) LN + gate -> gate_b bf16
    ln_gate_kernel<<<dim3(Mq / 4), blk, 0, stream>>>(y_b, g_b, ln_g, ln_b, gate_b);
    // 9) output projection (fp32 out)
    mgemm_kernel<3, 0, 0><<<mg, blk, 0, stream>>>(gate_b, Wt_o, out, Cq, Cq, nullptr, nosrc, nodst);
}

// Round 10
// 329.132 us; speedup vs baseline: 5.2376x; 1.0930x over previous
//
#include <hip/hip_runtime.h>
#include <hip/hip_bf16.h>

#define Bq 8
#define Tq 4096
#define Cq 192
#define NHq 24
#define HSq 8
#define Mq (Bq * Tq)   // 32768

#define CLq 64              // WKV chunk length
#define NCHq (Tq / CLq)     // 64 chunks
#define TSq 32              // LDS tile steps inside a chunk

typedef short short8 __attribute__((ext_vector_type(8)));
typedef float f32x4 __attribute__((ext_vector_type(4)));

__device__ __forceinline__ unsigned short f2bf(float f) {
    union { float f; unsigned u; } v; v.f = f;
    unsigned u = v.u;
    return (unsigned short)((u + 0x7FFFu + ((u >> 16) & 1u)) >> 16);
}
__device__ __forceinline__ float bf2f(unsigned short u) {
    union { unsigned u; float f; } v; v.u = (unsigned)u << 16;
    return v.f;
}
__device__ __forceinline__ float4 bf4_to_f4(ushort4 u) {
    return make_float4(bf2f(u.x), bf2f(u.y), bf2f(u.z), bf2f(u.w));
}

// ---------------------------------------------------------------------------
// fold lp/hd/vd/cd convs into one effective 3x3 kernel, bf16 [N=cout][K]
// ---------------------------------------------------------------------------
__global__ void prep_weights_kernel(const float* __restrict__ w_lp,
                                    const float* __restrict__ w_hd,
                                    const float* __restrict__ w_vd,
                                    const float* __restrict__ w_cd,
                                    const float* __restrict__ theta,
                                    unsigned short* __restrict__ Wg) {
    int idx = blockIdx.x * 256 + threadIdx.x;   // cout*192 + cin
    if (idx >= Cq * Cq) return;
    int cout = idx / Cq, cin = idx - cout * Cq;
    float t9[9];
#pragma unroll
    for (int t = 0; t < 9; ++t) t9[t] = 0.f;
    float lp = w_lp[idx];
    t9[1] += lp; t9[3] += lp; t9[5] += lp; t9[7] += lp; t9[4] -= 4.f * lp;
    float h0 = w_hd[idx * 3 + 0], h1 = w_hd[idx * 3 + 1], h2 = w_hd[idx * 3 + 2];
    t9[0] += h0; t9[3] += h1; t9[6] += h2;
    t9[2] -= h0; t9[5] -= h1; t9[8] -= h2;
    float v0 = w_vd[idx * 3 + 0], v1 = w_vd[idx * 3 + 1], v2 = w_vd[idx * 3 + 2];
    t9[0] += v0; t9[1] += v1; t9[2] += v2;
    t9[6] -= v0; t9[7] -= v1; t9[8] -= v2;
    float sum = 0.f;
#pragma unroll
    for (int t = 0; t < 9; ++t) {
        float cdv = w_cd[idx * 9 + t];
        t9[t] += cdv; sum += cdv;
    }
    t9[4] -= theta[0] * sum;
#pragma unroll
    for (int t = 0; t < 9; ++t)
        Wg[(size_t)cout * 1728 + t * Cq + cin] = f2bf(t9[t]);
}

// ---------------------------------------------------------------------------
// all other weight transposes/conversions in ONE launch (was 9 launches)
// ---------------------------------------------------------------------------
__global__ __launch_bounds__(256) void prep_pack_kernel(
    const float* __restrict__ maa_w1, const float* __restrict__ Wr,
    const float* __restrict__ Wk, const float* __restrict__ Wv,
    const float* __restrict__ Wgp, const float* __restrict__ Wo,
    const float* __restrict__ maa_w2, const float* __restrict__ d1,
    const float* __restrict__ d2,
    unsigned short* __restrict__ Wt_maa, unsigned short* __restrict__ Wt_r,
    unsigned short* __restrict__ Wt_k, unsigned short* __restrict__ Wt_v,
    unsigned short* __restrict__ Wt_g, unsigned short* __restrict__ Wt_o,
    unsigned short* __restrict__ w2t, unsigned short* __restrict__ Wt_d1,
    unsigned short* __restrict__ Wt_d2) {
    int idx = blockIdx.x * 256 + threadIdx.x;
    if (idx < 30720) {                       // maa_w1 [192][160] -> [160][192]
        int n = idx / 192, k = idx - n * 192;
        Wt_maa[idx] = f2bf(maa_w1[(size_t)k * 160 + n]);
        return;
    }
    idx -= 30720;
    if (idx < 5 * 36864) {                   // 5 square weights -> [N][K]
        int s = idx / 36864, e = idx - s * 36864;
        int n = e / 192, k = e - n * 192;
        const float* W = s == 0 ? Wr : s == 1 ? Wk : s == 2 ? Wv : s == 3 ? Wgp : Wo;
        unsigned short* D = s == 0 ? Wt_r : s == 1 ? Wt_k : s == 2 ? Wt_v : s == 3 ? Wt_g : Wt_o;
        D[e] = f2bf(W[(size_t)k * 192 + n]);
        return;
    }
    idx -= 5 * 36864;
    if (idx < 30720) {                       // w2 [5][32][192] -> [5][192][32]
        int f = idx / 6144, rem = idx - f * 6144;
        int n = rem >> 5, k = rem & 31;
        w2t[idx] = f2bf(maa_w2[(size_t)(f * 32 + k) * 192 + n]);
        return;
    }
    idx -= 30720;
    if (idx < 12288) {                       // d1 [192][64] -> [64][192]
        int n = idx / 192, k = idx - n * 192;
        Wt_d1[idx] = f2bf(d1[(size_t)k * 64 + n]);
        return;
    }
    idx -= 12288;
    if (idx < 12288) {                       // d2 [64][192] -> [192][64]
        int n = idx / 64, k = idx - n * 64;
        Wt_d2[idx] = f2bf(d2[(size_t)k * 192 + n]);
    }
}

// x [B,4096,192] fp32 -> x_halo [B][66][66][192] bf16, zero borders
__global__ __launch_bounds__(256) void halo_kernel(
    const float* __restrict__ x, unsigned short* __restrict__ xh) {
    int idx = blockIdx.x * 256 + threadIdx.x;
    int c4 = (idx % 48) * 4;
    int cell = idx / 48;
    int hx = cell % 66;
    int rest = cell / 66;
    int hy = rest % 66;
    int bb = rest / 66;
    ushort4 o = make_ushort4(0, 0, 0, 0);
    if (hy >= 1 && hy <= 64 && hx >= 1 && hx <= 64) {
        size_t g = ((size_t)(bb << 12) + (hy - 1) * 64 + (hx - 1)) * Cq + c4;
        float4 v = *(const float4*)&x[g];
        o = make_ushort4(f2bf(v.x), f2bf(v.y), f2bf(v.z), f2bf(v.w));
    }
    *(ushort4*)&xh[(size_t)cell * Cq + c4] = o;
}

// ---------------------------------------------------------------------------
// bf16 MFMA GEMM: C[M][N] = A @ Wt^T, Wt bf16 [N][K].
// ALOAD: 3 = plain bf16 A [M][K]; 1 = conv implicit-gemm from x_halo
// EPI: 0 none, 2 tanh, 4 exp(-exp(aux0[n]+acc)),
//      5 conv dual-out: xx=acc-x_halo -> Cb, xxx=x+xx*maa_x -> C2 (both bf16)
// OBF16: 1 = store bf16.  BN: N-tile width (64 or 96).
// tile 128xBNxK64, 4 waves, wave = 32 rows x BN cols
// ---------------------------------------------------------------------------
#define GBM 128
#define GBK 64

template <int ALOAD, int EPI, int OBF16, int BN>
__global__ __launch_bounds__(256) void mgemm_kernel(
    const unsigned short* __restrict__ Asrc,
    const unsigned short* __restrict__ Wt,
    void* __restrict__ Cv, int N, int K,
    const float* __restrict__ aux0,
    const unsigned short* __restrict__ xh,
    unsigned short* __restrict__ C2) {
    __shared__ unsigned char lds[(GBM + BN) * GBK * 2];
    unsigned char* Alds = lds;
    unsigned char* Blds = lds + GBM * GBK * 2;
    float* C = (float*)Cv;
    unsigned short* Cb = (unsigned short*)Cv;

    const int tid = threadIdx.x;
    const int wid = tid >> 6, lane = tid & 63;
    const int llo = lane & 15, lhi = lane >> 4;
    const int m0 = blockIdx.x * GBM, n0 = blockIdx.y * BN;
    const int NF = BN / 16;

    f32x4 acc[2][BN / 16];
#pragma unroll
    for (int a = 0; a < 2; ++a)
#pragma unroll
        for (int b = 0; b < NF; ++b) {
            f32x4 z = {0.f, 0.f, 0.f, 0.f};
            acc[a][b] = z;
        }

    for (int k0 = 0; k0 < K; k0 += GBK) {
        __syncthreads();
#pragma unroll
        for (int rep = 0; rep < 4; ++rep) {
            int c = tid + rep * 256;
            int row = c >> 3, kseg = c & 7;
            int m = m0 + row;
            short8 val;
            if (ALOAD == 3) {
                val = *(const short8*)&Asrc[(size_t)m * K + k0 + kseg * 8];
            } else {  // conv from halo: tap uniform per K-step, branch-free
                int tap = k0 / Cq;
                int cinb = k0 - tap * Cq;
                int t3 = tap / 3;
                int bb = m >> 12, pos = m & 4095;
                int hy = (pos >> 6) + t3;
                int hx = (pos & 63) + tap - t3 * 3;
                size_t g = ((size_t)bb * 4356 + hy * 66 + hx) * Cq + cinb + kseg * 8;
                val = *(const short8*)&Asrc[g];
            }
            *(short8*)(Alds + row * 128 + ((kseg * 16) ^ ((row & 7) << 4))) = val;
        }
#pragma unroll
        for (int rep = 0; rep < BN / 32; ++rep) {
            int c = tid + rep * 256;
            int row = c >> 3, kseg = c & 7;
            int n = n0 + row;
            short8 val = {0, 0, 0, 0, 0, 0, 0, 0};
            if (n < N) val = *(const short8*)&Wt[(size_t)n * K + k0 + kseg * 8];
            *(short8*)(Blds + row * 128 + ((kseg * 16) ^ ((row & 7) << 4))) = val;
        }
        __syncthreads();
#pragma unroll
        for (int kc = 0; kc < 2; ++kc) {
            int kb = kc * 64 + lhi * 16;
            short8 af[2], bq[BN / 16];
#pragma unroll
            for (int mf = 0; mf < 2; ++mf) {
                int row = wid * 32 + mf * 16 + llo;
                af[mf] = *(const short8*)(Alds + row * 128 + (kb ^ ((row & 7) << 4)));
            }
#pragma unroll
            for (int nf = 0; nf < NF; ++nf) {
                int row = nf * 16 + llo;
                bq[nf] = *(const short8*)(Blds + row * 128 + (kb ^ ((row & 7) << 4)));
            }
#pragma unroll
            for (int mf = 0; mf < 2; ++mf)
#pragma unroll
                for (int nf = 0; nf < NF; ++nf)
                    acc[mf][nf] = __builtin_amdgcn_mfma_f32_16x16x32_bf16(
                        af[mf], bq[nf], acc[mf][nf], 0, 0, 0);
        }
    }
    // ---- epilogue: C/D layout col(lane&15)=n, row(lhi*4+r)=m ----
    if (EPI == 5) {
#pragma unroll
        for (int mf = 0; mf < 2; ++mf)
#pragma unroll
            for (int nf = 0; nf < NF; ++nf) {
                int n = n0 + nf * 16 + llo;
#pragma unroll
                for (int r = 0; r < 4; ++r) {
                    int m = m0 + wid * 32 + mf * 16 + lhi * 4 + r;
                    int pos = m & 4095, bb = m >> 12;
                    size_t cell = (size_t)bb * 4356 + ((pos >> 6) + 1) * 66 + (pos & 63) + 1;
                    float xv = bf2f(xh[cell * Cq + n]);
                    float xxv = acc[mf][nf][r] - xv;
                    Cb[(size_t)m * Cq + n] = f2bf(xxv);
                    C2[(size_t)m * Cq + n] = f2bf(fmaf(xxv, aux0[n], xv));
                }
            }
        return;
    }
#pragma unroll
    for (int mf = 0; mf < 2; ++mf) {
#pragma unroll
        for (int nf = 0; nf < NF; ++nf) {
            int n = n0 + nf * 16 + llo;
            if (n >= N) continue;
#pragma unroll
            for (int r = 0; r < 4; ++r) {
                int m = m0 + wid * 32 + mf * 16 + lhi * 4 + r;
                float val = acc[mf][nf][r];
                if (EPI == 2) val = tanhf(val);
                else if (EPI == 4) val = expf(-expf(aux0[n] + val));
                if (OBF16) Cb[(size_t)m * N + n] = f2bf(val);
                else C[(size_t)m * N + n] = val;
            }
        }
    }
}

// ---------------------------------------------------------------------------
// proj4: 4 projections (v, r, k, g=silu) in one launch; blockIdx.z selects.
// Same 128x64 MFMA body; K=N=192, bf16 out.
// ---------------------------------------------------------------------------
__global__ __launch_bounds__(256) void proj4_kernel(
    const unsigned short* __restrict__ A0, const unsigned short* __restrict__ A1,
    const unsigned short* __restrict__ A2, const unsigned short* __restrict__ A3,
    const unsigned short* __restrict__ W0, const unsigned short* __restrict__ W1,
    const unsigned short* __restrict__ W2, const unsigned short* __restrict__ W3,
    unsigned short* __restrict__ O0, unsigned short* __restrict__ O1,
    unsigned short* __restrict__ O2, unsigned short* __restrict__ O3) {
    __shared__ unsigned char lds[(GBM + 64) * GBK * 2];
    unsigned char* Alds = lds;
    unsigned char* Blds = lds + GBM * GBK * 2;
    const int z = blockIdx.z;
    const unsigned short* Asrc = z == 0 ? A0 : z == 1 ? A1 : z == 2 ? A2 : A3;
    const unsigned short* Wt = z == 0 ? W0 : z == 1 ? W1 : z == 2 ? W2 : W3;
    unsigned short* Cb = z == 0 ? O0 : z == 1 ? O1 : z == 2 ? O2 : O3;
    const bool silu = (z == 3);

    const int tid = threadIdx.x;
    const int wid = tid >> 6, lane = tid & 63;
    const int llo = lane & 15, lhi = lane >> 4;
    const int m0 = blockIdx.x * GBM, n0 = blockIdx.y * 64;

    f32x4 acc[2][4];
#pragma unroll
    for (int a = 0; a < 2; ++a)
#pragma unroll
        for (int b = 0; b < 4; ++b) {
            f32x4 zz = {0.f, 0.f, 0.f, 0.f};
            acc[a][b] = zz;
        }

    for (int k0 = 0; k0 < Cq; k0 += GBK) {
        __syncthreads();
#pragma unroll
        for (int rep = 0; rep < 4; ++rep) {
            int c = tid + rep * 256;
            int row = c >> 3, kseg = c & 7;
            short8 val = *(const short8*)&Asrc[(size_t)(m0 + row) * Cq + k0 + kseg * 8];
            *(short8*)(Alds + row * 128 + ((kseg * 16) ^ ((row & 7) << 4))) = val;
        }
#pragma unroll
        for (int rep = 0; rep < 2; ++rep) {
            int c = tid + rep * 256;
            int row = c >> 3, kseg = c & 7;
            short8 val = *(const short8*)&Wt[(size_t)(n0 + row) * Cq + k0 + kseg * 8];
            *(short8*)(Blds + row * 128 + ((kseg * 16) ^ ((row & 7) << 4))) = val;
        }
        __syncthreads();
#pragma unroll
        for (int kc = 0; kc < 2; ++kc) {
            int kb = kc * 64 + lhi * 16;
            short8 af[2], bq[4];
#pragma unroll
            for (int mf = 0; mf < 2; ++mf) {
                int row = wid * 32 + mf * 16 + llo;
                af[mf] = *(const short8*)(Alds + row * 128 + (kb ^ ((row & 7) << 4)));
            }
#pragma unroll
            for (int nf = 0; nf < 4; ++nf) {
                int row = nf * 16 + llo;
                bq[nf] = *(const short8*)(Blds + row * 128 + (kb ^ ((row & 7) << 4)));
            }
#pragma unroll
            for (int mf = 0; mf < 2; ++mf)
#pragma unroll
                for (int nf = 0; nf < 4; ++nf)
                    acc[mf][nf] = __builtin_amdgcn_mfma_f32_16x16x32_bf16(
                        af[mf], bq[nf], acc[mf][nf], 0, 0, 0);
        }
    }
#pragma unroll
    for (int mf = 0; mf < 2; ++mf)
#pragma unroll
        for (int nf = 0; nf < 4; ++nf) {
            int n = n0 + nf * 16 + llo;
#pragma unroll
            for (int r = 0; r < 4; ++r) {
                int m = m0 + wid * 32 + mf * 16 + lhi * 4 + r;
                float val = acc[mf][nf][r];
                if (silu) val = val / (1.f + expf(-val));
                Cb[(size_t)m * Cq + n] = f2bf(val);
            }
        }
}

// ---------------------------------------------------------------------------
// mix5: operand-swapped MFMA + LDS-restaged coalesced stores.
// grid (Mq/64, 3), 128 threads (2 waves x 32 rows x 64 cols).
// ---------------------------------------------------------------------------
#define MLDW 72   // padded row (ushorts): 144 B, 16B-aligned, bank-spread
__global__ __launch_bounds__(128) void mix5_kernel(
    const unsigned short* __restrict__ xh,
    const unsigned short* __restrict__ xxb,
    const unsigned short* __restrict__ tmp_bf,
    const unsigned short* __restrict__ w2t,
    const float* __restrict__ maa_w, const float* __restrict__ maa_k,
    const float* __restrict__ maa_v, const float* __restrict__ maa_r,
    const float* __restrict__ maa_g,
    unsigned short* __restrict__ xw, unsigned short* __restrict__ xr,
    unsigned short* __restrict__ xk, unsigned short* __restrict__ xv,
    unsigned short* __restrict__ xg) {
    __shared__ unsigned short tile[2][5][16][MLDW];
    const int tid = threadIdx.x;
    const int wid = tid >> 6, lane = tid & 63;
    const int llo = lane & 15, lhi = lane >> 4;
    const int mb = blockIdx.x * 64 + wid * 32;    // 32 rows per wave
    const int nb = blockIdx.y * 64;               // 64 cols per block

    short8 aw[5][4];
#pragma unroll
    for (int f = 0; f < 5; ++f)
#pragma unroll
        for (int nf = 0; nf < 4; ++nf)
            aw[f][nf] = *(const short8*)&w2t[((size_t)f * Cq + nb + nf * 16 + llo) * 32 + lhi * 8];

    unsigned short* const outs[5] = {xw, xk, xv, xr, xg};

#pragma unroll
    for (int sub = 0; sub < 2; ++sub) {
        short8 bt[5];
        {
            const unsigned short* trow = &tmp_bf[(size_t)(mb + sub * 16 + llo) * 160 + lhi * 8];
#pragma unroll
            for (int f = 0; f < 5; ++f) bt[f] = *(const short8*)&trow[f * 32];
        }
        int m = mb + sub * 16 + llo;
        int pos = m & 4095, bb = m >> 12;
        size_t xbase = ((size_t)bb * 4356 + ((pos >> 6) + 1) * 66 + (pos & 63) + 1) * Cq;
#pragma unroll
        for (int nf = 0; nf < 4; ++nf) {
            f32x4 acc[5];
#pragma unroll
            for (int f = 0; f < 5; ++f) {
                f32x4 z = {0.f, 0.f, 0.f, 0.f};
                acc[f] = __builtin_amdgcn_mfma_f32_16x16x32_bf16(aw[f][nf], bt[f], z, 0, 0, 0);
            }
            int n0 = nb + nf * 16 + lhi * 4;
            size_t g = (size_t)m * Cq + n0;
            float4 xv4 = bf4_to_f4(*(const ushort4*)&xh[xbase + n0]);
            float4 xx4 = bf4_to_f4(*(const ushort4*)&xxb[g]);
            float4 mw4 = *(const float4*)&maa_w[n0];
            float4 mk4 = *(const float4*)&maa_k[n0];
            float4 mv4 = *(const float4*)&maa_v[n0];
            float4 mr4 = *(const float4*)&maa_r[n0];
            float4 mg4 = *(const float4*)&maa_g[n0];
            float xvv[4] = {xv4.x, xv4.y, xv4.z, xv4.w};
            float xxv[4] = {xx4.x, xx4.y, xx4.z, xx4.w};
            float mwv[4] = {mw4.x, mw4.y, mw4.z, mw4.w};
            float mkv[4] = {mk4.x, mk4.y, mk4.z, mk4.w};
            float mvv[4] = {mv4.x, mv4.y, mv4.z, mv4.w};
            float mrv[4] = {mr4.x, mr4.y, mr4.z, mr4.w};
            float mgv[4] = {mg4.x, mg4.y, mg4.z, mg4.w};
            ushort4 ov[5];
#pragma unroll
            for (int r = 0; r < 4; ++r) {
                ((unsigned short*)&ov[0])[r] = f2bf(fmaf(xxv[r], mwv[r] + acc[0][r], xvv[r]));
                ((unsigned short*)&ov[1])[r] = f2bf(fmaf(xxv[r], mkv[r] + acc[1][r], xvv[r]));
                ((unsigned short*)&ov[2])[r] = f2bf(fmaf(xxv[r], mvv[r] + acc[2][r], xvv[r]));
                ((unsigned short*)&ov[3])[r] = f2bf(fmaf(xxv[r], mrv[r] + acc[3][r], xvv[r]));
                ((unsigned short*)&ov[4])[r] = f2bf(fmaf(xxv[r], mgv[r] + acc[4][r], xvv[r]));
            }
            int col = nf * 16 + lhi * 4;
#pragma unroll
            for (int f = 0; f < 5; ++f)
                *(ushort4*)&tile[wid][f][llo][col] = ov[f];
        }
        // restaged coalesced stores: 8 lanes cover one 128B row segment
        int row16 = lane >> 3;          // 0..7
        int colc = (lane & 7) * 8;      // ushort offset, 16B chunks
#pragma unroll
        for (int f = 0; f < 5; ++f) {
#pragma unroll
            for (int p = 0; p < 2; ++p) {
                int rr = p * 8 + row16;
                int gm = mb + sub * 16 + rr;
                *(short8*)&outs[f][(size_t)gm * Cq + nb + colc] =
                    *(const short8*)&tile[wid][f][rr][colc];
            }
        }
    }
}

// ---------------------------------------------------------------------------
// WKV6 chunked scan: lane = slot*8+i, 8 heads/wave. k,v,r bf16; d fp32.
// ---------------------------------------------------------------------------
__global__ __launch_bounds__(64) void wkv_pass1_kernel(
    const unsigned short* __restrict__ k, const unsigned short* __restrict__ v,
    const float* __restrict__ d,
    float* __restrict__ Dbuf, float* __restrict__ Cbuf) {
    int chunk = blockIdx.x, hg = blockIdx.y, b = blockIdx.z;
    int lane = threadIdx.x;
    int slot = lane >> 3, i = lane & 7;
    int cbase = hg * 64;
    size_t gbase = ((size_t)b * Tq + (size_t)chunk * CLq) * Cq + cbase;
    __shared__ float ks[TSq][64], vs[TSq][64], ds[TSq][64];
    float S[8], D[8];
#pragma unroll
    for (int j = 0; j < 8; ++j) { S[j] = 0.f; D[j] = 1.f; }
    for (int t0 = 0; t0 < CLq; t0 += TSq) {
        int f = lane & 15, r4 = lane >> 4;
#pragma unroll
        for (int p = 0; p < 8; ++p) {
            int row = r4 + p * 4;
            size_t g = gbase + (size_t)(t0 + row) * Cq + f * 4;
            *(float4*)&ks[row][f * 4] = bf4_to_f4(*(const ushort4*)&k[g]);
            *(float4*)&vs[row][f * 4] = bf4_to_f4(*(const ushort4*)&v[g]);
            *(float4*)&ds[row][f * 4] = *(const float4*)&d[g];
        }
        __syncthreads();
#pragma unroll 8
        for (int t = 0; t < TSq; ++t) {
            float vv = vs[t][lane];
            float4 ka = *(const float4*)&ks[t][slot * 8];
            float4 kb = *(const float4*)&ks[t][slot * 8 + 4];
            float4 da = *(const float4*)&ds[t][slot * 8];
            float4 db = *(const float4*)&ds[t][slot * 8 + 4];
            float kk[8] = {ka.x, ka.y, ka.z, ka.w, kb.x, kb.y, kb.z, kb.w};
            float dd[8] = {da.x, da.y, da.z, da.w, db.x, db.y, db.z, db.w};
#pragma unroll
            for (int j = 0; j < 8; ++j) {
                float kv = kk[j] * vv;
                S[j] = fmaf(dd[j], S[j], kv);
                D[j] *= dd[j];
            }
        }
        __syncthreads();
    }
    size_t dbase = (((size_t)b * NCHq + chunk) * NHq + hg * 8) * 8;
    Dbuf[dbase + lane] = D[i];
    size_t cb = (((size_t)b * NCHq + chunk) * NHq + (hg * 8 + slot)) * 64 + i;
#pragma unroll
    for (int j = 0; j < 8; ++j) Cbuf[cb + j * 8] = S[j];
}

__global__ __launch_bounds__(64) void wkv_pass2_kernel(
    const float* __restrict__ Dbuf, const float* __restrict__ Cbuf,
    float* __restrict__ Sbuf) {
    int bh = blockIdx.x;
    int lane = threadIdx.x;
    int j = lane >> 3, i = lane & 7;
    int b = bh / NHq, h = bh - b * NHq;
    float S = 0.f;
    size_t stride = (size_t)NHq * 64;
    size_t base = ((size_t)b * NCHq * NHq + h) * 64 + j * 8 + i;
    size_t dstride = (size_t)NHq * 8;
    size_t dbase = ((size_t)b * NCHq * NHq + h) * 8 + j;
#pragma unroll 4
    for (int c = 0; c < NCHq; ++c) {
        Sbuf[base + c * stride] = S;
        float D = Dbuf[dbase + c * dstride];
        float C = Cbuf[base + c * stride];
        S = fmaf(D, S, C);
    }
}

__global__ __launch_bounds__(64) void wkv_pass3_kernel(
    const unsigned short* __restrict__ r, const unsigned short* __restrict__ k,
    const unsigned short* __restrict__ v, const float* __restrict__ d,
    const float* __restrict__ u, const float* __restrict__ Sbuf,
    unsigned short* __restrict__ y) {
    int chunk = blockIdx.x, hg = blockIdx.y, b = blockIdx.z;
    int lane = threadIdx.x;
    int slot = lane >> 3, i = lane & 7;
    int h = hg * 8 + slot;
    int cbase = hg * 64;
    size_t gbase = ((size_t)b * Tq + (size_t)chunk * CLq) * Cq + cbase;
    __shared__ float rs[TSq][64], ks[TSq][64], vs[TSq][64], ds[TSq][64];
    float S[8], uu[8];
    size_t sb = (((size_t)b * NCHq + chunk) * NHq + h) * 64 + i;
#pragma unroll
    for (int j = 0; j < 8; ++j) {
        S[j] = Sbuf[sb + j * 8];
        uu[j] = u[h * 8 + j];
    }
    for (int t0 = 0; t0 < CLq; t0 += TSq) {
        int f = lane & 15, r4 = lane >> 4;
#pragma unroll
        for (int p = 0; p < 8; ++p) {
            int row = r4 + p * 4;
            size_t g = gbase + (size_t)(t0 + row) * Cq + f * 4;
            *(float4*)&rs[row][f * 4] = bf4_to_f4(*(const ushort4*)&r[g]);
            *(float4*)&ks[row][f * 4] = bf4_to_f4(*(const ushort4*)&k[g]);
            *(float4*)&vs[row][f * 4] = bf4_to_f4(*(const ushort4*)&v[g]);
            *(float4*)&ds[row][f * 4] = *(const float4*)&d[g];
        }
        __syncthreads();
#pragma unroll 8
        for (int t = 0; t < TSq; ++t) {
            float vv = vs[t][lane];
            float4 ra = *(const float4*)&rs[t][slot * 8];
            float4 rb = *(const float4*)&rs[t][slot * 8 + 4];
            float4 ka = *(const float4*)&ks[t][slot * 8];
            float4 kb = *(const float4*)&ks[t][slot * 8 + 4];
            float4 da = *(const float4*)&ds[t][slot * 8];
            float4 db = *(const float4*)&ds[t][slot * 8 + 4];
            float rr[8] = {ra.x, ra.y, ra.z, ra.w, rb.x, rb.y, rb.z, rb.w};
            float kk[8] = {ka.x, ka.y, ka.z, ka.w, kb.x, kb.y, kb.z, kb.w};
            float dd[8] = {da.x, da.y, da.z, da.w, db.x, db.y, db.z, db.w};
            float yv = 0.f;
#pragma unroll
            for (int j = 0; j < 8; ++j) {
                float kv = kk[j] * vv;
                yv = fmaf(rr[j], fmaf(uu[j], kv, S[j]), yv);
                S[j] = fmaf(dd[j], S[j], kv);
            }
            y[gbase + (size_t)(t0 + t) * Cq + lane] = f2bf(yv);
        }
        __syncthreads();
    }
}

// ---------------------------------------------------------------------------
// LayerNorm + gate (y, g bf16 in) -> bf16 out
// ---------------------------------------------------------------------------
__global__ __launch_bounds__(256) void ln_gate_kernel(
    const unsigned short* __restrict__ y, const unsigned short* __restrict__ g,
    const float* __restrict__ ln_g, const float* __restrict__ ln_b,
    unsigned short* __restrict__ out) {
    int row = blockIdx.x * 4 + (threadIdx.x >> 6);
    int lane = threadIdx.x & 63;
    const unsigned short* yr = y + (size_t)row * Cq;
    float a0 = bf2f(yr[lane]), a1 = bf2f(yr[lane + 64]), a2 = bf2f(yr[lane + 128]);
    float s = a0 + a1 + a2;
    float ss = a0 * a0 + a1 * a1 + a2 * a2;
#pragma unroll
    for (int m = 1; m < 64; m <<= 1) {
        s += __shfl_xor(s, m);
        ss += __shfl_xor(ss, m);
    }
    float mu = s * (1.f / 192.f);
    float var = ss * (1.f / 192.f) - mu * mu;
    float rstd = rsqrtf(var + 1e-5f);
    const unsigned short* gr = g + (size_t)row * Cq;
    unsigned short* orow = out + (size_t)row * Cq;
    float aa[3] = {a0, a1, a2};
#pragma unroll
    for (int q = 0; q < 3; ++q) {
        int cc = lane + q * 64;
        float yn = (aa[q] - mu) * rstd * ln_g[cc] + ln_b[cc];
        orow[cc] = f2bf(yn * bf2f(gr[cc]));
    }
}

// ---------------------------------------------------------------------------
extern "C" void kernel_launch(void* const* d_in, const int* in_sizes, int n_in,
                              void* d_out, int out_size, void* d_ws, size_t ws_size,
                              hipStream_t stream) {
    const float* x        = (const float*)d_in[0];
    const float* maa_x    = (const float*)d_in[1];
    const float* maa_w    = (const float*)d_in[2];
    const float* maa_k    = (const float*)d_in[3];
    const float* maa_v    = (const float*)d_in[4];
    const float* maa_r    = (const float*)d_in[5];
    const float* maa_g    = (const float*)d_in[6];
    const float* maa_w1   = (const float*)d_in[7];
    const float* maa_w2   = (const float*)d_in[8];
    const float* decay_w1 = (const float*)d_in[9];
    const float* decay_w2 = (const float*)d_in[10];
    const float* sdecay   = (const float*)d_in[11];
    const float* u        = (const float*)d_in[12];
    const float* Wr       = (const float*)d_in[13];
    const float* Wk       = (const float*)d_in[14];
    const float* Wv       = (const float*)d_in[15];
    const float* Wgp      = (const float*)d_in[16];
    const float* Wo       = (const float*)d_in[17];
    const float* ln_g     = (const float*)d_in[18];
    const float* ln_b     = (const float*)d_in[19];
    const float* w_lp     = (const float*)d_in[20];
    const float* w_hd     = (const float*)d_in[21];
    const float* w_vd     = (const float*)d_in[22];
    const float* w_cd     = (const float*)d_in[23];
    const float* theta    = (const float*)d_in[24];
    float* out = (float*)d_out;

    const size_t BIG = (size_t)Mq * Cq;          // 6,291,456 floats
    float* ws = (float*)d_ws;
    unsigned short* Wgt_conv = (unsigned short*)ws;            // 192*1728
    unsigned short* Wt_maa = Wgt_conv + (size_t)Cq * 1728;     // 160*192
    unsigned short* Wt_r = Wt_maa + 160 * Cq;
    unsigned short* Wt_k = Wt_r + Cq * Cq;
    unsigned short* Wt_v = Wt_k + Cq * Cq;
    unsigned short* Wt_g = Wt_v + Cq * Cq;
    unsigned short* Wt_o = Wt_g + Cq * Cq;
    unsigned short* w2t  = Wt_o + Cq * Cq;                     // 5*192*32
    unsigned short* Wt_d1 = w2t + 5 * 192 * 32;                // 64*192
    unsigned short* Wt_d2 = Wt_d1 + 64 * Cq;                   // 192*64
    float* tmp  = ws + 331776;                  // M*160 region
    float* wtmp = tmp + (size_t)Mq * 160;       // M*64
    float* buf0 = wtmp + (size_t)Mq * 64;
    float* buf1 = buf0 + BIG;
    float* buf2 = buf1 + BIG;
    float* buf3 = buf2 + BIG;
    float* buf4 = buf3 + BIG;
    float* buf5 = buf4 + BIG;

    // tmp region: bf16 tmp (M*80 floats) then WKV scan scratch
    unsigned short* tmp_bf = (unsigned short*)tmp;
    float* Dbuf = tmp + (size_t)Mq * 80;
    float* Cbuf = Dbuf + (size_t)Bq * NCHq * NHq * 8;
    float* Sbuf = Cbuf + (size_t)Bq * NCHq * NHq * 64;

    // overlays (bf16 halves of fp32 buffers); lifetimes annotated:
    unsigned short* x_halo = (unsigned short*)buf1;            // halo..mix5 (6.69M us)
    unsigned short* y_b    = (unsigned short*)buf1;            // pass3..ln (front half)
    unsigned short* k_b    = (unsigned short*)(buf1 + BIG / 2); // proj4..pass3 (back half)
    unsigned short* xx_b   = (unsigned short*)buf0;            // conv..mix5
    unsigned short* xw_b   = (unsigned short*)(buf0 + BIG / 2); // mix5..decay1
    unsigned short* r_b    = (unsigned short*)buf0;            // proj4..pass3 (xx dead)
    unsigned short* xxx_b  = (unsigned short*)(buf2 + BIG / 2); // conv..maa
    unsigned short* xg_b   = xxx_b;                            // mix5..proj4
    unsigned short* xv_b   = (unsigned short*)buf2;            // mix5..proj4
    unsigned short* gate_b = (unsigned short*)buf2;            // ln..Wo (xv dead)
    unsigned short* v_b    = (unsigned short*)buf3;            // proj4..pass3
    unsigned short* g_b    = (unsigned short*)buf4;            // proj4..ln
    unsigned short* xr_b   = (unsigned short*)buf5;            // mix5..proj4
    unsigned short* xk_b   = (unsigned short*)(buf5 + BIG / 2); // mix5..proj4
    float* d_f             = buf5;                             // decay2..pass3 (fp32)
    unsigned short* wtmp_b = (unsigned short*)wtmp;            // decay mid [M][64]

    dim3 blk(256);
    const unsigned short* nosrc = nullptr;
    unsigned short* nodst = nullptr;

    // 1) weight prep (2 launches)
    prep_weights_kernel<<<dim3(144), blk, 0, stream>>>(w_lp, w_hd, w_vd, w_cd, theta, Wgt_conv);
    prep_pack_kernel<<<dim3(1056), blk, 0, stream>>>(
        maa_w1, Wr, Wk, Wv, Wgp, Wo, maa_w2, decay_w1, decay_w2,
        Wt_maa, Wt_r, Wt_k, Wt_v, Wt_g, Wt_o, w2t, Wt_d1, Wt_d2);
    // 2) halo-pad x; conv implicit GEMM (BN=96), dual-out xx_b + xxx_b
    halo_kernel<<<dim3(8 * 66 * 66 * 48 / 256), blk, 0, stream>>>(x, x_halo);
    mgemm_kernel<1, 5, 1, 96><<<dim3(Mq / GBM, 2), blk, 0, stream>>>(
        x_halo, Wgt_conv, xx_b, Cq, 1728, maa_x, x_halo, xxx_b);
    // 3) tmp_bf = bf16(tanh(xxx @ maa_w1)) [M,160]
    mgemm_kernel<3, 2, 1, 64><<<dim3(Mq / GBM, 3), blk, 0, stream>>>(
        xxx_b, Wt_maa, tmp_bf, 160, Cq, nullptr, nosrc, nodst);
    // 4) fused mixes: all five bf16, LDS-restaged stores
    mix5_kernel<<<dim3(Mq / 64, 3), dim3(128), 0, stream>>>(
        x_halo, xx_b, tmp_bf, w2t, maa_w, maa_k, maa_v, maa_r, maa_g,
        xw_b, xr_b, xk_b, xv_b, xg_b);
    // 5) merged projections: z = {v, r, k, g=silu}
    proj4_kernel<<<dim3(Mq / GBM, 3, 4), blk, 0, stream>>>(
        xv_b, xr_b, xk_b, xg_b,
        Wt_v, Wt_r, Wt_k, Wt_g,
        v_b, r_b, k_b, g_b);
    // 6) decay: wtmp_b = bf16(tanh(xw@w1)); d = exp(-exp(sd+.@w2)) fp32
    mgemm_kernel<3, 2, 1, 64><<<dim3(Mq / GBM, 1), blk, 0, stream>>>(
        xw_b, Wt_d1, wtmp_b, 64, Cq, nullptr, nosrc, nodst);
    mgemm_kernel<3, 4, 0, 64><<<dim3(Mq / GBM, 3), blk, 0, stream>>>(
        wtmp_b, Wt_d2, d_f, Cq, 64, sdecay, nosrc, nodst);
    // 7) WKV chunked scan (k,v,r bf16; d fp32) -> y_b bf16
    wkv_pass1_kernel<<<dim3(NCHq, 3, Bq), dim3(64), 0, stream>>>(k_b, v_b, d_f, Dbuf, Cbuf);
    wkv_pass2_kernel<<<dim3(Bq * NHq), dim3(64), 0, stream>>>(Dbuf, Cbuf, Sbuf);
    wkv_pass3_kernel<<<dim3(NCHq, 3, Bq), dim3(64), 0, stream>>>(r_b, k_b, v_b, d_f, u, Sbuf, y_b);
    // 8) LN + gate -> gate_b bf16
    ln_gate_kernel<<<dim3(Mq / 4), blk, 0, stream>>>(y_b, g_b, ln_g, ln_b, gate_b);
    // 9) output projection (fp32 out)
    mgemm_kernel<3, 0, 0, 64><<<dim3(Mq / GBM, 3), blk, 0, stream>>>(
        gate_b, Wt_o, out, Cq, Cq, nullptr, nosrc, nodst);
}